// Round 19
// baseline (492.128 us; speedup 1.0000x reference)
//
#include <hip/hip_runtime.h>
#include <math.h>

// Problem constants
#define BATCH 32
#define BB    64     // merged batch: rows 0..31 = H, 32..63 = F
#define SEQ  512
#define DIM  512
#define MM   1000
#define NHEAD 8
#define DHEAD 64
#define DFFN 2048
#define BROWS (BB * SEQ)     // 32768 rows (both passes)

typedef __attribute__((ext_vector_type(8))) short short8;
typedef __attribute__((ext_vector_type(4))) float f32x4;

__device__ __forceinline__ ushort f2bf(float x) {
    unsigned u = __builtin_bit_cast(unsigned, x);
    unsigned r = (u + 0x7FFFu + ((u >> 16) & 1u)) >> 16;
    return (ushort)r;
}
__device__ __forceinline__ float bf2f(ushort h) {
    unsigned u = ((unsigned)h) << 16;
    return __builtin_bit_cast(float, u);
}

// async global->LDS, 16B per lane. LDS dest must be wave-uniform base
// (HW adds lane*16); global src is per-lane. [m97/m104 semantics]
#define GL2LDS(g, s) __builtin_amdgcn_global_load_lds( \
    (const __attribute__((address_space(1))) unsigned int*)(g), \
    (__attribute__((address_space(3))) unsigned int*)(s), 16, 0, 0)

// ---------------------------------------------------------------------------
// ws layout (float32-slot offsets) — total 52,559,872 slots = 210.2 MB
// (d_ws = 256 MiB). FFN dataflow (r11-13 invariant): ehi/elo hold pristine
// h for ALL W1 chunks; h' accumulates in Qb/Kb; rbuf spans Vtb+R2.
// ---------------------------------------------------------------------------
constexpr size_t OFF_WMT  = 0;         // fp32 [1000][512]
constexpr size_t OFF_MASK = 524288;    // fp32 [32768]
constexpr size_t OFF_POOL = 557056;    // fp32 [64][512]
constexpr size_t OFF_HENC = 589824;    // fp32 [64][512]
constexpr size_t OFF_WQTH = 655360;    // bf16 [2048][512] concat Wq|Wk|Wv|Wo
constexpr size_t OFF_W1TH = 1179648;   // bf16 [2048][512]
constexpr size_t OFF_W2TH = 1703936;   // bf16 [512][2048]
constexpr size_t OFF_EHI  = 2228224;   // bf16 [32768][512]  e -> h (pristine)
constexpr size_t OFF_ELO  = 10616832;  // bf16 [32768][512]
constexpr size_t OFF_QB   = 19005440;  // bf16 Q -> O -> h'_hi
constexpr size_t OFF_KB   = 27394048;  // bf16 K -> h'_lo
constexpr size_t OFF_VB   = 35782656;  // bf16 V^T [b][512][512]; + R2 ->
                                       //   rbuf [32768][1024]

// ---------------- fused setup: WmT + WqkvT + W1T + W2T ---------------------
// grid 3584 x 256: [0,512) transpose_wm, [512,1536) split_wT4,
// [1536,2560) W1 (K=512,N=2048), [2560,3584) W2 (K=2048,N=512).
__global__ __launch_bounds__(256)
void setup_all(const float* __restrict__ Wm,
               const float* __restrict__ Wq, const float* __restrict__ Wk,
               const float* __restrict__ Wv, const float* __restrict__ Wo,
               const float* __restrict__ W1, const float* __restrict__ W2,
               float* __restrict__ WmT, ushort* __restrict__ WqkvTh,
               ushort* __restrict__ W1Th, ushort* __restrict__ W2Th)
{
    __shared__ float tile[32][33];
    const int bid = blockIdx.x;
    const int tx = threadIdx.x & 31;
    const int ty = threadIdx.x >> 5;
    if (bid < 512) {                         // W_m [512,1000] -> [1000,512] f32
        int mx = (bid & 31) * 32, dy = (bid >> 5) * 32;
        for (int i = ty; i < 32; i += 8) {
            int d = dy + i, m = mx + tx;
            tile[i][tx] = (m < MM) ? Wm[(size_t)d * MM + m] : 0.f;
        }
        __syncthreads();
        for (int i = ty; i < 32; i += 8) {
            int m = mx + i, d = dy + tx;
            if (m < MM) WmT[(size_t)m * DIM + d] = tile[tx][i];
        }
    } else if (bid < 1536) {                 // Wq|Wk|Wv|Wo -> [2048][512] bf16
        int id = bid - 512;
        int n0 = (id & 63) * 32, k0 = (id >> 6) * 32;
        const float* W = (n0 < 512) ? Wq : (n0 < 1024) ? Wk
                       : (n0 < 1536) ? Wv : Wo;
        int nc = n0 & 511;
        for (int i = ty; i < 32; i += 8)
            tile[i][tx] = W[(size_t)(k0 + i) * 512 + nc + tx];
        __syncthreads();
        for (int i = ty; i < 32; i += 8)
            WqkvTh[(size_t)(n0 + i) * 512 + k0 + tx] = f2bf(tile[tx][i]);
    } else if (bid < 2560) {                 // W1 [512,2048] -> [2048][512]
        int id = bid - 1536;
        int n0 = (id & 63) * 32, k0 = (id >> 6) * 32;
        for (int i = ty; i < 32; i += 8)
            tile[i][tx] = W1[(size_t)(k0 + i) * DFFN + n0 + tx];
        __syncthreads();
        for (int i = ty; i < 32; i += 8)
            W1Th[(size_t)(n0 + i) * DIM + k0 + tx] = f2bf(tile[tx][i]);
    } else {                                 // W2 [2048,512] -> [512][2048]
        int id = bid - 2560;
        int n0 = (id & 15) * 32, k0 = (id >> 4) * 32;
        for (int i = ty; i < 32; i += 8)
            tile[i][tx] = W2[(size_t)(k0 + i) * DIM + n0 + tx];
        __syncthreads();
        for (int i = ty; i < 32; i += 8)
            W2Th[(size_t)(n0 + i) * DFFN + k0 + tx] = f2bf(tile[tx][i]);
    }
}

// ---------------- embedding + mask -> e_hi/e_lo bf16 (both passes) ---------
__global__ __launch_bounds__(256)
void embed_kernel(const float* __restrict__ xH, const float* __restrict__ xF,
                  const float* __restrict__ WmT, const float* __restrict__ Wt,
                  const float* __restrict__ bt,
                  ushort* __restrict__ ehi, ushort* __restrict__ elo,
                  float* __restrict__ maskA)
{
    int sub  = threadIdx.x >> 6;          // 0..3
    int lane = threadIdx.x & 63;          // 0..63
    int bs   = blockIdx.x * 4 + sub;      // 0..32767
    const float* xp = (bs < BATCH * SEQ) ? (xH + (size_t)bs * 2)
                                         : (xF + (size_t)(bs - BATCH * SEQ) * 2);
    float t   = xp[0];
    float mkf = xp[1];
    int   mk  = (int)fminf(fmaxf(mkf, 0.f), (float)(MM - 1));
    bool  valid = (t >= 0.f);
    if (lane == 0) maskA[bs] = valid ? 1.f : 0.f;
    const float* wrow = WmT + (size_t)mk * DIM + lane * 8;
    float4 w0 = *reinterpret_cast<const float4*>(wrow);
    float4 w1 = *reinterpret_cast<const float4*>(wrow + 4);
    float4 t0 = *reinterpret_cast<const float4*>(Wt + lane * 8);
    float4 t1 = *reinterpret_cast<const float4*>(Wt + lane * 8 + 4);
    float4 b0 = *reinterpret_cast<const float4*>(bt + lane * 8);
    float4 b1 = *reinterpret_cast<const float4*>(bt + lane * 8 + 4);
    float v[8];
    v[0] = w0.x * 0.5f + 0.5f * (t0.x * t + b0.x);
    v[1] = w0.y * 0.5f + 0.5f * (t0.y * t + b0.y);
    v[2] = w0.z * 0.5f + 0.5f * (t0.z * t + b0.z);
    v[3] = w0.w * 0.5f + 0.5f * (t0.w * t + b0.w);
    v[4] = w1.x * 0.5f + 0.5f * (t1.x * t + b1.x);
    v[5] = w1.y * 0.5f + 0.5f * (t1.y * t + b1.y);
    v[6] = w1.z * 0.5f + 0.5f * (t1.z * t + b1.z);
    v[7] = w1.w * 0.5f + 0.5f * (t1.w * t + b1.w);
    union { uint4 u; ushort s[8]; } ph, pl;
    #pragma unroll
    for (int j = 0; j < 8; ++j) {
        float vv = valid ? v[j] : 0.f;
        ushort h = f2bf(vv);
        ph.s[j] = h;
        pl.s[j] = f2bf(vv - bf2f(h));
    }
    size_t base = (size_t)bs * DIM + lane * 8;
    *reinterpret_cast<uint4*>(ehi + base) = ph.u;
    *reinterpret_cast<uint4*>(elo + base) = pl.u;
}

// ---------------- bf16 MFMA GEMM, 128x128 tile, 2-phase dbuf ---------------
// (unchanged from r18 — proven)
template<int SEGS, bool BIAS, bool RELU, bool RES, bool PAIR, bool TOUT, bool TRIPLE>
__global__ __launch_bounds__(256)
void gemm_bf16(const ushort* __restrict__ A0, const ushort* __restrict__ A1,
               const ushort* __restrict__ B0, const ushort* __restrict__ B1,
               const float* __restrict__ bias,
               const ushort* __restrict__ Rh, const ushort* __restrict__ Rl,
               ushort* __restrict__ Oh, ushort* __restrict__ Ol,
               ushort* __restrict__ Ot,
               int Md, int Nd, int Kd, int lda, int ldb,
               const float* __restrict__ mrow)
{
    __shared__ __align__(16) ushort As[2][128 * 64];
    __shared__ __align__(16) ushort Bs[2][128 * 64];
    const int tid = threadIdx.x;
    const int w = tid >> 6, l = tid & 63;
    const int wr = w >> 1, wc = w & 1;
    const int l15 = l & 15, lg = l >> 4;
    const int id  = blockIdx.x + gridDim.x * blockIdx.y;
    const int nwg = gridDim.x * gridDim.y;
    const int qc  = nwg >> 3;
    const int lin = (id & 7) * qc + (id >> 3);
    const int row0 = (lin / gridDim.x) * 128;
    const int col0 = (lin % gridDim.x) * 128;
    const int lrow   = l >> 3;
    const int gchunk = (l & 7) ^ lrow;

    if (mrow) {
        float mv = (tid < 128) ? mrow[row0 + tid] : 0.f;
        if (!__syncthreads_or(mv != 0.f)) return;
    }

    f32x4 acc[4][4];
    #pragma unroll
    for (int m = 0; m < 4; m++)
        #pragma unroll
        for (int n = 0; n < 4; n++)
            acc[m][n] = (f32x4){0.f, 0.f, 0.f, 0.f};

    const int NT = SEGS * (Kd >> 6);
    int sseg = 0, skt = 0;

    auto stage = [&](int bi) {
        const ushort* Ap = (sseg == 1) ? A1 : A0;
        const ushort* Bp = (sseg == 2) ? B1 : B0;
        ushort* Asb = &As[bi][0];
        ushort* Bsb = &Bs[bi][0];
        #pragma unroll
        for (int r = 0; r < 4; ++r) {
            int rowb = w * 32 + r * 8;
            int row  = rowb + lrow;
            GL2LDS(Ap + (size_t)(row0 + row) * lda + skt + gchunk * 8,
                   Asb + rowb * 64);
            GL2LDS(Bp + (size_t)(col0 + row) * ldb + skt + gchunk * 8,
                   Bsb + rowb * 64);
        }
        skt += 64;
        if (skt == Kd) { skt = 0; ++sseg; }
    };

    stage(0);
    __syncthreads();

    for (int t = 0; t < NT; ++t) {
        const int cur = t & 1;
        if (t + 1 < NT) stage(cur ^ 1);
        const char* AsB = (const char*)&As[cur][0];
        const char* BsB = (const char*)&Bs[cur][0];
        #pragma unroll
        for (int ks = 0; ks < 2; ++ks) {
            const int g = ks * 4 + lg;
            short8 af[4], bfr[4];
            #pragma unroll
            for (int m = 0; m < 4; ++m) {
                int row = wr * 64 + m * 16 + l15;
                af[m] = *reinterpret_cast<const short8*>(
                    AsB + row * 128 + ((g ^ (row & 7)) << 4));
            }
            #pragma unroll
            for (int n = 0; n < 4; ++n) {
                int row = wc * 64 + n * 16 + l15;
                bfr[n] = *reinterpret_cast<const short8*>(
                    BsB + row * 128 + ((g ^ (row & 7)) << 4));
            }
            #pragma unroll
            for (int m = 0; m < 4; ++m)
                #pragma unroll
                for (int n = 0; n < 4; ++n)
                    acc[m][n] = __builtin_amdgcn_mfma_f32_16x16x32_bf16(
                        af[m], bfr[n], acc[m][n], 0, 0, 0);
        }
        __syncthreads();
    }

    #pragma unroll
    for (int m = 0; m < 4; ++m) {
        #pragma unroll
        for (int n = 0; n < 4; ++n) {
            int col = col0 + wc * 64 + n * 16 + l15;
            if (TRIPLE) {
                if (col0 < 512) {
                    #pragma unroll
                    for (int j = 0; j < 4; ++j) {
                        int row = row0 + wr * 64 + m * 16 + lg * 4 + j;
                        Oh[(size_t)row * 512 + col] = f2bf(acc[m][n][j]);
                    }
                } else if (col0 < 1024) {
                    #pragma unroll
                    for (int j = 0; j < 4; ++j) {
                        int row = row0 + wr * 64 + m * 16 + lg * 4 + j;
                        Ol[(size_t)row * 512 + (col - 512)] = f2bf(acc[m][n][j]);
                    }
                } else {
                    union { uint2 u; ushort s4[4]; } pk;
                    #pragma unroll
                    for (int j = 0; j < 4; ++j) pk.s4[j] = f2bf(acc[m][n][j]);
                    int brow = row0 + wr * 64 + m * 16 + lg * 4;
                    size_t idx = ((size_t)(brow >> 9) << 18)
                               + (size_t)(col - 1024) * SEQ + (brow & 511);
                    *reinterpret_cast<uint2*>(Ot + idx) = pk.u;
                }
            } else if (TOUT) {
                union { uint2 u; ushort s4[4]; } pk;
                #pragma unroll
                for (int j = 0; j < 4; ++j) pk.s4[j] = f2bf(acc[m][n][j]);
                int brow = row0 + wr * 64 + m * 16 + lg * 4;
                size_t idx = ((size_t)(brow >> 9) << 18) + (size_t)col * SEQ + (brow & 511);
                *reinterpret_cast<uint2*>(Oh + idx) = pk.u;
            } else {
                float bia = 0.f;
                if (BIAS) bia = bias[col];
                #pragma unroll
                for (int j = 0; j < 4; ++j) {
                    int row = row0 + wr * 64 + m * 16 + lg * 4 + j;
                    size_t idx = (size_t)row * Nd + col;
                    float v = acc[m][n][j] + bia;
                    if (RES)  v += bf2f(Rh[idx]) + bf2f(Rl[idx]);
                    if (RELU) v = fmaxf(v, 0.f);
                    ushort hv = f2bf(v);
                    Oh[idx] = hv;
                    if (PAIR) Ol[idx] = f2bf(v - bf2f(hv));
                }
            }
        }
    }
}

// ---------------- MFMA flash attention, 128 q-rows, KV dbuf, static-max ----
// grid (NHEAD, BB, 4). 512 threads = 8 waves; wave owns 16 q-rows.
// Full mask row preloaded to LDS once; per-64-kv-tile valid bits computed
// block-uniformly up front (8 syncthreads_or). Valid tiles iterated with
// 2-phase K/V double-buffering (T3-minimum, GEMM-proven): stage(next valid)
// -> compute(current) -> barrier. STATIC-MAX softmax (scores bounded <<1):
// p = mask * exp(s/8), exact. P per-wave buffer reused per tile (wave-
// private, in-order LDS). Q-stage aliases Pl (af hoisted before P writes).
// LDS: Ks 2x8K + Vs 2x8K + Pl 16K + ms 2K = 50.5KB -> 3 blocks/CU.
__global__ __launch_bounds__(512)
void attn_mfma(ushort* __restrict__ QO, const ushort* __restrict__ K,
               const ushort* __restrict__ Vt, const float* __restrict__ maskA)
{
    __shared__ __align__(16) ushort Ks[2][64 * 64];   // [buf][kv][dh]
    __shared__ __align__(16) ushort Vs[2][64 * 64];   // [buf][dh][kv]
    __shared__ __align__(16) ushort Pl[8][16 * 64];   // [wave][q][kv] (Q alias)
    __shared__ float ms[512];
    const int h   = blockIdx.x;
    const int b   = blockIdx.y;
    const int qt  = blockIdx.z;
    const int tid = threadIdx.x;
    const int w = tid >> 6, l = tid & 63;
    const int l15 = l & 15, lg = l >> 4, l7 = l & 7;
    const int lrow   = l >> 3;
    const int gchunk = (l & 7) ^ lrow;
    const int qbase = qt * 128;

    // stage Q tile [128 q][64 dh] into Pl (dead until first P write)
    #pragma unroll
    for (int rr = 0; rr < 2; ++rr) {
        int rowb = rr * 64 + w * 8;             // 16 stripes, wave-uniform
        GL2LDS(QO + ((size_t)(b * SEQ + qbase + rowb + lrow)) * DIM
                  + h * DHEAD + gchunk * 8,
               &Pl[0][0] + rowb * 64);
    }
    // full mask row -> LDS (published by the q-skip barrier below)
    ms[tid] = maskA[b * SEQ + tid];
    // dead q-tile skip (global reads; barrier also drains Q-stage + ms)
    float qm = (tid < 128) ? maskA[b * SEQ + qbase + tid] : 0.f;
    if (!__syncthreads_or(qm != 0.f)) return;

    // per-64-kv-tile valid bits (block-uniform)
    unsigned hbits = 0;
    #pragma unroll
    for (int t = 0; t < 8; ++t) {
        int mine = (tid < 64) ? (ms[t * 64 + tid] != 0.f) : 0;
        if (__syncthreads_or(mine)) hbits |= (1u << t);
    }

    // hoist Q A-frags (reads Pl BEFORE any P write); wave w rows w*16+l15
    short8 af[2];
    #pragma unroll
    for (int s = 0; s < 2; ++s) {
        int q = w * 16 + l15;
        int c = (s * 4 + lg) ^ l7;
        af[s] = *reinterpret_cast<const short8*>(&Pl[0][0] + q * 64 + c * 8);
    }

    f32x4 oacc[4];
    #pragma unroll
    for (int t = 0; t < 4; ++t) oacc[t] = (f32x4){0.f, 0.f, 0.f, 0.f};
    float lrun[4];
    #pragma unroll
    for (int j = 0; j < 4; ++j) lrun[j] = 0.f;

    ushort* pw = &Pl[w][0];

    // one GL2LDS each for K and V^T per thread per tile (8 waves x 8 rows)
    auto stagekv = [&](int t, int bi) {
        int kv0 = t * 64;
        GL2LDS(K + ((size_t)(b * SEQ + kv0 + w * 8 + lrow)) * DIM
                 + h * DHEAD + gchunk * 8,
               &Ks[bi][0] + w * 8 * 64);
        GL2LDS(Vt + ((size_t)b << 18) + (size_t)(h * DHEAD + w * 8 + lrow) * SEQ
                  + kv0 + gchunk * 8,
               &Vs[bi][0] + w * 8 * 64);
    };

    int t0 = 0;
    while (t0 < 8 && !(hbits & (1u << t0))) ++t0;
    stagekv(t0, 0);
    __syncthreads();                         // tile t0 K/V ready
    int cur = 0;
    for (int t = t0; t < 8; ) {
        int tn = t + 1;
        while (tn < 8 && !(hbits & (1u << tn))) ++tn;
        if (tn < 8) stagekv(tn, cur ^ 1);    // async prefetch next valid tile

        // QK^T: 4 kv16-tiles x 2 k-steps
        f32x4 sacc[4];
        #pragma unroll
        for (int t4 = 0; t4 < 4; ++t4) sacc[t4] = (f32x4){0.f, 0.f, 0.f, 0.f};
        #pragma unroll
        for (int s = 0; s < 2; ++s) {
            int c = (s * 4 + lg) ^ l7;
            #pragma unroll
            for (int t4 = 0; t4 < 4; ++t4) {
                int kv = t4 * 16 + l15;
                short8 bf = *reinterpret_cast<const short8*>(
                    &Ks[cur][0] + kv * 64 + c * 8);
                sacc[t4] = __builtin_amdgcn_mfma_f32_16x16x32_bf16(af[s], bf, sacc[t4], 0, 0, 0);
            }
        }

        // static-max softmax: p = mask * exp(s/8)
        float mk[4];
        #pragma unroll
        for (int t4 = 0; t4 < 4; ++t4) mk[t4] = ms[t * 64 + t4 * 16 + l15];
        #pragma unroll
        for (int t4 = 0; t4 < 4; ++t4)
            #pragma unroll
            for (int j = 0; j < 4; ++j)
                sacc[t4][j] = mk[t4] * __expf(sacc[t4][j] * 0.125f);
        #pragma unroll
        for (int j = 0; j < 4; ++j) {
            float ps = (sacc[0][j] + sacc[1][j]) + (sacc[2][j] + sacc[3][j]);
            ps += __shfl_xor(ps, 1);
            ps += __shfl_xor(ps, 2);
            ps += __shfl_xor(ps, 4);
            ps += __shfl_xor(ps, 8);
            lrun[j] += ps;
        }

        // P (bf16) -> per-wave LDS [16 q][64 kv], chunk-XOR swizzle
        #pragma unroll
        for (int t4 = 0; t4 < 4; ++t4) {
            #pragma unroll
            for (int j = 0; j < 4; ++j) {
                int qrow = lg * 4 + j;
                int kvh = t4 * 16 + l15;
                int phys = qrow * 64 + (kvh & 7) + ((((kvh >> 3) ^ (qrow & 7))) << 3);
                pw[phys] = f2bf(sacc[t4][j]);
            }
        }

        // PV: A = P[16 q][64 kv], B = Vs[dh][kv]; 2 k-steps x 4 dh-tiles
        #pragma unroll
        for (int s = 0; s < 2; ++s) {
            int c = (s * 4 + lg) ^ l7;
            short8 pa = *reinterpret_cast<const short8*>(&pw[l15 * 64 + c * 8]);
            #pragma unroll
            for (int dt = 0; dt < 4; ++dt) {
                int dh = dt * 16 + l15;
                short8 vb = *reinterpret_cast<const short8*>(
                    &Vs[cur][0] + dh * 64 + c * 8);
                oacc[dt] = __builtin_amdgcn_mfma_f32_16x16x32_bf16(pa, vb, oacc[dt], 0, 0, 0);
            }
        }

        __syncthreads();                     // buf[cur] free for stage(t+2)
        cur ^= 1;
        t = tn;
    }

    // epilogue: O[q][h*64+dh] = oacc / lrun, in place over Q
    float inv[4];
    #pragma unroll
    for (int j = 0; j < 4; ++j) inv[j] = 1.0f / lrun[j];
    #pragma unroll
    for (int t = 0; t < 4; ++t) {
        #pragma unroll
        for (int j = 0; j < 4; ++j) {
            size_t g = ((size_t)(b * SEQ + qbase + w * 16 + lg * 4 + j)) * DIM
                     + h * DHEAD + t * 16 + l15;
            QO[g] = f2bf(oacc[t][j] * inv[j]);
        }
    }
}

// ---------------- masked mean pool (reads bf16 hi/lo h') -------------------
__global__ __launch_bounds__(512)
void pool_kernel(const ushort* __restrict__ hh, const ushort* __restrict__ hl,
                 const float* __restrict__ maskA, float* __restrict__ pooled)
{
    int b  = blockIdx.x;
    int dq = blockIdx.y;
    int dl = threadIdx.x & 31;       // 32 d-pairs
    int sg = threadIdx.x >> 5;       // 0..15 s-group
    int d  = dq * 64 + dl * 2;
    float a0 = 0.f, a1 = 0.f, cnt = 0.f;
    for (int s = sg; s < SEQ; s += 16) {
        float mv = maskA[b * SEQ + s];
        if (mv == 0.f) continue;
        size_t idx = ((size_t)(b * SEQ + s)) * DIM + d;
        unsigned vh = *reinterpret_cast<const unsigned*>(&hh[idx]);
        unsigned vl = *reinterpret_cast<const unsigned*>(&hl[idx]);
        a0 += bf2f((ushort)(vh & 0xffff)) + bf2f((ushort)(vl & 0xffff));
        a1 += bf2f((ushort)(vh >> 16))    + bf2f((ushort)(vl >> 16));
        cnt += 1.f;
    }
    __shared__ float r0[16][32];
    __shared__ float r1[16][32];
    __shared__ float rc[16];
    r0[sg][dl] = a0;
    r1[sg][dl] = a1;
    if (dl == 0) rc[sg] = cnt;
    __syncthreads();
    if (sg == 0) {
        float t0 = 0.f, t1 = 0.f, c = 0.f;
        #pragma unroll
        for (int g = 0; g < 16; ++g) { t0 += r0[g][dl]; t1 += r1[g][dl]; c += rc[g]; }
        float invc = 1.0f / fmaxf(c, 1.f);
        pooled[b * DIM + d]     = t0 * invc;
        pooled[b * DIM + d + 1] = t1 * invc;
    }
}

// ---------------- pooled @ Wp + bp -> henc row b ---------------------------
__global__ __launch_bounds__(512)
void proj_kernel(const float* __restrict__ pooled, const float* __restrict__ Wp,
                 const float* __restrict__ bp, float* __restrict__ henc)
{
    int b = blockIdx.x;
    int j = threadIdx.x;
    __shared__ float p[DIM];
    p[j] = pooled[b * DIM + j];
    __syncthreads();
    float a0 = 0.f, a1 = 0.f, a2 = 0.f, a3 = 0.f;
    for (int d = 0; d < DIM; d += 4) {
        a0 += p[d]     * Wp[(size_t)d       * DIM + j];
        a1 += p[d + 1] * Wp[(size_t)(d + 1) * DIM + j];
        a2 += p[d + 2] * Wp[(size_t)(d + 2) * DIM + j];
        a3 += p[d + 3] * Wp[(size_t)(d + 3) * DIM + j];
    }
    henc[(size_t)b * DIM + j] = ((a0 + a1) + (a2 + a3)) + bp[j];
}

// ---------------- fused head: logits + softmax + argmax --------------------
// grid 32 blocks x 256 threads; logits stay in registers.
__global__ __launch_bounds__(256)
void head_kernel(const float* __restrict__ henc, const float* __restrict__ Wout,
                 const float* __restrict__ bout, float* __restrict__ out)
{
    int b   = blockIdx.x;
    int tid = threadIdx.x;
    __shared__ float hh[2 * DIM];
    __shared__ float red[256];
    __shared__ int   redi[256];
    for (int j = tid; j < DIM; j += 256) {
        hh[j]       = henc[(size_t)b * DIM + j];
        hh[DIM + j] = henc[(size_t)(BATCH + b) * DIM + j];
    }
    __syncthreads();

    float v[4];
    float mx = -INFINITY;
    #pragma unroll
    for (int i = 0; i < 4; ++i) {
        int m = tid + i * 256;
        if (m < MM) {
            float a0 = 0.f, a1 = 0.f, a2 = 0.f, a3 = 0.f;
            for (int j = 0; j < 2 * DIM; j += 4) {
                a0 += hh[j]     * Wout[(size_t)j       * MM + m];
                a1 += hh[j + 1] * Wout[(size_t)(j + 1) * MM + m];
                a2 += hh[j + 2] * Wout[(size_t)(j + 2) * MM + m];
                a3 += hh[j + 3] * Wout[(size_t)(j + 3) * MM + m];
            }
            v[i] = ((a0 + a1) + (a2 + a3)) + bout[m];
            mx = fmaxf(mx, v[i]);
        } else v[i] = -INFINITY;
    }
    red[tid] = mx; __syncthreads();
    for (int st = 128; st > 0; st >>= 1) {
        if (tid < st) red[tid] = fmaxf(red[tid], red[tid + st]);
        __syncthreads();
    }
    mx = red[0]; __syncthreads();

    float sum = 0.f;
    #pragma unroll
    for (int i = 0; i < 4; ++i) {
        int m = tid + i * 256;
        if (m < MM) { v[i] = expf(v[i] - mx); sum += v[i]; }
    }
    red[tid] = sum; __syncthreads();
    for (int st = 128; st > 0; st >>= 1) {
        if (tid < st) red[tid] += red[tid + st];
        __syncthreads();
    }
    float inv = 1.0f / red[0]; __syncthreads();

    float bestv = -INFINITY; int besti = 0x7fffffff;
    #pragma unroll
    for (int i = 0; i < 4; ++i) {
        int m = tid + i * 256;
        if (m < MM) {
            float lam = v[i] * inv;
            out[b * MM + m] = lam;
            if (lam > bestv) { bestv = lam; besti = m; }
        }
    }
    red[tid] = bestv; redi[tid] = besti; __syncthreads();
    for (int st = 128; st > 0; st >>= 1) {
        if (tid < st) {
            float ov = red[tid + st]; int oi = redi[tid + st];
            if (ov > red[tid] || (ov == red[tid] && oi < redi[tid])) {
                red[tid] = ov; redi[tid] = oi;
            }
        }
        __syncthreads();
    }
    if (tid == 0) out[BATCH * MM + b] = (float)redi[0];
}

// ---------------------------------------------------------------------------
extern "C" void kernel_launch(void* const* d_in, const int* in_sizes, int n_in,
                              void* d_out, int out_size, void* d_ws, size_t ws_size,
                              hipStream_t stream)
{
    const float* xH   = (const float*)d_in[0];
    const float* xF   = (const float*)d_in[1];
    const float* Wm   = (const float*)d_in[2];
    const float* Wt   = (const float*)d_in[3];
    const float* bt   = (const float*)d_in[4];
    const float* Wq   = (const float*)d_in[5];
    const float* Wk   = (const float*)d_in[6];
    const float* Wv   = (const float*)d_in[7];
    const float* Wo   = (const float*)d_in[8];
    const float* W1   = (const float*)d_in[9];
    const float* b1   = (const float*)d_in[10];
    const float* W2   = (const float*)d_in[11];
    const float* b2   = (const float*)d_in[12];
    const float* Wp   = (const float*)d_in[13];
    const float* bp   = (const float*)d_in[14];
    const float* Wout = (const float*)d_in[15];
    const float* bout = (const float*)d_in[16];
    float* out = (float*)d_out;

    float* ws     = (float*)d_ws;
    float*  WmT    = ws + OFF_WMT;
    float*  maskA  = ws + OFF_MASK;
    float*  pooled = ws + OFF_POOL;
    float*  henc   = ws + OFF_HENC;
    ushort* WqkvTh = (ushort*)(ws + OFF_WQTH);
    ushort* WoTh   = WqkvTh + (size_t)1536 * 512;
    ushort* W1Th   = (ushort*)(ws + OFF_W1TH);
    ushort* W2Th   = (ushort*)(ws + OFF_W2TH);
    ushort* ehi    = (ushort*)(ws + OFF_EHI);
    ushort* elo    = (ushort*)(ws + OFF_ELO);
    ushort* Qb     = (ushort*)(ws + OFF_QB);
    ushort* Kb     = (ushort*)(ws + OFF_KB);
    ushort* Vtb    = (ushort*)(ws + OFF_VB);
    ushort* rbuf   = (ushort*)(ws + OFF_VB);   // [32768][1024] over Vtb+R2

    // ---- fused setup ----
    setup_all<<<dim3(3584), 256, 0, stream>>>(
        Wm, Wq, Wk, Wv, Wo, W1, W2, WmT, WqkvTh, W1Th, W2Th);

    // ---- merged H+F pass ----
    embed_kernel<<<dim3(BROWS / 4), 256, 0, stream>>>(
        xH, xF, WmT, Wt, bt, ehi, elo, maskA);
    gemm_bf16<1,false,false,false,false,false,true><<<dim3(12, 256), 256, 0, stream>>>(
        ehi, nullptr, WqkvTh, nullptr, nullptr, nullptr, nullptr,
        Qb, Kb, Vtb, BROWS, 512, DIM, DIM, DIM, maskA);
    attn_mfma<<<dim3(NHEAD, BB, 4), 512, 0, stream>>>(Qb, Kb, Vtb, maskA);
    gemm_bf16<1,false,false,true,true,false,false><<<dim3(4, 256), 256, 0, stream>>>(
        Qb, nullptr, WoTh, nullptr, nullptr, ehi, elo,
        ehi, elo, nullptr, BROWS, DIM, DIM, DIM, DIM, maskA);
    for (int nc = 0; nc < 2; nc++) {
        gemm_bf16<1,true,true,false,false,false,false><<<dim3(8, 256), 256, 0, stream>>>(
            ehi, nullptr, W1Th + (size_t)nc * 1024 * DIM, nullptr,
            b1 + nc * 1024, nullptr, nullptr,
            rbuf, nullptr, nullptr, BROWS, 1024, DIM, DIM, DIM, maskA);
        if (nc == 0)
            gemm_bf16<1,true,false,true,true,false,false><<<dim3(4, 256), 256, 0, stream>>>(
                rbuf, nullptr, W2Th, nullptr, b2, ehi, elo,
                Qb, Kb, nullptr, BROWS, DIM, 1024, 1024, DFFN, maskA);
        else
            gemm_bf16<1,false,false,true,true,false,false><<<dim3(4, 256), 256, 0, stream>>>(
                rbuf, nullptr, W2Th + 1024, nullptr, nullptr, Qb, Kb,
                Qb, Kb, nullptr, BROWS, DIM, 1024, 1024, DFFN, maskA);
    }
    pool_kernel<<<dim3(BB, 8), 512, 0, stream>>>(Qb, Kb, maskA, pooled);
    proj_kernel<<<dim3(BB), 512, 0, stream>>>(pooled, Wp, bp, henc);
    head_kernel<<<dim3(BATCH), 256, 0, stream>>>(henc, Wout, bout, out);
}

// Round 20
// 406.864 us; speedup vs baseline: 1.2096x; 1.2096x over previous
//
#include <hip/hip_runtime.h>
#include <math.h>

// Problem constants
#define BATCH 32
#define BB    64     // merged batch: rows 0..31 = H, 32..63 = F
#define SEQ  512
#define DIM  512
#define MM   1000
#define NHEAD 8
#define DHEAD 64
#define DFFN 2048
#define BROWS (BB * SEQ)     // 32768 rows (both passes)

typedef __attribute__((ext_vector_type(8))) short short8;
typedef __attribute__((ext_vector_type(4))) float f32x4;

__device__ __forceinline__ ushort f2bf(float x) {
    unsigned u = __builtin_bit_cast(unsigned, x);
    unsigned r = (u + 0x7FFFu + ((u >> 16) & 1u)) >> 16;
    return (ushort)r;
}
__device__ __forceinline__ float bf2f(ushort h) {
    unsigned u = ((unsigned)h) << 16;
    return __builtin_bit_cast(float, u);
}

// async global->LDS, 16B per lane. LDS dest must be wave-uniform base
// (HW adds lane*16); global src is per-lane. [m97/m104 semantics]
#define GL2LDS(g, s) __builtin_amdgcn_global_load_lds( \
    (const __attribute__((address_space(1))) unsigned int*)(g), \
    (__attribute__((address_space(3))) unsigned int*)(s), 16, 0, 0)

// ---------------------------------------------------------------------------
// ws layout (float32-slot offsets) — total 52,559,872 slots = 210.2 MB
// (d_ws = 256 MiB). FFN dataflow (r11-13 invariant): ehi/elo hold pristine
// h for ALL W1 chunks; h' accumulates in Qb/Kb; rbuf spans Vtb+R2.
// ---------------------------------------------------------------------------
constexpr size_t OFF_WMT  = 0;         // fp32 [1000][512]
constexpr size_t OFF_MASK = 524288;    // fp32 [32768]
constexpr size_t OFF_POOL = 557056;    // fp32 [64][512]
constexpr size_t OFF_HENC = 589824;    // fp32 [64][512]
constexpr size_t OFF_LOG  = 622592;    // fp32 [32][1000]
constexpr size_t OFF_WQTH = 655360;    // bf16 [2048][512] concat Wq|Wk|Wv|Wo
constexpr size_t OFF_W1TH = 1179648;   // bf16 [2048][512]
constexpr size_t OFF_W2TH = 1703936;   // bf16 [512][2048]
constexpr size_t OFF_EHI  = 2228224;   // bf16 [32768][512]  e -> h (pristine)
constexpr size_t OFF_ELO  = 10616832;  // bf16 [32768][512]
constexpr size_t OFF_QB   = 19005440;  // bf16 Q -> O -> h'_hi
constexpr size_t OFF_KB   = 27394048;  // bf16 K -> h'_lo
constexpr size_t OFF_VB   = 35782656;  // bf16 V^T [b][512][512]; + R2 ->
                                       //   rbuf [32768][1024]

// ---------------- fused setup: WmT + WqkvT + W1T + W2T ---------------------
// grid 3584 x 256: [0,512) transpose_wm, [512,1536) split_wT4,
// [1536,2560) W1 (K=512,N=2048), [2560,3584) W2 (K=2048,N=512).
__global__ __launch_bounds__(256)
void setup_all(const float* __restrict__ Wm,
               const float* __restrict__ Wq, const float* __restrict__ Wk,
               const float* __restrict__ Wv, const float* __restrict__ Wo,
               const float* __restrict__ W1, const float* __restrict__ W2,
               float* __restrict__ WmT, ushort* __restrict__ WqkvTh,
               ushort* __restrict__ W1Th, ushort* __restrict__ W2Th)
{
    __shared__ float tile[32][33];
    const int bid = blockIdx.x;
    const int tx = threadIdx.x & 31;
    const int ty = threadIdx.x >> 5;
    if (bid < 512) {                         // W_m [512,1000] -> [1000,512] f32
        int mx = (bid & 31) * 32, dy = (bid >> 5) * 32;
        for (int i = ty; i < 32; i += 8) {
            int d = dy + i, m = mx + tx;
            tile[i][tx] = (m < MM) ? Wm[(size_t)d * MM + m] : 0.f;
        }
        __syncthreads();
        for (int i = ty; i < 32; i += 8) {
            int m = mx + i, d = dy + tx;
            if (m < MM) WmT[(size_t)m * DIM + d] = tile[tx][i];
        }
    } else if (bid < 1536) {                 // Wq|Wk|Wv|Wo -> [2048][512] bf16
        int id = bid - 512;
        int n0 = (id & 63) * 32, k0 = (id >> 6) * 32;
        const float* W = (n0 < 512) ? Wq : (n0 < 1024) ? Wk
                       : (n0 < 1536) ? Wv : Wo;
        int nc = n0 & 511;
        for (int i = ty; i < 32; i += 8)
            tile[i][tx] = W[(size_t)(k0 + i) * 512 + nc + tx];
        __syncthreads();
        for (int i = ty; i < 32; i += 8)
            WqkvTh[(size_t)(n0 + i) * 512 + k0 + tx] = f2bf(tile[tx][i]);
    } else if (bid < 2560) {                 // W1 [512,2048] -> [2048][512]
        int id = bid - 1536;
        int n0 = (id & 63) * 32, k0 = (id >> 6) * 32;
        for (int i = ty; i < 32; i += 8)
            tile[i][tx] = W1[(size_t)(k0 + i) * DFFN + n0 + tx];
        __syncthreads();
        for (int i = ty; i < 32; i += 8)
            W1Th[(size_t)(n0 + i) * DIM + k0 + tx] = f2bf(tile[tx][i]);
    } else {                                 // W2 [2048,512] -> [512][2048]
        int id = bid - 2560;
        int n0 = (id & 15) * 32, k0 = (id >> 4) * 32;
        for (int i = ty; i < 32; i += 8)
            tile[i][tx] = W2[(size_t)(k0 + i) * DIM + n0 + tx];
        __syncthreads();
        for (int i = ty; i < 32; i += 8)
            W2Th[(size_t)(n0 + i) * DFFN + k0 + tx] = f2bf(tile[tx][i]);
    }
}

// ---------------- embedding + mask -> e_hi/e_lo bf16 (both passes) ---------
__global__ __launch_bounds__(256)
void embed_kernel(const float* __restrict__ xH, const float* __restrict__ xF,
                  const float* __restrict__ WmT, const float* __restrict__ Wt,
                  const float* __restrict__ bt,
                  ushort* __restrict__ ehi, ushort* __restrict__ elo,
                  float* __restrict__ maskA)
{
    int sub  = threadIdx.x >> 6;          // 0..3
    int lane = threadIdx.x & 63;          // 0..63
    int bs   = blockIdx.x * 4 + sub;      // 0..32767
    const float* xp = (bs < BATCH * SEQ) ? (xH + (size_t)bs * 2)
                                         : (xF + (size_t)(bs - BATCH * SEQ) * 2);
    float t   = xp[0];
    float mkf = xp[1];
    int   mk  = (int)fminf(fmaxf(mkf, 0.f), (float)(MM - 1));
    bool  valid = (t >= 0.f);
    if (lane == 0) maskA[bs] = valid ? 1.f : 0.f;
    const float* wrow = WmT + (size_t)mk * DIM + lane * 8;
    float4 w0 = *reinterpret_cast<const float4*>(wrow);
    float4 w1 = *reinterpret_cast<const float4*>(wrow + 4);
    float4 t0 = *reinterpret_cast<const float4*>(Wt + lane * 8);
    float4 t1 = *reinterpret_cast<const float4*>(Wt + lane * 8 + 4);
    float4 b0 = *reinterpret_cast<const float4*>(bt + lane * 8);
    float4 b1 = *reinterpret_cast<const float4*>(bt + lane * 8 + 4);
    float v[8];
    v[0] = w0.x * 0.5f + 0.5f * (t0.x * t + b0.x);
    v[1] = w0.y * 0.5f + 0.5f * (t0.y * t + b0.y);
    v[2] = w0.z * 0.5f + 0.5f * (t0.z * t + b0.z);
    v[3] = w0.w * 0.5f + 0.5f * (t0.w * t + b0.w);
    v[4] = w1.x * 0.5f + 0.5f * (t1.x * t + b1.x);
    v[5] = w1.y * 0.5f + 0.5f * (t1.y * t + b1.y);
    v[6] = w1.z * 0.5f + 0.5f * (t1.z * t + b1.z);
    v[7] = w1.w * 0.5f + 0.5f * (t1.w * t + b1.w);
    union { uint4 u; ushort s[8]; } ph, pl;
    #pragma unroll
    for (int j = 0; j < 8; ++j) {
        float vv = valid ? v[j] : 0.f;
        ushort h = f2bf(vv);
        ph.s[j] = h;
        pl.s[j] = f2bf(vv - bf2f(h));
    }
    size_t base = (size_t)bs * DIM + lane * 8;
    *reinterpret_cast<uint4*>(ehi + base) = ph.u;
    *reinterpret_cast<uint4*>(elo + base) = pl.u;
}

// ---------------- bf16 MFMA GEMM, 128x128 tile, 2-phase dbuf ---------------
// (unchanged — proven)
template<int SEGS, bool BIAS, bool RELU, bool RES, bool PAIR, bool TOUT, bool TRIPLE>
__global__ __launch_bounds__(256)
void gemm_bf16(const ushort* __restrict__ A0, const ushort* __restrict__ A1,
               const ushort* __restrict__ B0, const ushort* __restrict__ B1,
               const float* __restrict__ bias,
               const ushort* __restrict__ Rh, const ushort* __restrict__ Rl,
               ushort* __restrict__ Oh, ushort* __restrict__ Ol,
               ushort* __restrict__ Ot,
               int Md, int Nd, int Kd, int lda, int ldb,
               const float* __restrict__ mrow)
{
    __shared__ __align__(16) ushort As[2][128 * 64];
    __shared__ __align__(16) ushort Bs[2][128 * 64];
    const int tid = threadIdx.x;
    const int w = tid >> 6, l = tid & 63;
    const int wr = w >> 1, wc = w & 1;
    const int l15 = l & 15, lg = l >> 4;
    const int id  = blockIdx.x + gridDim.x * blockIdx.y;
    const int nwg = gridDim.x * gridDim.y;
    const int qc  = nwg >> 3;
    const int lin = (id & 7) * qc + (id >> 3);
    const int row0 = (lin / gridDim.x) * 128;
    const int col0 = (lin % gridDim.x) * 128;
    const int lrow   = l >> 3;
    const int gchunk = (l & 7) ^ lrow;

    if (mrow) {
        float mv = (tid < 128) ? mrow[row0 + tid] : 0.f;
        if (!__syncthreads_or(mv != 0.f)) return;
    }

    f32x4 acc[4][4];
    #pragma unroll
    for (int m = 0; m < 4; m++)
        #pragma unroll
        for (int n = 0; n < 4; n++)
            acc[m][n] = (f32x4){0.f, 0.f, 0.f, 0.f};

    const int NT = SEGS * (Kd >> 6);
    int sseg = 0, skt = 0;

    auto stage = [&](int bi) {
        const ushort* Ap = (sseg == 1) ? A1 : A0;
        const ushort* Bp = (sseg == 2) ? B1 : B0;
        ushort* Asb = &As[bi][0];
        ushort* Bsb = &Bs[bi][0];
        #pragma unroll
        for (int r = 0; r < 4; ++r) {
            int rowb = w * 32 + r * 8;
            int row  = rowb + lrow;
            GL2LDS(Ap + (size_t)(row0 + row) * lda + skt + gchunk * 8,
                   Asb + rowb * 64);
            GL2LDS(Bp + (size_t)(col0 + row) * ldb + skt + gchunk * 8,
                   Bsb + rowb * 64);
        }
        skt += 64;
        if (skt == Kd) { skt = 0; ++sseg; }
    };

    stage(0);
    __syncthreads();

    for (int t = 0; t < NT; ++t) {
        const int cur = t & 1;
        if (t + 1 < NT) stage(cur ^ 1);
        const char* AsB = (const char*)&As[cur][0];
        const char* BsB = (const char*)&Bs[cur][0];
        #pragma unroll
        for (int ks = 0; ks < 2; ++ks) {
            const int g = ks * 4 + lg;
            short8 af[4], bfr[4];
            #pragma unroll
            for (int m = 0; m < 4; ++m) {
                int row = wr * 64 + m * 16 + l15;
                af[m] = *reinterpret_cast<const short8*>(
                    AsB + row * 128 + ((g ^ (row & 7)) << 4));
            }
            #pragma unroll
            for (int n = 0; n < 4; ++n) {
                int row = wc * 64 + n * 16 + l15;
                bfr[n] = *reinterpret_cast<const short8*>(
                    BsB + row * 128 + ((g ^ (row & 7)) << 4));
            }
            #pragma unroll
            for (int m = 0; m < 4; ++m)
                #pragma unroll
                for (int n = 0; n < 4; ++n)
                    acc[m][n] = __builtin_amdgcn_mfma_f32_16x16x32_bf16(
                        af[m], bfr[n], acc[m][n], 0, 0, 0);
        }
        __syncthreads();
    }

    #pragma unroll
    for (int m = 0; m < 4; ++m) {
        #pragma unroll
        for (int n = 0; n < 4; ++n) {
            int col = col0 + wc * 64 + n * 16 + l15;
            if (TRIPLE) {
                if (col0 < 512) {
                    #pragma unroll
                    for (int j = 0; j < 4; ++j) {
                        int row = row0 + wr * 64 + m * 16 + lg * 4 + j;
                        Oh[(size_t)row * 512 + col] = f2bf(acc[m][n][j]);
                    }
                } else if (col0 < 1024) {
                    #pragma unroll
                    for (int j = 0; j < 4; ++j) {
                        int row = row0 + wr * 64 + m * 16 + lg * 4 + j;
                        Ol[(size_t)row * 512 + (col - 512)] = f2bf(acc[m][n][j]);
                    }
                } else {
                    union { uint2 u; ushort s4[4]; } pk;
                    #pragma unroll
                    for (int j = 0; j < 4; ++j) pk.s4[j] = f2bf(acc[m][n][j]);
                    int brow = row0 + wr * 64 + m * 16 + lg * 4;
                    size_t idx = ((size_t)(brow >> 9) << 18)
                               + (size_t)(col - 1024) * SEQ + (brow & 511);
                    *reinterpret_cast<uint2*>(Ot + idx) = pk.u;
                }
            } else if (TOUT) {
                union { uint2 u; ushort s4[4]; } pk;
                #pragma unroll
                for (int j = 0; j < 4; ++j) pk.s4[j] = f2bf(acc[m][n][j]);
                int brow = row0 + wr * 64 + m * 16 + lg * 4;
                size_t idx = ((size_t)(brow >> 9) << 18) + (size_t)col * SEQ + (brow & 511);
                *reinterpret_cast<uint2*>(Oh + idx) = pk.u;
            } else {
                float bia = 0.f;
                if (BIAS) bia = bias[col];
                #pragma unroll
                for (int j = 0; j < 4; ++j) {
                    int row = row0 + wr * 64 + m * 16 + lg * 4 + j;
                    size_t idx = (size_t)row * Nd + col;
                    float v = acc[m][n][j] + bia;
                    if (RES)  v += bf2f(Rh[idx]) + bf2f(Rl[idx]);
                    if (RELU) v = fmaxf(v, 0.f);
                    ushort hv = f2bf(v);
                    Oh[idx] = hv;
                    if (PAIR) Ol[idx] = f2bf(v - bf2f(hv));
                }
            }
        }
    }
}

// ---------------- MFMA flash attention, 128 q-rows, KV dbuf, static-max ----
// (unchanged from r19 — the dbuf pipeline that cut attn ~76 -> ~25-30 us)
__global__ __launch_bounds__(512)
void attn_mfma(ushort* __restrict__ QO, const ushort* __restrict__ K,
               const ushort* __restrict__ Vt, const float* __restrict__ maskA)
{
    __shared__ __align__(16) ushort Ks[2][64 * 64];   // [buf][kv][dh]
    __shared__ __align__(16) ushort Vs[2][64 * 64];   // [buf][dh][kv]
    __shared__ __align__(16) ushort Pl[8][16 * 64];   // [wave][q][kv] (Q alias)
    __shared__ float ms[512];
    const int h   = blockIdx.x;
    const int b   = blockIdx.y;
    const int qt  = blockIdx.z;
    const int tid = threadIdx.x;
    const int w = tid >> 6, l = tid & 63;
    const int l15 = l & 15, lg = l >> 4, l7 = l & 7;
    const int lrow   = l >> 3;
    const int gchunk = (l & 7) ^ lrow;
    const int qbase = qt * 128;

    // stage Q tile [128 q][64 dh] into Pl (dead until first P write)
    #pragma unroll
    for (int rr = 0; rr < 2; ++rr) {
        int rowb = rr * 64 + w * 8;             // 16 stripes, wave-uniform
        GL2LDS(QO + ((size_t)(b * SEQ + qbase + rowb + lrow)) * DIM
                  + h * DHEAD + gchunk * 8,
               &Pl[0][0] + rowb * 64);
    }
    // full mask row -> LDS (published by the q-skip barrier below)
    ms[tid] = maskA[b * SEQ + tid];
    // dead q-tile skip (global reads; barrier also drains Q-stage + ms)
    float qm = (tid < 128) ? maskA[b * SEQ + qbase + tid] : 0.f;
    if (!__syncthreads_or(qm != 0.f)) return;

    // per-64-kv-tile valid bits (block-uniform)
    unsigned hbits = 0;
    #pragma unroll
    for (int t = 0; t < 8; ++t) {
        int mine = (tid < 64) ? (ms[t * 64 + tid] != 0.f) : 0;
        if (__syncthreads_or(mine)) hbits |= (1u << t);
    }

    // hoist Q A-frags (reads Pl BEFORE any P write); wave w rows w*16+l15
    short8 af[2];
    #pragma unroll
    for (int s = 0; s < 2; ++s) {
        int q = w * 16 + l15;
        int c = (s * 4 + lg) ^ l7;
        af[s] = *reinterpret_cast<const short8*>(&Pl[0][0] + q * 64 + c * 8);
    }

    f32x4 oacc[4];
    #pragma unroll
    for (int t = 0; t < 4; ++t) oacc[t] = (f32x4){0.f, 0.f, 0.f, 0.f};
    float lrun[4];
    #pragma unroll
    for (int j = 0; j < 4; ++j) lrun[j] = 0.f;

    ushort* pw = &Pl[w][0];

    auto stagekv = [&](int t, int bi) {
        int kv0 = t * 64;
        GL2LDS(K + ((size_t)(b * SEQ + kv0 + w * 8 + lrow)) * DIM
                 + h * DHEAD + gchunk * 8,
               &Ks[bi][0] + w * 8 * 64);
        GL2LDS(Vt + ((size_t)b << 18) + (size_t)(h * DHEAD + w * 8 + lrow) * SEQ
                  + kv0 + gchunk * 8,
               &Vs[bi][0] + w * 8 * 64);
    };

    int t0 = 0;
    while (t0 < 8 && !(hbits & (1u << t0))) ++t0;
    stagekv(t0, 0);
    __syncthreads();                         // tile t0 K/V ready
    int cur = 0;
    for (int t = t0; t < 8; ) {
        int tn = t + 1;
        while (tn < 8 && !(hbits & (1u << tn))) ++tn;
        if (tn < 8) stagekv(tn, cur ^ 1);    // async prefetch next valid tile

        // QK^T: 4 kv16-tiles x 2 k-steps
        f32x4 sacc[4];
        #pragma unroll
        for (int t4 = 0; t4 < 4; ++t4) sacc[t4] = (f32x4){0.f, 0.f, 0.f, 0.f};
        #pragma unroll
        for (int s = 0; s < 2; ++s) {
            int c = (s * 4 + lg) ^ l7;
            #pragma unroll
            for (int t4 = 0; t4 < 4; ++t4) {
                int kv = t4 * 16 + l15;
                short8 bf = *reinterpret_cast<const short8*>(
                    &Ks[cur][0] + kv * 64 + c * 8);
                sacc[t4] = __builtin_amdgcn_mfma_f32_16x16x32_bf16(af[s], bf, sacc[t4], 0, 0, 0);
            }
        }

        // static-max softmax: p = mask * exp(s/8)
        float mk[4];
        #pragma unroll
        for (int t4 = 0; t4 < 4; ++t4) mk[t4] = ms[t * 64 + t4 * 16 + l15];
        #pragma unroll
        for (int t4 = 0; t4 < 4; ++t4)
            #pragma unroll
            for (int j = 0; j < 4; ++j)
                sacc[t4][j] = mk[t4] * __expf(sacc[t4][j] * 0.125f);
        #pragma unroll
        for (int j = 0; j < 4; ++j) {
            float ps = (sacc[0][j] + sacc[1][j]) + (sacc[2][j] + sacc[3][j]);
            ps += __shfl_xor(ps, 1);
            ps += __shfl_xor(ps, 2);
            ps += __shfl_xor(ps, 4);
            ps += __shfl_xor(ps, 8);
            lrun[j] += ps;
        }

        // P (bf16) -> per-wave LDS [16 q][64 kv], chunk-XOR swizzle
        #pragma unroll
        for (int t4 = 0; t4 < 4; ++t4) {
            #pragma unroll
            for (int j = 0; j < 4; ++j) {
                int qrow = lg * 4 + j;
                int kvh = t4 * 16 + l15;
                int phys = qrow * 64 + (kvh & 7) + ((((kvh >> 3) ^ (qrow & 7))) << 3);
                pw[phys] = f2bf(sacc[t4][j]);
            }
        }

        // PV: A = P[16 q][64 kv], B = Vs[dh][kv]; 2 k-steps x 4 dh-tiles
        #pragma unroll
        for (int s = 0; s < 2; ++s) {
            int c = (s * 4 + lg) ^ l7;
            short8 pa = *reinterpret_cast<const short8*>(&pw[l15 * 64 + c * 8]);
            #pragma unroll
            for (int dt = 0; dt < 4; ++dt) {
                int dh = dt * 16 + l15;
                short8 vb = *reinterpret_cast<const short8*>(
                    &Vs[cur][0] + dh * 64 + c * 8);
                oacc[dt] = __builtin_amdgcn_mfma_f32_16x16x32_bf16(pa, vb, oacc[dt], 0, 0, 0);
            }
        }

        __syncthreads();                     // buf[cur] free for stage(t+2)
        cur ^= 1;
        t = tn;
    }

    // epilogue: O[q][h*64+dh] = oacc / lrun, in place over Q
    float inv[4];
    #pragma unroll
    for (int j = 0; j < 4; ++j) inv[j] = 1.0f / lrun[j];
    #pragma unroll
    for (int t = 0; t < 4; ++t) {
        #pragma unroll
        for (int j = 0; j < 4; ++j) {
            size_t g = ((size_t)(b * SEQ + qbase + w * 16 + lg * 4 + j)) * DIM
                     + h * DHEAD + t * 16 + l15;
            QO[g] = f2bf(oacc[t][j] * inv[j]);
        }
    }
}

// ---------------- masked mean pool (reads bf16 hi/lo h') -------------------
__global__ __launch_bounds__(512)
void pool_kernel(const ushort* __restrict__ hh, const ushort* __restrict__ hl,
                 const float* __restrict__ maskA, float* __restrict__ pooled)
{
    int b  = blockIdx.x;
    int dq = blockIdx.y;
    int dl = threadIdx.x & 31;       // 32 d-pairs
    int sg = threadIdx.x >> 5;       // 0..15 s-group
    int d  = dq * 64 + dl * 2;
    float a0 = 0.f, a1 = 0.f, cnt = 0.f;
    for (int s = sg; s < SEQ; s += 16) {
        float mv = maskA[b * SEQ + s];
        if (mv == 0.f) continue;
        size_t idx = ((size_t)(b * SEQ + s)) * DIM + d;
        unsigned vh = *reinterpret_cast<const unsigned*>(&hh[idx]);
        unsigned vl = *reinterpret_cast<const unsigned*>(&hl[idx]);
        a0 += bf2f((ushort)(vh & 0xffff)) + bf2f((ushort)(vl & 0xffff));
        a1 += bf2f((ushort)(vh >> 16))    + bf2f((ushort)(vl >> 16));
        cnt += 1.f;
    }
    __shared__ float r0[16][32];
    __shared__ float r1[16][32];
    __shared__ float rc[16];
    r0[sg][dl] = a0;
    r1[sg][dl] = a1;
    if (dl == 0) rc[sg] = cnt;
    __syncthreads();
    if (sg == 0) {
        float t0 = 0.f, t1 = 0.f, c = 0.f;
        #pragma unroll
        for (int g = 0; g < 16; ++g) { t0 += r0[g][dl]; t1 += r1[g][dl]; c += rc[g]; }
        float invc = 1.0f / fmaxf(c, 1.f);
        pooled[b * DIM + d]     = t0 * invc;
        pooled[b * DIM + d + 1] = t1 * invc;
    }
}

// ---------------- pooled @ Wp + bp -> henc row b ---------------------------
__global__ __launch_bounds__(512)
void proj_kernel(const float* __restrict__ pooled, const float* __restrict__ Wp,
                 const float* __restrict__ bp, float* __restrict__ henc)
{
    int b = blockIdx.x;
    int j = threadIdx.x;
    __shared__ float p[DIM];
    p[j] = pooled[b * DIM + j];
    __syncthreads();
    float a0 = 0.f, a1 = 0.f, a2 = 0.f, a3 = 0.f;
    for (int d = 0; d < DIM; d += 4) {
        a0 += p[d]     * Wp[(size_t)d       * DIM + j];
        a1 += p[d + 1] * Wp[(size_t)(d + 1) * DIM + j];
        a2 += p[d + 2] * Wp[(size_t)(d + 2) * DIM + j];
        a3 += p[d + 3] * Wp[(size_t)(d + 3) * DIM + j];
    }
    henc[(size_t)b * DIM + j] = ((a0 + a1) + (a2 + a3)) + bp[j];
}

// ---------------- logits = concat(hH,hF) @ W_out + b_out -------------------
__global__ __launch_bounds__(256)
void logits_kernel(const float* __restrict__ henc, const float* __restrict__ Wout,
                   const float* __restrict__ bout, float* __restrict__ logits)
{
    int b = blockIdx.y;
    int m = blockIdx.x * 256 + threadIdx.x;
    __shared__ float hh[2 * DIM];
    for (int j = threadIdx.x; j < DIM; j += 256) {
        hh[j]       = henc[(size_t)b * DIM + j];
        hh[DIM + j] = henc[(size_t)(BATCH + b) * DIM + j];
    }
    __syncthreads();
    if (m < MM) {
        float a0 = 0.f, a1 = 0.f, a2 = 0.f, a3 = 0.f;
        for (int j = 0; j < 2 * DIM; j += 4) {
            a0 += hh[j]     * Wout[(size_t)j       * MM + m];
            a1 += hh[j + 1] * Wout[(size_t)(j + 1) * MM + m];
            a2 += hh[j + 2] * Wout[(size_t)(j + 2) * MM + m];
            a3 += hh[j + 3] * Wout[(size_t)(j + 3) * MM + m];
        }
        logits[b * MM + m] = ((a0 + a1) + (a2 + a3)) + bout[m];
    }
}

// ---------------- softmax + argmax ----------------
__global__ __launch_bounds__(256)
void smax_kernel(const float* __restrict__ logits, float* __restrict__ out)
{
    int b   = blockIdx.x;
    int tid = threadIdx.x;
    __shared__ float red[256];
    __shared__ int   redi[256];

    float v[4];
    float mx = -INFINITY;
    #pragma unroll
    for (int i = 0; i < 4; i++) {
        int m = tid + i * 256;
        if (m < MM) { v[i] = logits[b * MM + m]; mx = fmaxf(mx, v[i]); }
        else v[i] = -INFINITY;
    }
    red[tid] = mx; __syncthreads();
    for (int st = 128; st > 0; st >>= 1) {
        if (tid < st) red[tid] = fmaxf(red[tid], red[tid + st]);
        __syncthreads();
    }
    mx = red[0]; __syncthreads();

    float sum = 0.f;
    #pragma unroll
    for (int i = 0; i < 4; i++) {
        int m = tid + i * 256;
        if (m < MM) { v[i] = expf(v[i] - mx); sum += v[i]; }
    }
    red[tid] = sum; __syncthreads();
    for (int st = 128; st > 0; st >>= 1) {
        if (tid < st) red[tid] += red[tid + st];
        __syncthreads();
    }
    float inv = 1.0f / red[0]; __syncthreads();

    float bestv = -INFINITY; int besti = 0x7fffffff;
    #pragma unroll
    for (int i = 0; i < 4; i++) {
        int m = tid + i * 256;
        if (m < MM) {
            float lam = v[i] * inv;
            out[b * MM + m] = lam;
            if (lam > bestv) { bestv = lam; besti = m; }
        }
    }
    red[tid] = bestv; redi[tid] = besti; __syncthreads();
    for (int st = 128; st > 0; st >>= 1) {
        if (tid < st) {
            float ov = red[tid + st]; int oi = redi[tid + st];
            if (ov > red[tid] || (ov == red[tid] && oi < redi[tid])) {
                red[tid] = ov; redi[tid] = oi;
            }
        }
        __syncthreads();
    }
    if (tid == 0) out[BATCH * MM + b] = (float)redi[0];
}

// ---------------------------------------------------------------------------
extern "C" void kernel_launch(void* const* d_in, const int* in_sizes, int n_in,
                              void* d_out, int out_size, void* d_ws, size_t ws_size,
                              hipStream_t stream)
{
    const float* xH   = (const float*)d_in[0];
    const float* xF   = (const float*)d_in[1];
    const float* Wm   = (const float*)d_in[2];
    const float* Wt   = (const float*)d_in[3];
    const float* bt   = (const float*)d_in[4];
    const float* Wq   = (const float*)d_in[5];
    const float* Wk   = (const float*)d_in[6];
    const float* Wv   = (const float*)d_in[7];
    const float* Wo   = (const float*)d_in[8];
    const float* W1   = (const float*)d_in[9];
    const float* b1   = (const float*)d_in[10];
    const float* W2   = (const float*)d_in[11];
    const float* b2   = (const float*)d_in[12];
    const float* Wp   = (const float*)d_in[13];
    const float* bp   = (const float*)d_in[14];
    const float* Wout = (const float*)d_in[15];
    const float* bout = (const float*)d_in[16];
    float* out = (float*)d_out;

    float* ws     = (float*)d_ws;
    float*  WmT    = ws + OFF_WMT;
    float*  maskA  = ws + OFF_MASK;
    float*  pooled = ws + OFF_POOL;
    float*  henc   = ws + OFF_HENC;
    float*  logits = ws + OFF_LOG;
    ushort* WqkvTh = (ushort*)(ws + OFF_WQTH);
    ushort* WoTh   = WqkvTh + (size_t)1536 * 512;
    ushort* W1Th   = (ushort*)(ws + OFF_W1TH);
    ushort* W2Th   = (ushort*)(ws + OFF_W2TH);
    ushort* ehi    = (ushort*)(ws + OFF_EHI);
    ushort* elo    = (ushort*)(ws + OFF_ELO);
    ushort* Qb     = (ushort*)(ws + OFF_QB);
    ushort* Kb     = (ushort*)(ws + OFF_KB);
    ushort* Vtb    = (ushort*)(ws + OFF_VB);
    ushort* rbuf   = (ushort*)(ws + OFF_VB);   // [32768][1024] over Vtb+R2

    // ---- fused setup ----
    setup_all<<<dim3(3584), 256, 0, stream>>>(
        Wm, Wq, Wk, Wv, Wo, W1, W2, WmT, WqkvTh, W1Th, W2Th);

    // ---- merged H+F pass ----
    embed_kernel<<<dim3(BROWS / 4), 256, 0, stream>>>(
        xH, xF, WmT, Wt, bt, ehi, elo, maskA);
    gemm_bf16<1,false,false,false,false,false,true><<<dim3(12, 256), 256, 0, stream>>>(
        ehi, nullptr, WqkvTh, nullptr, nullptr, nullptr, nullptr,
        Qb, Kb, Vtb, BROWS, 512, DIM, DIM, DIM, maskA);
    attn_mfma<<<dim3(NHEAD, BB, 4), 512, 0, stream>>>(Qb, Kb, Vtb, maskA);
    gemm_bf16<1,false,false,true,true,false,false><<<dim3(4, 256), 256, 0, stream>>>(
        Qb, nullptr, WoTh, nullptr, nullptr, ehi, elo,
        ehi, elo, nullptr, BROWS, DIM, DIM, DIM, DIM, maskA);
    for (int nc = 0; nc < 2; nc++) {
        gemm_bf16<1,true,true,false,false,false,false><<<dim3(8, 256), 256, 0, stream>>>(
            ehi, nullptr, W1Th + (size_t)nc * 1024 * DIM, nullptr,
            b1 + nc * 1024, nullptr, nullptr,
            rbuf, nullptr, nullptr, BROWS, 1024, DIM, DIM, DIM, maskA);
        if (nc == 0)
            gemm_bf16<1,true,false,true,true,false,false><<<dim3(4, 256), 256, 0, stream>>>(
                rbuf, nullptr, W2Th, nullptr, b2, ehi, elo,
                Qb, Kb, nullptr, BROWS, DIM, 1024, 1024, DFFN, maskA);
        else
            gemm_bf16<1,false,false,true,true,false,false><<<dim3(4, 256), 256, 0, stream>>>(
                rbuf, nullptr, W2Th + 1024, nullptr, nullptr, Qb, Kb,
                Qb, Kb, nullptr, BROWS, DIM, 1024, 1024, DFFN, maskA);
    }
    pool_kernel<<<dim3(BB, 8), 512, 0, stream>>>(Qb, Kb, maskA, pooled);
    proj_kernel<<<dim3(BB), 512, 0, stream>>>(pooled, Wp, bp, henc);
    logits_kernel<<<dim3(4, BATCH), 256, 0, stream>>>(henc, Wout, bout, logits);
    smax_kernel<<<dim3(BATCH), 256, 0, stream>>>(logits, out);
}

// Round 21
// 396.531 us; speedup vs baseline: 1.2411x; 1.0261x over previous
//
#include <hip/hip_runtime.h>
#include <math.h>

// Problem constants
#define BATCH 32
#define BB    64     // merged batch: rows 0..31 = H, 32..63 = F
#define SEQ  512
#define DIM  512
#define MM   1000
#define NHEAD 8
#define DHEAD 64
#define DFFN 2048
#define BROWS (BB * SEQ)     // 32768 rows (both passes)

typedef __attribute__((ext_vector_type(8))) short short8;
typedef __attribute__((ext_vector_type(4))) float f32x4;

__device__ __forceinline__ ushort f2bf(float x) {
    unsigned u = __builtin_bit_cast(unsigned, x);
    unsigned r = (u + 0x7FFFu + ((u >> 16) & 1u)) >> 16;
    return (ushort)r;
}
__device__ __forceinline__ float bf2f(ushort h) {
    unsigned u = ((unsigned)h) << 16;
    return __builtin_bit_cast(float, u);
}
// packed f32x2 -> bf16x2 (RTNE), D[15:0]=bf16(lo), D[31:16]=bf16(hi)
__device__ __forceinline__ unsigned cvtpk_bf16(float lo, float hi) {
    unsigned r;
    asm volatile("v_cvt_pk_bf16_f32 %0, %1, %2" : "=v"(r) : "v"(lo), "v"(hi));
    return r;
}

// async global->LDS, 16B per lane. LDS dest must be wave-uniform base
// (HW adds lane*16); global src is per-lane. [m97/m104 semantics]
#define GL2LDS(g, s) __builtin_amdgcn_global_load_lds( \
    (const __attribute__((address_space(1))) unsigned int*)(g), \
    (__attribute__((address_space(3))) unsigned int*)(s), 16, 0, 0)

// ---------------------------------------------------------------------------
// ws layout (float32-slot offsets) — total 52,559,872 slots = 210.2 MB
// (d_ws = 256 MiB). FFN dataflow (r11-13 invariant): ehi/elo hold pristine
// h for ALL W1 chunks; h' accumulates in Qb/Kb; rbuf spans Vtb+R2.
// ---------------------------------------------------------------------------
constexpr size_t OFF_WMT  = 0;         // fp32 [1000][512]
constexpr size_t OFF_MASK = 524288;    // fp32 [32768]
constexpr size_t OFF_POOL = 557056;    // fp32 [64][512]
constexpr size_t OFF_HENC = 589824;    // fp32 [64][512]
constexpr size_t OFF_LOG  = 622592;    // fp32 [32][1000]
constexpr size_t OFF_WQTH = 655360;    // bf16 [2048][512] concat Wq|Wk|Wv|Wo
constexpr size_t OFF_W1TH = 1179648;   // bf16 [2048][512]
constexpr size_t OFF_W2TH = 1703936;   // bf16 [512][2048]
constexpr size_t OFF_EHI  = 2228224;   // bf16 [32768][512]  e -> h (pristine)
constexpr size_t OFF_ELO  = 10616832;  // bf16 [32768][512]
constexpr size_t OFF_QB   = 19005440;  // bf16 Q -> O -> h'_hi
constexpr size_t OFF_KB   = 27394048;  // bf16 K -> h'_lo
constexpr size_t OFF_VB   = 35782656;  // bf16 V^T [b][512][512]; + R2 ->
                                       //   rbuf [32768][1024]

// ---------------- fused setup: WmT + WqkvT + W1T + W2T ---------------------
__global__ __launch_bounds__(256)
void setup_all(const float* __restrict__ Wm,
               const float* __restrict__ Wq, const float* __restrict__ Wk,
               const float* __restrict__ Wv, const float* __restrict__ Wo,
               const float* __restrict__ W1, const float* __restrict__ W2,
               float* __restrict__ WmT, ushort* __restrict__ WqkvTh,
               ushort* __restrict__ W1Th, ushort* __restrict__ W2Th)
{
    __shared__ float tile[32][33];
    const int bid = blockIdx.x;
    const int tx = threadIdx.x & 31;
    const int ty = threadIdx.x >> 5;
    if (bid < 512) {                         // W_m [512,1000] -> [1000,512] f32
        int mx = (bid & 31) * 32, dy = (bid >> 5) * 32;
        for (int i = ty; i < 32; i += 8) {
            int d = dy + i, m = mx + tx;
            tile[i][tx] = (m < MM) ? Wm[(size_t)d * MM + m] : 0.f;
        }
        __syncthreads();
        for (int i = ty; i < 32; i += 8) {
            int m = mx + i, d = dy + tx;
            if (m < MM) WmT[(size_t)m * DIM + d] = tile[tx][i];
        }
    } else if (bid < 1536) {                 // Wq|Wk|Wv|Wo -> [2048][512] bf16
        int id = bid - 512;
        int n0 = (id & 63) * 32, k0 = (id >> 6) * 32;
        const float* W = (n0 < 512) ? Wq : (n0 < 1024) ? Wk
                       : (n0 < 1536) ? Wv : Wo;
        int nc = n0 & 511;
        for (int i = ty; i < 32; i += 8)
            tile[i][tx] = W[(size_t)(k0 + i) * 512 + nc + tx];
        __syncthreads();
        for (int i = ty; i < 32; i += 8)
            WqkvTh[(size_t)(n0 + i) * 512 + k0 + tx] = f2bf(tile[tx][i]);
    } else if (bid < 2560) {                 // W1 [512,2048] -> [2048][512]
        int id = bid - 1536;
        int n0 = (id & 63) * 32, k0 = (id >> 6) * 32;
        for (int i = ty; i < 32; i += 8)
            tile[i][tx] = W1[(size_t)(k0 + i) * DFFN + n0 + tx];
        __syncthreads();
        for (int i = ty; i < 32; i += 8)
            W1Th[(size_t)(n0 + i) * DIM + k0 + tx] = f2bf(tile[tx][i]);
    } else {                                 // W2 [2048,512] -> [512][2048]
        int id = bid - 2560;
        int n0 = (id & 15) * 32, k0 = (id >> 4) * 32;
        for (int i = ty; i < 32; i += 8)
            tile[i][tx] = W2[(size_t)(k0 + i) * DIM + n0 + tx];
        __syncthreads();
        for (int i = ty; i < 32; i += 8)
            W2Th[(size_t)(n0 + i) * DFFN + k0 + tx] = f2bf(tile[tx][i]);
    }
}

// ---------------- embedding + mask -> e_hi/e_lo bf16 (both passes) ---------
__global__ __launch_bounds__(256)
void embed_kernel(const float* __restrict__ xH, const float* __restrict__ xF,
                  const float* __restrict__ WmT, const float* __restrict__ Wt,
                  const float* __restrict__ bt,
                  ushort* __restrict__ ehi, ushort* __restrict__ elo,
                  float* __restrict__ maskA)
{
    int sub  = threadIdx.x >> 6;          // 0..3
    int lane = threadIdx.x & 63;          // 0..63
    int bs   = blockIdx.x * 4 + sub;      // 0..32767
    const float* xp = (bs < BATCH * SEQ) ? (xH + (size_t)bs * 2)
                                         : (xF + (size_t)(bs - BATCH * SEQ) * 2);
    float t   = xp[0];
    float mkf = xp[1];
    int   mk  = (int)fminf(fmaxf(mkf, 0.f), (float)(MM - 1));
    bool  valid = (t >= 0.f);
    if (lane == 0) maskA[bs] = valid ? 1.f : 0.f;
    const float* wrow = WmT + (size_t)mk * DIM + lane * 8;
    float4 w0 = *reinterpret_cast<const float4*>(wrow);
    float4 w1 = *reinterpret_cast<const float4*>(wrow + 4);
    float4 t0 = *reinterpret_cast<const float4*>(Wt + lane * 8);
    float4 t1 = *reinterpret_cast<const float4*>(Wt + lane * 8 + 4);
    float4 b0 = *reinterpret_cast<const float4*>(bt + lane * 8);
    float4 b1 = *reinterpret_cast<const float4*>(bt + lane * 8 + 4);
    float v[8];
    v[0] = w0.x * 0.5f + 0.5f * (t0.x * t + b0.x);
    v[1] = w0.y * 0.5f + 0.5f * (t0.y * t + b0.y);
    v[2] = w0.z * 0.5f + 0.5f * (t0.z * t + b0.z);
    v[3] = w0.w * 0.5f + 0.5f * (t0.w * t + b0.w);
    v[4] = w1.x * 0.5f + 0.5f * (t1.x * t + b1.x);
    v[5] = w1.y * 0.5f + 0.5f * (t1.y * t + b1.y);
    v[6] = w1.z * 0.5f + 0.5f * (t1.z * t + b1.z);
    v[7] = w1.w * 0.5f + 0.5f * (t1.w * t + b1.w);
    union { uint4 u; ushort s[8]; } ph, pl;
    #pragma unroll
    for (int j = 0; j < 8; ++j) {
        float vv = valid ? v[j] : 0.f;
        ushort h = f2bf(vv);
        ph.s[j] = h;
        pl.s[j] = f2bf(vv - bf2f(h));
    }
    size_t base = (size_t)bs * DIM + lane * 8;
    *reinterpret_cast<uint4*>(ehi + base) = ph.u;
    *reinterpret_cast<uint4*>(elo + base) = pl.u;
}

// ---------------- bf16 MFMA GEMM, 128x128 tile, 2-phase dbuf ---------------
// (unchanged — proven)
template<int SEGS, bool BIAS, bool RELU, bool RES, bool PAIR, bool TOUT, bool TRIPLE>
__global__ __launch_bounds__(256)
void gemm_bf16(const ushort* __restrict__ A0, const ushort* __restrict__ A1,
               const ushort* __restrict__ B0, const ushort* __restrict__ B1,
               const float* __restrict__ bias,
               const ushort* __restrict__ Rh, const ushort* __restrict__ Rl,
               ushort* __restrict__ Oh, ushort* __restrict__ Ol,
               ushort* __restrict__ Ot,
               int Md, int Nd, int Kd, int lda, int ldb,
               const float* __restrict__ mrow)
{
    __shared__ __align__(16) ushort As[2][128 * 64];
    __shared__ __align__(16) ushort Bs[2][128 * 64];
    const int tid = threadIdx.x;
    const int w = tid >> 6, l = tid & 63;
    const int wr = w >> 1, wc = w & 1;
    const int l15 = l & 15, lg = l >> 4;
    const int id  = blockIdx.x + gridDim.x * blockIdx.y;
    const int nwg = gridDim.x * gridDim.y;
    const int qc  = nwg >> 3;
    const int lin = (id & 7) * qc + (id >> 3);
    const int row0 = (lin / gridDim.x) * 128;
    const int col0 = (lin % gridDim.x) * 128;
    const int lrow   = l >> 3;
    const int gchunk = (l & 7) ^ lrow;

    if (mrow) {
        float mv = (tid < 128) ? mrow[row0 + tid] : 0.f;
        if (!__syncthreads_or(mv != 0.f)) return;
    }

    f32x4 acc[4][4];
    #pragma unroll
    for (int m = 0; m < 4; m++)
        #pragma unroll
        for (int n = 0; n < 4; n++)
            acc[m][n] = (f32x4){0.f, 0.f, 0.f, 0.f};

    const int NT = SEGS * (Kd >> 6);
    int sseg = 0, skt = 0;

    auto stage = [&](int bi) {
        const ushort* Ap = (sseg == 1) ? A1 : A0;
        const ushort* Bp = (sseg == 2) ? B1 : B0;
        ushort* Asb = &As[bi][0];
        ushort* Bsb = &Bs[bi][0];
        #pragma unroll
        for (int r = 0; r < 4; ++r) {
            int rowb = w * 32 + r * 8;
            int row  = rowb + lrow;
            GL2LDS(Ap + (size_t)(row0 + row) * lda + skt + gchunk * 8,
                   Asb + rowb * 64);
            GL2LDS(Bp + (size_t)(col0 + row) * ldb + skt + gchunk * 8,
                   Bsb + rowb * 64);
        }
        skt += 64;
        if (skt == Kd) { skt = 0; ++sseg; }
    };

    stage(0);
    __syncthreads();

    for (int t = 0; t < NT; ++t) {
        const int cur = t & 1;
        if (t + 1 < NT) stage(cur ^ 1);
        const char* AsB = (const char*)&As[cur][0];
        const char* BsB = (const char*)&Bs[cur][0];
        #pragma unroll
        for (int ks = 0; ks < 2; ++ks) {
            const int g = ks * 4 + lg;
            short8 af[4], bfr[4];
            #pragma unroll
            for (int m = 0; m < 4; ++m) {
                int row = wr * 64 + m * 16 + l15;
                af[m] = *reinterpret_cast<const short8*>(
                    AsB + row * 128 + ((g ^ (row & 7)) << 4));
            }
            #pragma unroll
            for (int n = 0; n < 4; ++n) {
                int row = wc * 64 + n * 16 + l15;
                bfr[n] = *reinterpret_cast<const short8*>(
                    BsB + row * 128 + ((g ^ (row & 7)) << 4));
            }
            #pragma unroll
            for (int m = 0; m < 4; ++m)
                #pragma unroll
                for (int n = 0; n < 4; ++n)
                    acc[m][n] = __builtin_amdgcn_mfma_f32_16x16x32_bf16(
                        af[m], bfr[n], acc[m][n], 0, 0, 0);
        }
        __syncthreads();
    }

    #pragma unroll
    for (int m = 0; m < 4; ++m) {
        #pragma unroll
        for (int n = 0; n < 4; ++n) {
            int col = col0 + wc * 64 + n * 16 + l15;
            if (TRIPLE) {
                if (col0 < 512) {
                    #pragma unroll
                    for (int j = 0; j < 4; ++j) {
                        int row = row0 + wr * 64 + m * 16 + lg * 4 + j;
                        Oh[(size_t)row * 512 + col] = f2bf(acc[m][n][j]);
                    }
                } else if (col0 < 1024) {
                    #pragma unroll
                    for (int j = 0; j < 4; ++j) {
                        int row = row0 + wr * 64 + m * 16 + lg * 4 + j;
                        Ol[(size_t)row * 512 + (col - 512)] = f2bf(acc[m][n][j]);
                    }
                } else {
                    union { uint2 u; ushort s4[4]; } pk;
                    #pragma unroll
                    for (int j = 0; j < 4; ++j) pk.s4[j] = f2bf(acc[m][n][j]);
                    int brow = row0 + wr * 64 + m * 16 + lg * 4;
                    size_t idx = ((size_t)(brow >> 9) << 18)
                               + (size_t)(col - 1024) * SEQ + (brow & 511);
                    *reinterpret_cast<uint2*>(Ot + idx) = pk.u;
                }
            } else if (TOUT) {
                union { uint2 u; ushort s4[4]; } pk;
                #pragma unroll
                for (int j = 0; j < 4; ++j) pk.s4[j] = f2bf(acc[m][n][j]);
                int brow = row0 + wr * 64 + m * 16 + lg * 4;
                size_t idx = ((size_t)(brow >> 9) << 18) + (size_t)col * SEQ + (brow & 511);
                *reinterpret_cast<uint2*>(Oh + idx) = pk.u;
            } else {
                float bia = 0.f;
                if (BIAS) bia = bias[col];
                #pragma unroll
                for (int j = 0; j < 4; ++j) {
                    int row = row0 + wr * 64 + m * 16 + lg * 4 + j;
                    size_t idx = (size_t)row * Nd + col;
                    float v = acc[m][n][j] + bia;
                    if (RES)  v += bf2f(Rh[idx]) + bf2f(Rl[idx]);
                    if (RELU) v = fmaxf(v, 0.f);
                    ushort hv = f2bf(v);
                    Oh[idx] = hv;
                    if (PAIR) Ol[idx] = f2bf(v - bf2f(hv));
                }
            }
        }
    }
}

// ---------------- MFMA flash attention, 128 q-rows, KV dbuf, static-max ----
// grid (NHEAD, BB, 4). 512 threads = 8 waves; wave owns 16 q-rows.
// r21 VALU cuts: (a) lrun via ones-MFMA — lacc = mfma(pa, ones, lacc)
// accumulates row-sums of P across tiles (replaces per-tile shfl tree;
// denominator now uses bf16-rounded P, consistent with PV numerator);
// (b) P->bf16 via packed v_cvt_pk_bf16_f32 (RTNE, 2 vals/instr).
__global__ __launch_bounds__(512)
void attn_mfma(ushort* __restrict__ QO, const ushort* __restrict__ K,
               const ushort* __restrict__ Vt, const float* __restrict__ maskA)
{
    __shared__ __align__(16) ushort Ks[2][64 * 64];   // [buf][kv][dh]
    __shared__ __align__(16) ushort Vs[2][64 * 64];   // [buf][dh][kv]
    __shared__ __align__(16) ushort Pl[8][16 * 64];   // [wave][q][kv] (Q alias)
    __shared__ float ms[512];
    const int h   = blockIdx.x;
    const int b   = blockIdx.y;
    const int qt  = blockIdx.z;
    const int tid = threadIdx.x;
    const int w = tid >> 6, l = tid & 63;
    const int l15 = l & 15, lg = l >> 4, l7 = l & 7;
    const int lrow   = l >> 3;
    const int gchunk = (l & 7) ^ lrow;
    const int qbase = qt * 128;

    // stage Q tile [128 q][64 dh] into Pl (dead until first P write)
    #pragma unroll
    for (int rr = 0; rr < 2; ++rr) {
        int rowb = rr * 64 + w * 8;             // 16 stripes, wave-uniform
        GL2LDS(QO + ((size_t)(b * SEQ + qbase + rowb + lrow)) * DIM
                  + h * DHEAD + gchunk * 8,
               &Pl[0][0] + rowb * 64);
    }
    // full mask row -> LDS (published by the q-skip barrier below)
    ms[tid] = maskA[b * SEQ + tid];
    // dead q-tile skip (global reads; barrier also drains Q-stage + ms)
    float qm = (tid < 128) ? maskA[b * SEQ + qbase + tid] : 0.f;
    if (!__syncthreads_or(qm != 0.f)) return;

    // per-64-kv-tile valid bits (block-uniform)
    unsigned hbits = 0;
    #pragma unroll
    for (int t = 0; t < 8; ++t) {
        int mine = (tid < 64) ? (ms[t * 64 + tid] != 0.f) : 0;
        if (__syncthreads_or(mine)) hbits |= (1u << t);
    }

    // hoist Q A-frags (reads Pl BEFORE any P write); wave w rows w*16+l15
    short8 af[2];
    #pragma unroll
    for (int s = 0; s < 2; ++s) {
        int q = w * 16 + l15;
        int c = (s * 4 + lg) ^ l7;
        af[s] = *reinterpret_cast<const short8*>(&Pl[0][0] + q * 64 + c * 8);
    }

    // all-ones bf16 B operand for row-sum MFMA
    short8 bones;
    #pragma unroll
    for (int i = 0; i < 8; ++i) bones[i] = (short)0x3F80;

    f32x4 oacc[4];
    #pragma unroll
    for (int t = 0; t < 4; ++t) oacc[t] = (f32x4){0.f, 0.f, 0.f, 0.f};
    f32x4 lacc = (f32x4){0.f, 0.f, 0.f, 0.f};   // row-sums of P (all cols equal)

    ushort* pw = &Pl[w][0];

    auto stagekv = [&](int t, int bi) {
        int kv0 = t * 64;
        GL2LDS(K + ((size_t)(b * SEQ + kv0 + w * 8 + lrow)) * DIM
                 + h * DHEAD + gchunk * 8,
               &Ks[bi][0] + w * 8 * 64);
        GL2LDS(Vt + ((size_t)b << 18) + (size_t)(h * DHEAD + w * 8 + lrow) * SEQ
                  + kv0 + gchunk * 8,
               &Vs[bi][0] + w * 8 * 64);
    };

    int t0 = 0;
    while (t0 < 8 && !(hbits & (1u << t0))) ++t0;
    stagekv(t0, 0);
    __syncthreads();                         // tile t0 K/V ready
    int cur = 0;
    for (int t = t0; t < 8; ) {
        int tn = t + 1;
        while (tn < 8 && !(hbits & (1u << tn))) ++tn;
        if (tn < 8) stagekv(tn, cur ^ 1);    // async prefetch next valid tile

        // QK^T: 4 kv16-tiles x 2 k-steps
        f32x4 sacc[4];
        #pragma unroll
        for (int t4 = 0; t4 < 4; ++t4) sacc[t4] = (f32x4){0.f, 0.f, 0.f, 0.f};
        #pragma unroll
        for (int s = 0; s < 2; ++s) {
            int c = (s * 4 + lg) ^ l7;
            #pragma unroll
            for (int t4 = 0; t4 < 4; ++t4) {
                int kv = t4 * 16 + l15;
                short8 bf = *reinterpret_cast<const short8*>(
                    &Ks[cur][0] + kv * 64 + c * 8);
                sacc[t4] = __builtin_amdgcn_mfma_f32_16x16x32_bf16(af[s], bf, sacc[t4], 0, 0, 0);
            }
        }

        // static-max softmax: p = mask * exp(s/8); packed bf16 P writes
        float mk[4];
        #pragma unroll
        for (int t4 = 0; t4 < 4; ++t4) mk[t4] = ms[t * 64 + t4 * 16 + l15];
        #pragma unroll
        for (int t4 = 0; t4 < 4; ++t4)
            #pragma unroll
            for (int j = 0; j < 4; ++j)
                sacc[t4][j] = mk[t4] * __expf(sacc[t4][j] * 0.125f);

        // P (bf16) -> per-wave LDS [16 q][64 kv], chunk-XOR swizzle;
        // pairs (j, j+1) packed with one v_cvt_pk_bf16_f32
        #pragma unroll
        for (int t4 = 0; t4 < 4; ++t4) {
            int kvh = t4 * 16 + l15;
            int base = (kvh & 7);
            int hi3  = (kvh >> 3);
            #pragma unroll
            for (int jp = 0; jp < 4; jp += 2) {
                unsigned u = cvtpk_bf16(sacc[t4][jp], sacc[t4][jp + 1]);
                int q0 = lg * 4 + jp;
                int q1 = q0 + 1;
                pw[q0 * 64 + base + ((hi3 ^ (q0 & 7)) << 3)] = (ushort)u;
                pw[q1 * 64 + base + ((hi3 ^ (q1 & 7)) << 3)] = (ushort)(u >> 16);
            }
        }

        // PV + row-sum: A = P[16 q][64 kv]; B = Vs[dh][kv] and ones
        #pragma unroll
        for (int s = 0; s < 2; ++s) {
            int c = (s * 4 + lg) ^ l7;
            short8 pa = *reinterpret_cast<const short8*>(&pw[l15 * 64 + c * 8]);
            lacc = __builtin_amdgcn_mfma_f32_16x16x32_bf16(pa, bones, lacc, 0, 0, 0);
            #pragma unroll
            for (int dt = 0; dt < 4; ++dt) {
                int dh = dt * 16 + l15;
                short8 vb = *reinterpret_cast<const short8*>(
                    &Vs[cur][0] + dh * 64 + c * 8);
                oacc[dt] = __builtin_amdgcn_mfma_f32_16x16x32_bf16(pa, vb, oacc[dt], 0, 0, 0);
            }
        }

        __syncthreads();                     // buf[cur] free for stage(t+2)
        cur ^= 1;
        t = tn;
    }

    // epilogue: O[q][h*64+dh] = oacc / lacc, in place over Q
    float inv[4];
    #pragma unroll
    for (int j = 0; j < 4; ++j) inv[j] = 1.0f / lacc[j];
    #pragma unroll
    for (int t = 0; t < 4; ++t) {
        #pragma unroll
        for (int j = 0; j < 4; ++j) {
            size_t g = ((size_t)(b * SEQ + qbase + w * 16 + lg * 4 + j)) * DIM
                     + h * DHEAD + t * 16 + l15;
            QO[g] = f2bf(oacc[t][j] * inv[j]);
        }
    }
}

// ---------------- masked mean pool (reads bf16 hi/lo h') -------------------
__global__ __launch_bounds__(512)
void pool_kernel(const ushort* __restrict__ hh, const ushort* __restrict__ hl,
                 const float* __restrict__ maskA, float* __restrict__ pooled)
{
    int b  = blockIdx.x;
    int dq = blockIdx.y;
    int dl = threadIdx.x & 31;       // 32 d-pairs
    int sg = threadIdx.x >> 5;       // 0..15 s-group
    int d  = dq * 64 + dl * 2;
    float a0 = 0.f, a1 = 0.f, cnt = 0.f;
    for (int s = sg; s < SEQ; s += 16) {
        float mv = maskA[b * SEQ + s];
        if (mv == 0.f) continue;
        size_t idx = ((size_t)(b * SEQ + s)) * DIM + d;
        unsigned vh = *reinterpret_cast<const unsigned*>(&hh[idx]);
        unsigned vl = *reinterpret_cast<const unsigned*>(&hl[idx]);
        a0 += bf2f((ushort)(vh & 0xffff)) + bf2f((ushort)(vl & 0xffff));
        a1 += bf2f((ushort)(vh >> 16))    + bf2f((ushort)(vl >> 16));
        cnt += 1.f;
    }
    __shared__ float r0[16][32];
    __shared__ float r1[16][32];
    __shared__ float rc[16];
    r0[sg][dl] = a0;
    r1[sg][dl] = a1;
    if (dl == 0) rc[sg] = cnt;
    __syncthreads();
    if (sg == 0) {
        float t0 = 0.f, t1 = 0.f, c = 0.f;
        #pragma unroll
        for (int g = 0; g < 16; ++g) { t0 += r0[g][dl]; t1 += r1[g][dl]; c += rc[g]; }
        float invc = 1.0f / fmaxf(c, 1.f);
        pooled[b * DIM + d]     = t0 * invc;
        pooled[b * DIM + d + 1] = t1 * invc;
    }
}

// ---------------- pooled @ Wp + bp -> henc row b ---------------------------
__global__ __launch_bounds__(512)
void proj_kernel(const float* __restrict__ pooled, const float* __restrict__ Wp,
                 const float* __restrict__ bp, float* __restrict__ henc)
{
    int b = blockIdx.x;
    int j = threadIdx.x;
    __shared__ float p[DIM];
    p[j] = pooled[b * DIM + j];
    __syncthreads();
    float a0 = 0.f, a1 = 0.f, a2 = 0.f, a3 = 0.f;
    for (int d = 0; d < DIM; d += 4) {
        a0 += p[d]     * Wp[(size_t)d       * DIM + j];
        a1 += p[d + 1] * Wp[(size_t)(d + 1) * DIM + j];
        a2 += p[d + 2] * Wp[(size_t)(d + 2) * DIM + j];
        a3 += p[d + 3] * Wp[(size_t)(d + 3) * DIM + j];
    }
    henc[(size_t)b * DIM + j] = ((a0 + a1) + (a2 + a3)) + bp[j];
}

// ---------------- logits = concat(hH,hF) @ W_out + b_out -------------------
__global__ __launch_bounds__(256)
void logits_kernel(const float* __restrict__ henc, const float* __restrict__ Wout,
                   const float* __restrict__ bout, float* __restrict__ logits)
{
    int b = blockIdx.y;
    int m = blockIdx.x * 256 + threadIdx.x;
    __shared__ float hh[2 * DIM];
    for (int j = threadIdx.x; j < DIM; j += 256) {
        hh[j]       = henc[(size_t)b * DIM + j];
        hh[DIM + j] = henc[(size_t)(BATCH + b) * DIM + j];
    }
    __syncthreads();
    if (m < MM) {
        float a0 = 0.f, a1 = 0.f, a2 = 0.f, a3 = 0.f;
        for (int j = 0; j < 2 * DIM; j += 4) {
            a0 += hh[j]     * Wout[(size_t)j       * MM + m];
            a1 += hh[j + 1] * Wout[(size_t)(j + 1) * MM + m];
            a2 += hh[j + 2] * Wout[(size_t)(j + 2) * MM + m];
            a3 += hh[j + 3] * Wout[(size_t)(j + 3) * MM + m];
        }
        logits[b * MM + m] = ((a0 + a1) + (a2 + a3)) + bout[m];
    }
}

// ---------------- softmax + argmax ----------------
__global__ __launch_bounds__(256)
void smax_kernel(const float* __restrict__ logits, float* __restrict__ out)
{
    int b   = blockIdx.x;
    int tid = threadIdx.x;
    __shared__ float red[256];
    __shared__ int   redi[256];

    float v[4];
    float mx = -INFINITY;
    #pragma unroll
    for (int i = 0; i < 4; i++) {
        int m = tid + i * 256;
        if (m < MM) { v[i] = logits[b * MM + m]; mx = fmaxf(mx, v[i]); }
        else v[i] = -INFINITY;
    }
    red[tid] = mx; __syncthreads();
    for (int st = 128; st > 0; st >>= 1) {
        if (tid < st) red[tid] = fmaxf(red[tid], red[tid + st]);
        __syncthreads();
    }
    mx = red[0]; __syncthreads();

    float sum = 0.f;
    #pragma unroll
    for (int i = 0; i < 4; i++) {
        int m = tid + i * 256;
        if (m < MM) { v[i] = expf(v[i] - mx); sum += v[i]; }
    }
    red[tid] = sum; __syncthreads();
    for (int st = 128; st > 0; st >>= 1) {
        if (tid < st) red[tid] += red[tid + st];
        __syncthreads();
    }
    float inv = 1.0f / red[0]; __syncthreads();

    float bestv = -INFINITY; int besti = 0x7fffffff;
    #pragma unroll
    for (int i = 0; i < 4; i++) {
        int m = tid + i * 256;
        if (m < MM) {
            float lam = v[i] * inv;
            out[b * MM + m] = lam;
            if (lam > bestv) { bestv = lam; besti = m; }
        }
    }
    red[tid] = bestv; redi[tid] = besti; __syncthreads();
    for (int st = 128; st > 0; st >>= 1) {
        if (tid < st) {
            float ov = red[tid + st]; int oi = redi[tid + st];
            if (ov > red[tid] || (ov == red[tid] && oi < redi[tid])) {
                red[tid] = ov; redi[tid] = oi;
            }
        }
        __syncthreads();
    }
    if (tid == 0) out[BATCH * MM + b] = (float)redi[0];
}

// ---------------------------------------------------------------------------
extern "C" void kernel_launch(void* const* d_in, const int* in_sizes, int n_in,
                              void* d_out, int out_size, void* d_ws, size_t ws_size,
                              hipStream_t stream)
{
    const float* xH   = (const float*)d_in[0];
    const float* xF   = (const float*)d_in[1];
    const float* Wm   = (const float*)d_in[2];
    const float* Wt   = (const float*)d_in[3];
    const float* bt   = (const float*)d_in[4];
    const float* Wq   = (const float*)d_in[5];
    const float* Wk   = (const float*)d_in[6];
    const float* Wv   = (const float*)d_in[7];
    const float* Wo   = (const float*)d_in[8];
    const float* W1   = (const float*)d_in[9];
    const float* b1   = (const float*)d_in[10];
    const float* W2   = (const float*)d_in[11];
    const float* b2   = (const float*)d_in[12];
    const float* Wp   = (const float*)d_in[13];
    const float* bp   = (const float*)d_in[14];
    const float* Wout = (const float*)d_in[15];
    const float* bout = (const float*)d_in[16];
    float* out = (float*)d_out;

    float* ws     = (float*)d_ws;
    float*  WmT    = ws + OFF_WMT;
    float*  maskA  = ws + OFF_MASK;
    float*  pooled = ws + OFF_POOL;
    float*  henc   = ws + OFF_HENC;
    float*  logits = ws + OFF_LOG;
    ushort* WqkvTh = (ushort*)(ws + OFF_WQTH);
    ushort* WoTh   = WqkvTh + (size_t)1536 * 512;
    ushort* W1Th   = (ushort*)(ws + OFF_W1TH);
    ushort* W2Th   = (ushort*)(ws + OFF_W2TH);
    ushort* ehi    = (ushort*)(ws + OFF_EHI);
    ushort* elo    = (ushort*)(ws + OFF_ELO);
    ushort* Qb     = (ushort*)(ws + OFF_QB);
    ushort* Kb     = (ushort*)(ws + OFF_KB);
    ushort* Vtb    = (ushort*)(ws + OFF_VB);
    ushort* rbuf   = (ushort*)(ws + OFF_VB);   // [32768][1024] over Vtb+R2

    // ---- fused setup ----
    setup_all<<<dim3(3584), 256, 0, stream>>>(
        Wm, Wq, Wk, Wv, Wo, W1, W2, WmT, WqkvTh, W1Th, W2Th);

    // ---- merged H+F pass ----
    embed_kernel<<<dim3(BROWS / 4), 256, 0, stream>>>(
        xH, xF, WmT, Wt, bt, ehi, elo, maskA);
    gemm_bf16<1,false,false,false,false,false,true><<<dim3(12, 256), 256, 0, stream>>>(
        ehi, nullptr, WqkvTh, nullptr, nullptr, nullptr, nullptr,
        Qb, Kb, Vtb, BROWS, 512, DIM, DIM, DIM, maskA);
    attn_mfma<<<dim3(NHEAD, BB, 4), 512, 0, stream>>>(Qb, Kb, Vtb, maskA);
    gemm_bf16<1,false,false,true,true,false,false><<<dim3(4, 256), 256, 0, stream>>>(
        Qb, nullptr, WoTh, nullptr, nullptr, ehi, elo,
        ehi, elo, nullptr, BROWS, DIM, DIM, DIM, DIM, maskA);
    for (int nc = 0; nc < 2; nc++) {
        gemm_bf16<1,true,true,false,false,false,false><<<dim3(8, 256), 256, 0, stream>>>(
            ehi, nullptr, W1Th + (size_t)nc * 1024 * DIM, nullptr,
            b1 + nc * 1024, nullptr, nullptr,
            rbuf, nullptr, nullptr, BROWS, 1024, DIM, DIM, DIM, maskA);
        if (nc == 0)
            gemm_bf16<1,true,false,true,true,false,false><<<dim3(4, 256), 256, 0, stream>>>(
                rbuf, nullptr, W2Th, nullptr, b2, ehi, elo,
                Qb, Kb, nullptr, BROWS, DIM, 1024, 1024, DFFN, maskA);
        else
            gemm_bf16<1,false,false,true,true,false,false><<<dim3(4, 256), 256, 0, stream>>>(
                rbuf, nullptr, W2Th + 1024, nullptr, nullptr, Qb, Kb,
                Qb, Kb, nullptr, BROWS, DIM, 1024, 1024, DFFN, maskA);
    }
    pool_kernel<<<dim3(BB, 8), 512, 0, stream>>>(Qb, Kb, maskA, pooled);
    proj_kernel<<<dim3(BB), 512, 0, stream>>>(pooled, Wp, bp, henc);
    logits_kernel<<<dim3(4, BATCH), 256, 0, stream>>>(henc, Wout, bout, logits);
    smax_kernel<<<dim3(BATCH), 256, 0, stream>>>(logits, out);
}

// Round 22
// 386.603 us; speedup vs baseline: 1.2730x; 1.0257x over previous
//
#include <hip/hip_runtime.h>
#include <math.h>

// Problem constants
#define BATCH 32
#define BB    64     // merged batch: rows 0..31 = H, 32..63 = F
#define SEQ  512
#define DIM  512
#define MM   1000
#define NHEAD 8
#define DHEAD 64
#define DFFN 2048
#define BROWS (BB * SEQ)     // 32768 rows (both passes)

typedef __attribute__((ext_vector_type(8))) short short8;
typedef __attribute__((ext_vector_type(4))) float f32x4;

__device__ __forceinline__ ushort f2bf(float x) {
    unsigned u = __builtin_bit_cast(unsigned, x);
    unsigned r = (u + 0x7FFFu + ((u >> 16) & 1u)) >> 16;
    return (ushort)r;
}
__device__ __forceinline__ float bf2f(ushort h) {
    unsigned u = ((unsigned)h) << 16;
    return __builtin_bit_cast(float, u);
}
// packed f32x2 -> bf16x2 (RTNE), D[15:0]=bf16(lo), D[31:16]=bf16(hi)
__device__ __forceinline__ unsigned cvtpk_bf16(float lo, float hi) {
    unsigned r;
    asm volatile("v_cvt_pk_bf16_f32 %0, %1, %2" : "=v"(r) : "v"(lo), "v"(hi));
    return r;
}

// async global->LDS, 16B per lane. LDS dest must be wave-uniform base
// (HW adds lane*16); global src is per-lane. [m97/m104 semantics]
#define GL2LDS(g, s) __builtin_amdgcn_global_load_lds( \
    (const __attribute__((address_space(1))) unsigned int*)(g), \
    (__attribute__((address_space(3))) unsigned int*)(s), 16, 0, 0)

// ---------------------------------------------------------------------------
// ws layout (float32-slot offsets) — 210.2 MB used of 256 MiB d_ws.
// SINGLE-bf16 residual stream (r22): ehi = e -> h (in-place Wo, pristine
// for both W1 chunks); h' single bf16 accumulates in Qb (dead after Wo);
// rbuf spans Vtb+R2. elo region now unused.
// ---------------------------------------------------------------------------
constexpr size_t OFF_WMT  = 0;         // fp32 [1000][512]
constexpr size_t OFF_MASK = 524288;    // fp32 [32768]
constexpr size_t OFF_POOL = 557056;    // fp32 [64][512]
constexpr size_t OFF_HENC = 589824;    // fp32 [64][512]
constexpr size_t OFF_LOG  = 622592;    // fp32 [32][1000]
constexpr size_t OFF_WQTH = 655360;    // bf16 [2048][512] concat Wq|Wk|Wv|Wo
constexpr size_t OFF_W1TH = 1179648;   // bf16 [2048][512]
constexpr size_t OFF_W2TH = 1703936;   // bf16 [512][2048]
constexpr size_t OFF_EHI  = 2228224;   // bf16 [32768][512]  e -> h (pristine)
constexpr size_t OFF_ELO  = 10616832;  // (unused)
constexpr size_t OFF_QB   = 19005440;  // bf16 Q -> O -> h' (single)
constexpr size_t OFF_KB   = 27394048;  // bf16 K
constexpr size_t OFF_VB   = 35782656;  // bf16 V^T [b][512][512]; + R2 ->
                                       //   rbuf [32768][1024]

// ---------------- fused setup: WmT + WqkvT + W1T + W2T ---------------------
__global__ __launch_bounds__(256)
void setup_all(const float* __restrict__ Wm,
               const float* __restrict__ Wq, const float* __restrict__ Wk,
               const float* __restrict__ Wv, const float* __restrict__ Wo,
               const float* __restrict__ W1, const float* __restrict__ W2,
               float* __restrict__ WmT, ushort* __restrict__ WqkvTh,
               ushort* __restrict__ W1Th, ushort* __restrict__ W2Th)
{
    __shared__ float tile[32][33];
    const int bid = blockIdx.x;
    const int tx = threadIdx.x & 31;
    const int ty = threadIdx.x >> 5;
    if (bid < 512) {                         // W_m [512,1000] -> [1000,512] f32
        int mx = (bid & 31) * 32, dy = (bid >> 5) * 32;
        for (int i = ty; i < 32; i += 8) {
            int d = dy + i, m = mx + tx;
            tile[i][tx] = (m < MM) ? Wm[(size_t)d * MM + m] : 0.f;
        }
        __syncthreads();
        for (int i = ty; i < 32; i += 8) {
            int m = mx + i, d = dy + tx;
            if (m < MM) WmT[(size_t)m * DIM + d] = tile[tx][i];
        }
    } else if (bid < 1536) {                 // Wq|Wk|Wv|Wo -> [2048][512] bf16
        int id = bid - 512;
        int n0 = (id & 63) * 32, k0 = (id >> 6) * 32;
        const float* W = (n0 < 512) ? Wq : (n0 < 1024) ? Wk
                       : (n0 < 1536) ? Wv : Wo;
        int nc = n0 & 511;
        for (int i = ty; i < 32; i += 8)
            tile[i][tx] = W[(size_t)(k0 + i) * 512 + nc + tx];
        __syncthreads();
        for (int i = ty; i < 32; i += 8)
            WqkvTh[(size_t)(n0 + i) * 512 + k0 + tx] = f2bf(tile[tx][i]);
    } else if (bid < 2560) {                 // W1 [512,2048] -> [2048][512]
        int id = bid - 1536;
        int n0 = (id & 63) * 32, k0 = (id >> 6) * 32;
        for (int i = ty; i < 32; i += 8)
            tile[i][tx] = W1[(size_t)(k0 + i) * DFFN + n0 + tx];
        __syncthreads();
        for (int i = ty; i < 32; i += 8)
            W1Th[(size_t)(n0 + i) * DIM + k0 + tx] = f2bf(tile[tx][i]);
    } else {                                 // W2 [2048,512] -> [512][2048]
        int id = bid - 2560;
        int n0 = (id & 15) * 32, k0 = (id >> 4) * 32;
        for (int i = ty; i < 32; i += 8)
            tile[i][tx] = W2[(size_t)(k0 + i) * DIM + n0 + tx];
        __syncthreads();
        for (int i = ty; i < 32; i += 8)
            W2Th[(size_t)(n0 + i) * DFFN + k0 + tx] = f2bf(tile[tx][i]);
    }
}

// ---------------- embedding + mask -> e bf16 (single, both passes) ---------
__global__ __launch_bounds__(256)
void embed_kernel(const float* __restrict__ xH, const float* __restrict__ xF,
                  const float* __restrict__ WmT, const float* __restrict__ Wt,
                  const float* __restrict__ bt,
                  ushort* __restrict__ ehi, float* __restrict__ maskA)
{
    int sub  = threadIdx.x >> 6;          // 0..3
    int lane = threadIdx.x & 63;          // 0..63
    int bs   = blockIdx.x * 4 + sub;      // 0..32767
    const float* xp = (bs < BATCH * SEQ) ? (xH + (size_t)bs * 2)
                                         : (xF + (size_t)(bs - BATCH * SEQ) * 2);
    float t   = xp[0];
    float mkf = xp[1];
    int   mk  = (int)fminf(fmaxf(mkf, 0.f), (float)(MM - 1));
    bool  valid = (t >= 0.f);
    if (lane == 0) maskA[bs] = valid ? 1.f : 0.f;
    const float* wrow = WmT + (size_t)mk * DIM + lane * 8;
    float4 w0 = *reinterpret_cast<const float4*>(wrow);
    float4 w1 = *reinterpret_cast<const float4*>(wrow + 4);
    float4 t0 = *reinterpret_cast<const float4*>(Wt + lane * 8);
    float4 t1 = *reinterpret_cast<const float4*>(Wt + lane * 8 + 4);
    float4 b0 = *reinterpret_cast<const float4*>(bt + lane * 8);
    float4 b1 = *reinterpret_cast<const float4*>(bt + lane * 8 + 4);
    float v[8];
    v[0] = w0.x * 0.5f + 0.5f * (t0.x * t + b0.x);
    v[1] = w0.y * 0.5f + 0.5f * (t0.y * t + b0.y);
    v[2] = w0.z * 0.5f + 0.5f * (t0.z * t + b0.z);
    v[3] = w0.w * 0.5f + 0.5f * (t0.w * t + b0.w);
    v[4] = w1.x * 0.5f + 0.5f * (t1.x * t + b1.x);
    v[5] = w1.y * 0.5f + 0.5f * (t1.y * t + b1.y);
    v[6] = w1.z * 0.5f + 0.5f * (t1.z * t + b1.z);
    v[7] = w1.w * 0.5f + 0.5f * (t1.w * t + b1.w);
    union { uint4 u; ushort s[8]; } ph;
    #pragma unroll
    for (int j = 0; j < 8; ++j)
        ph.s[j] = f2bf(valid ? v[j] : 0.f);
    *reinterpret_cast<uint4*>(ehi + (size_t)bs * DIM + lane * 8) = ph.u;
}

// ---------------- bf16 MFMA GEMM, 128x128 tile, 2-phase dbuf ---------------
// C[M,N] = A @ B^T [+bias] [+res (single bf16)] [relu], single bf16 out.
// TRIPLE: B concat [1536][512]; cols 0-511 -> Oh (Q), 512-1023 -> Ol (K),
// 1024-1535 -> Ot transposed-per-batch (V^T).
template<bool BIAS, bool RELU, bool RES, bool TRIPLE>
__global__ __launch_bounds__(256)
void gemm_bf16(const ushort* __restrict__ A0, const ushort* __restrict__ B0,
               const float* __restrict__ bias, const ushort* __restrict__ Rh,
               ushort* __restrict__ Oh, ushort* __restrict__ Ol,
               ushort* __restrict__ Ot,
               int Md, int Nd, int Kd, int lda, int ldb,
               const float* __restrict__ mrow)
{
    __shared__ __align__(16) ushort As[2][128 * 64];
    __shared__ __align__(16) ushort Bs[2][128 * 64];
    const int tid = threadIdx.x;
    const int w = tid >> 6, l = tid & 63;
    const int wr = w >> 1, wc = w & 1;
    const int l15 = l & 15, lg = l >> 4;
    const int id  = blockIdx.x + gridDim.x * blockIdx.y;
    const int nwg = gridDim.x * gridDim.y;
    const int qc  = nwg >> 3;
    const int lin = (id & 7) * qc + (id >> 3);
    const int row0 = (lin / gridDim.x) * 128;
    const int col0 = (lin % gridDim.x) * 128;
    const int lrow   = l >> 3;
    const int gchunk = (l & 7) ^ lrow;

    if (mrow) {
        float mv = (tid < 128) ? mrow[row0 + tid] : 0.f;
        if (!__syncthreads_or(mv != 0.f)) return;
    }

    f32x4 acc[4][4];
    #pragma unroll
    for (int m = 0; m < 4; m++)
        #pragma unroll
        for (int n = 0; n < 4; n++)
            acc[m][n] = (f32x4){0.f, 0.f, 0.f, 0.f};

    const int NT = Kd >> 6;
    int skt = 0;

    auto stage = [&](int bi) {
        ushort* Asb = &As[bi][0];
        ushort* Bsb = &Bs[bi][0];
        #pragma unroll
        for (int r = 0; r < 4; ++r) {
            int rowb = w * 32 + r * 8;
            int row  = rowb + lrow;
            GL2LDS(A0 + (size_t)(row0 + row) * lda + skt + gchunk * 8,
                   Asb + rowb * 64);
            GL2LDS(B0 + (size_t)(col0 + row) * ldb + skt + gchunk * 8,
                   Bsb + rowb * 64);
        }
        skt += 64;
    };

    stage(0);
    __syncthreads();

    for (int t = 0; t < NT; ++t) {
        const int cur = t & 1;
        if (t + 1 < NT) stage(cur ^ 1);
        const char* AsB = (const char*)&As[cur][0];
        const char* BsB = (const char*)&Bs[cur][0];
        #pragma unroll
        for (int ks = 0; ks < 2; ++ks) {
            const int g = ks * 4 + lg;
            short8 af[4], bfr[4];
            #pragma unroll
            for (int m = 0; m < 4; ++m) {
                int row = wr * 64 + m * 16 + l15;
                af[m] = *reinterpret_cast<const short8*>(
                    AsB + row * 128 + ((g ^ (row & 7)) << 4));
            }
            #pragma unroll
            for (int n = 0; n < 4; ++n) {
                int row = wc * 64 + n * 16 + l15;
                bfr[n] = *reinterpret_cast<const short8*>(
                    BsB + row * 128 + ((g ^ (row & 7)) << 4));
            }
            #pragma unroll
            for (int m = 0; m < 4; ++m)
                #pragma unroll
                for (int n = 0; n < 4; ++n)
                    acc[m][n] = __builtin_amdgcn_mfma_f32_16x16x32_bf16(
                        af[m], bfr[n], acc[m][n], 0, 0, 0);
        }
        __syncthreads();
    }

    #pragma unroll
    for (int m = 0; m < 4; ++m) {
        #pragma unroll
        for (int n = 0; n < 4; ++n) {
            int col = col0 + wc * 64 + n * 16 + l15;
            if (TRIPLE) {
                if (col0 < 512) {
                    #pragma unroll
                    for (int j = 0; j < 4; ++j) {
                        int row = row0 + wr * 64 + m * 16 + lg * 4 + j;
                        Oh[(size_t)row * 512 + col] = f2bf(acc[m][n][j]);
                    }
                } else if (col0 < 1024) {
                    #pragma unroll
                    for (int j = 0; j < 4; ++j) {
                        int row = row0 + wr * 64 + m * 16 + lg * 4 + j;
                        Ol[(size_t)row * 512 + (col - 512)] = f2bf(acc[m][n][j]);
                    }
                } else {
                    union { uint2 u; ushort s4[4]; } pk;
                    #pragma unroll
                    for (int j = 0; j < 4; ++j) pk.s4[j] = f2bf(acc[m][n][j]);
                    int brow = row0 + wr * 64 + m * 16 + lg * 4;
                    size_t idx = ((size_t)(brow >> 9) << 18)
                               + (size_t)(col - 1024) * SEQ + (brow & 511);
                    *reinterpret_cast<uint2*>(Ot + idx) = pk.u;
                }
            } else {
                float bia = 0.f;
                if (BIAS) bia = bias[col];
                #pragma unroll
                for (int j = 0; j < 4; ++j) {
                    int row = row0 + wr * 64 + m * 16 + lg * 4 + j;
                    size_t idx = (size_t)row * Nd + col;
                    float v = acc[m][n][j] + bia;
                    if (RES)  v += bf2f(Rh[idx]);
                    if (RELU) v = fmaxf(v, 0.f);
                    Oh[idx] = f2bf(v);
                }
            }
        }
    }
}

// ---------------- MFMA flash attention, 128 q-rows, KV dbuf, static-max ----
// (unchanged from r21 — proven: ones-MFMA lrun + packed cvt_pk P writes)
__global__ __launch_bounds__(512)
void attn_mfma(ushort* __restrict__ QO, const ushort* __restrict__ K,
               const ushort* __restrict__ Vt, const float* __restrict__ maskA)
{
    __shared__ __align__(16) ushort Ks[2][64 * 64];   // [buf][kv][dh]
    __shared__ __align__(16) ushort Vs[2][64 * 64];   // [buf][dh][kv]
    __shared__ __align__(16) ushort Pl[8][16 * 64];   // [wave][q][kv] (Q alias)
    __shared__ float ms[512];
    const int h   = blockIdx.x;
    const int b   = blockIdx.y;
    const int qt  = blockIdx.z;
    const int tid = threadIdx.x;
    const int w = tid >> 6, l = tid & 63;
    const int l15 = l & 15, lg = l >> 4, l7 = l & 7;
    const int lrow   = l >> 3;
    const int gchunk = (l & 7) ^ lrow;
    const int qbase = qt * 128;

    // stage Q tile [128 q][64 dh] into Pl (dead until first P write)
    #pragma unroll
    for (int rr = 0; rr < 2; ++rr) {
        int rowb = rr * 64 + w * 8;             // 16 stripes, wave-uniform
        GL2LDS(QO + ((size_t)(b * SEQ + qbase + rowb + lrow)) * DIM
                  + h * DHEAD + gchunk * 8,
               &Pl[0][0] + rowb * 64);
    }
    // full mask row -> LDS (published by the q-skip barrier below)
    ms[tid] = maskA[b * SEQ + tid];
    // dead q-tile skip (global reads; barrier also drains Q-stage + ms)
    float qm = (tid < 128) ? maskA[b * SEQ + qbase + tid] : 0.f;
    if (!__syncthreads_or(qm != 0.f)) return;

    // per-64-kv-tile valid bits (block-uniform)
    unsigned hbits = 0;
    #pragma unroll
    for (int t = 0; t < 8; ++t) {
        int mine = (tid < 64) ? (ms[t * 64 + tid] != 0.f) : 0;
        if (__syncthreads_or(mine)) hbits |= (1u << t);
    }

    // hoist Q A-frags (reads Pl BEFORE any P write); wave w rows w*16+l15
    short8 af[2];
    #pragma unroll
    for (int s = 0; s < 2; ++s) {
        int q = w * 16 + l15;
        int c = (s * 4 + lg) ^ l7;
        af[s] = *reinterpret_cast<const short8*>(&Pl[0][0] + q * 64 + c * 8);
    }

    // all-ones bf16 B operand for row-sum MFMA
    short8 bones;
    #pragma unroll
    for (int i = 0; i < 8; ++i) bones[i] = (short)0x3F80;

    f32x4 oacc[4];
    #pragma unroll
    for (int t = 0; t < 4; ++t) oacc[t] = (f32x4){0.f, 0.f, 0.f, 0.f};
    f32x4 lacc = (f32x4){0.f, 0.f, 0.f, 0.f};   // row-sums of P

    ushort* pw = &Pl[w][0];

    auto stagekv = [&](int t, int bi) {
        int kv0 = t * 64;
        GL2LDS(K + ((size_t)(b * SEQ + kv0 + w * 8 + lrow)) * DIM
                 + h * DHEAD + gchunk * 8,
               &Ks[bi][0] + w * 8 * 64);
        GL2LDS(Vt + ((size_t)b << 18) + (size_t)(h * DHEAD + w * 8 + lrow) * SEQ
                  + kv0 + gchunk * 8,
               &Vs[bi][0] + w * 8 * 64);
    };

    int t0 = 0;
    while (t0 < 8 && !(hbits & (1u << t0))) ++t0;
    stagekv(t0, 0);
    __syncthreads();                         // tile t0 K/V ready
    int cur = 0;
    for (int t = t0; t < 8; ) {
        int tn = t + 1;
        while (tn < 8 && !(hbits & (1u << tn))) ++tn;
        if (tn < 8) stagekv(tn, cur ^ 1);    // async prefetch next valid tile

        // QK^T: 4 kv16-tiles x 2 k-steps
        f32x4 sacc[4];
        #pragma unroll
        for (int t4 = 0; t4 < 4; ++t4) sacc[t4] = (f32x4){0.f, 0.f, 0.f, 0.f};
        #pragma unroll
        for (int s = 0; s < 2; ++s) {
            int c = (s * 4 + lg) ^ l7;
            #pragma unroll
            for (int t4 = 0; t4 < 4; ++t4) {
                int kv = t4 * 16 + l15;
                short8 bf = *reinterpret_cast<const short8*>(
                    &Ks[cur][0] + kv * 64 + c * 8);
                sacc[t4] = __builtin_amdgcn_mfma_f32_16x16x32_bf16(af[s], bf, sacc[t4], 0, 0, 0);
            }
        }

        // static-max softmax: p = mask * exp(s/8)
        float mk[4];
        #pragma unroll
        for (int t4 = 0; t4 < 4; ++t4) mk[t4] = ms[t * 64 + t4 * 16 + l15];
        #pragma unroll
        for (int t4 = 0; t4 < 4; ++t4)
            #pragma unroll
            for (int j = 0; j < 4; ++j)
                sacc[t4][j] = mk[t4] * __expf(sacc[t4][j] * 0.125f);

        // P (bf16) -> per-wave LDS [16 q][64 kv], chunk-XOR swizzle;
        // pairs packed with v_cvt_pk_bf16_f32
        #pragma unroll
        for (int t4 = 0; t4 < 4; ++t4) {
            int kvh = t4 * 16 + l15;
            int base = (kvh & 7);
            int hi3  = (kvh >> 3);
            #pragma unroll
            for (int jp = 0; jp < 4; jp += 2) {
                unsigned u = cvtpk_bf16(sacc[t4][jp], sacc[t4][jp + 1]);
                int q0 = lg * 4 + jp;
                int q1 = q0 + 1;
                pw[q0 * 64 + base + ((hi3 ^ (q0 & 7)) << 3)] = (ushort)u;
                pw[q1 * 64 + base + ((hi3 ^ (q1 & 7)) << 3)] = (ushort)(u >> 16);
            }
        }

        // PV + row-sum: A = P[16 q][64 kv]; B = Vs[dh][kv] and ones
        #pragma unroll
        for (int s = 0; s < 2; ++s) {
            int c = (s * 4 + lg) ^ l7;
            short8 pa = *reinterpret_cast<const short8*>(&pw[l15 * 64 + c * 8]);
            lacc = __builtin_amdgcn_mfma_f32_16x16x32_bf16(pa, bones, lacc, 0, 0, 0);
            #pragma unroll
            for (int dt = 0; dt < 4; ++dt) {
                int dh = dt * 16 + l15;
                short8 vb = *reinterpret_cast<const short8*>(
                    &Vs[cur][0] + dh * 64 + c * 8);
                oacc[dt] = __builtin_amdgcn_mfma_f32_16x16x32_bf16(pa, vb, oacc[dt], 0, 0, 0);
            }
        }

        __syncthreads();                     // buf[cur] free for stage(t+2)
        cur ^= 1;
        t = tn;
    }

    // epilogue: O[q][h*64+dh] = oacc / lacc, in place over Q
    float inv[4];
    #pragma unroll
    for (int j = 0; j < 4; ++j) inv[j] = 1.0f / lacc[j];
    #pragma unroll
    for (int t = 0; t < 4; ++t) {
        #pragma unroll
        for (int j = 0; j < 4; ++j) {
            size_t g = ((size_t)(b * SEQ + qbase + w * 16 + lg * 4 + j)) * DIM
                     + h * DHEAD + t * 16 + l15;
            QO[g] = f2bf(oacc[t][j] * inv[j]);
        }
    }
}

// ---------------- masked mean pool (reads single bf16 h') ------------------
__global__ __launch_bounds__(512)
void pool_kernel(const ushort* __restrict__ hh,
                 const float* __restrict__ maskA, float* __restrict__ pooled)
{
    int b  = blockIdx.x;
    int dq = blockIdx.y;
    int dl = threadIdx.x & 31;       // 32 d-pairs
    int sg = threadIdx.x >> 5;       // 0..15 s-group
    int d  = dq * 64 + dl * 2;
    float a0 = 0.f, a1 = 0.f, cnt = 0.f;
    for (int s = sg; s < SEQ; s += 16) {
        float mv = maskA[b * SEQ + s];
        if (mv == 0.f) continue;
        unsigned vh = *reinterpret_cast<const unsigned*>(
            &hh[((size_t)(b * SEQ + s)) * DIM + d]);
        a0 += bf2f((ushort)(vh & 0xffff));
        a1 += bf2f((ushort)(vh >> 16));
        cnt += 1.f;
    }
    __shared__ float r0[16][32];
    __shared__ float r1[16][32];
    __shared__ float rc[16];
    r0[sg][dl] = a0;
    r1[sg][dl] = a1;
    if (dl == 0) rc[sg] = cnt;
    __syncthreads();
    if (sg == 0) {
        float t0 = 0.f, t1 = 0.f, c = 0.f;
        #pragma unroll
        for (int g = 0; g < 16; ++g) { t0 += r0[g][dl]; t1 += r1[g][dl]; c += rc[g]; }
        float invc = 1.0f / fmaxf(c, 1.f);
        pooled[b * DIM + d]     = t0 * invc;
        pooled[b * DIM + d + 1] = t1 * invc;
    }
}

// ---------------- pooled @ Wp + bp -> henc row b ---------------------------
__global__ __launch_bounds__(512)
void proj_kernel(const float* __restrict__ pooled, const float* __restrict__ Wp,
                 const float* __restrict__ bp, float* __restrict__ henc)
{
    int b = blockIdx.x;
    int j = threadIdx.x;
    __shared__ float p[DIM];
    p[j] = pooled[b * DIM + j];
    __syncthreads();
    float a0 = 0.f, a1 = 0.f, a2 = 0.f, a3 = 0.f;
    for (int d = 0; d < DIM; d += 4) {
        a0 += p[d]     * Wp[(size_t)d       * DIM + j];
        a1 += p[d + 1] * Wp[(size_t)(d + 1) * DIM + j];
        a2 += p[d + 2] * Wp[(size_t)(d + 2) * DIM + j];
        a3 += p[d + 3] * Wp[(size_t)(d + 3) * DIM + j];
    }
    henc[(size_t)b * DIM + j] = ((a0 + a1) + (a2 + a3)) + bp[j];
}

// ---------------- logits = concat(hH,hF) @ W_out + b_out -------------------
__global__ __launch_bounds__(256)
void logits_kernel(const float* __restrict__ henc, const float* __restrict__ Wout,
                   const float* __restrict__ bout, float* __restrict__ logits)
{
    int b = blockIdx.y;
    int m = blockIdx.x * 256 + threadIdx.x;
    __shared__ float hh[2 * DIM];
    for (int j = threadIdx.x; j < DIM; j += 256) {
        hh[j]       = henc[(size_t)b * DIM + j];
        hh[DIM + j] = henc[(size_t)(BATCH + b) * DIM + j];
    }
    __syncthreads();
    if (m < MM) {
        float a0 = 0.f, a1 = 0.f, a2 = 0.f, a3 = 0.f;
        for (int j = 0; j < 2 * DIM; j += 4) {
            a0 += hh[j]     * Wout[(size_t)j       * MM + m];
            a1 += hh[j + 1] * Wout[(size_t)(j + 1) * MM + m];
            a2 += hh[j + 2] * Wout[(size_t)(j + 2) * MM + m];
            a3 += hh[j + 3] * Wout[(size_t)(j + 3) * MM + m];
        }
        logits[b * MM + m] = ((a0 + a1) + (a2 + a3)) + bout[m];
    }
}

// ---------------- softmax + argmax ----------------
__global__ __launch_bounds__(256)
void smax_kernel(const float* __restrict__ logits, float* __restrict__ out)
{
    int b   = blockIdx.x;
    int tid = threadIdx.x;
    __shared__ float red[256];
    __shared__ int   redi[256];

    float v[4];
    float mx = -INFINITY;
    #pragma unroll
    for (int i = 0; i < 4; i++) {
        int m = tid + i * 256;
        if (m < MM) { v[i] = logits[b * MM + m]; mx = fmaxf(mx, v[i]); }
        else v[i] = -INFINITY;
    }
    red[tid] = mx; __syncthreads();
    for (int st = 128; st > 0; st >>= 1) {
        if (tid < st) red[tid] = fmaxf(red[tid], red[tid + st]);
        __syncthreads();
    }
    mx = red[0]; __syncthreads();

    float sum = 0.f;
    #pragma unroll
    for (int i = 0; i < 4; i++) {
        int m = tid + i * 256;
        if (m < MM) { v[i] = expf(v[i] - mx); sum += v[i]; }
    }
    red[tid] = sum; __syncthreads();
    for (int st = 128; st > 0; st >>= 1) {
        if (tid < st) red[tid] += red[tid + st];
        __syncthreads();
    }
    float inv = 1.0f / red[0]; __syncthreads();

    float bestv = -INFINITY; int besti = 0x7fffffff;
    #pragma unroll
    for (int i = 0; i < 4; i++) {
        int m = tid + i * 256;
        if (m < MM) {
            float lam = v[i] * inv;
            out[b * MM + m] = lam;
            if (lam > bestv) { bestv = lam; besti = m; }
        }
    }
    red[tid] = bestv; redi[tid] = besti; __syncthreads();
    for (int st = 128; st > 0; st >>= 1) {
        if (tid < st) {
            float ov = red[tid + st]; int oi = redi[tid + st];
            if (ov > red[tid] || (ov == red[tid] && oi < redi[tid])) {
                red[tid] = ov; redi[tid] = oi;
            }
        }
        __syncthreads();
    }
    if (tid == 0) out[BATCH * MM + b] = (float)redi[0];
}

// ---------------------------------------------------------------------------
extern "C" void kernel_launch(void* const* d_in, const int* in_sizes, int n_in,
                              void* d_out, int out_size, void* d_ws, size_t ws_size,
                              hipStream_t stream)
{
    const float* xH   = (const float*)d_in[0];
    const float* xF   = (const float*)d_in[1];
    const float* Wm   = (const float*)d_in[2];
    const float* Wt   = (const float*)d_in[3];
    const float* bt   = (const float*)d_in[4];
    const float* Wq   = (const float*)d_in[5];
    const float* Wk   = (const float*)d_in[6];
    const float* Wv   = (const float*)d_in[7];
    const float* Wo   = (const float*)d_in[8];
    const float* W1   = (const float*)d_in[9];
    const float* b1   = (const float*)d_in[10];
    const float* W2   = (const float*)d_in[11];
    const float* b2   = (const float*)d_in[12];
    const float* Wp   = (const float*)d_in[13];
    const float* bp   = (const float*)d_in[14];
    const float* Wout = (const float*)d_in[15];
    const float* bout = (const float*)d_in[16];
    float* out = (float*)d_out;

    float* ws     = (float*)d_ws;
    float*  WmT    = ws + OFF_WMT;
    float*  maskA  = ws + OFF_MASK;
    float*  pooled = ws + OFF_POOL;
    float*  henc   = ws + OFF_HENC;
    float*  logits = ws + OFF_LOG;
    ushort* WqkvTh = (ushort*)(ws + OFF_WQTH);
    ushort* WoTh   = WqkvTh + (size_t)1536 * 512;
    ushort* W1Th   = (ushort*)(ws + OFF_W1TH);
    ushort* W2Th   = (ushort*)(ws + OFF_W2TH);
    ushort* ehi    = (ushort*)(ws + OFF_EHI);   // e -> h (pristine for FFN)
    ushort* Qb     = (ushort*)(ws + OFF_QB);    // Q -> O -> h' (single)
    ushort* Kb     = (ushort*)(ws + OFF_KB);
    ushort* Vtb    = (ushort*)(ws + OFF_VB);
    ushort* rbuf   = (ushort*)(ws + OFF_VB);    // [32768][1024] over Vtb+R2

    // ---- fused setup ----
    setup_all<<<dim3(3584), 256, 0, stream>>>(
        Wm, Wq, Wk, Wv, Wo, W1, W2, WmT, WqkvTh, W1Th, W2Th);

    // ---- merged H+F pass (single-bf16 residual stream) ----
    embed_kernel<<<dim3(BROWS / 4), 256, 0, stream>>>(
        xH, xF, WmT, Wt, bt, ehi, maskA);
    // fused QKV: Q->Qb, K->Kb, V->Vtb (transposed per batch)
    gemm_bf16<false,false,false,true><<<dim3(12, 256), 256, 0, stream>>>(
        ehi, WqkvTh, nullptr, nullptr,
        Qb, Kb, Vtb, BROWS, 512, DIM, DIM, DIM, maskA);
    // MFMA attention, O overwrites Q
    attn_mfma<<<dim3(NHEAD, BB, 4), 512, 0, stream>>>(Qb, Kb, Vtb, maskA);
    // h = e + O @ Wo  (in place over ehi; single residual)
    gemm_bf16<false,false,true,false><<<dim3(4, 256), 256, 0, stream>>>(
        Qb, WoTh, nullptr, ehi,
        ehi, nullptr, nullptr, BROWS, DIM, DIM, DIM, DIM, maskA);
    // FFN over 2 DFF-chunks of 1024 (ehi = pristine h for both W1 chunks;
    // h' single bf16 accumulates in Qb; rbuf = dead Vtb+R2):
    for (int nc = 0; nc < 2; nc++) {
        gemm_bf16<true,true,false,false><<<dim3(8, 256), 256, 0, stream>>>(
            ehi, W1Th + (size_t)nc * 1024 * DIM, b1 + nc * 1024, nullptr,
            rbuf, nullptr, nullptr, BROWS, 1024, DIM, DIM, DIM, maskA);
        if (nc == 0)
            gemm_bf16<true,false,true,false><<<dim3(4, 256), 256, 0, stream>>>(
                rbuf, W2Th, b2, ehi,
                Qb, nullptr, nullptr, BROWS, DIM, 1024, 1024, DFFN, maskA);
        else
            gemm_bf16<false,false,true,false><<<dim3(4, 256), 256, 0, stream>>>(
                rbuf, W2Th + 1024, nullptr, Qb,
                Qb, nullptr, nullptr, BROWS, DIM, 1024, 1024, DFFN, maskA);
    }
    // masked mean pool over h' (single bf16 in Qb; masked rows skipped)
    pool_kernel<<<dim3(BB, 8), 512, 0, stream>>>(Qb, maskA, pooled);
    proj_kernel<<<dim3(BB), 512, 0, stream>>>(pooled, Wp, bp, henc);
    logits_kernel<<<dim3(4, BATCH), 256, 0, stream>>>(henc, Wout, bout, logits);
    smax_kernel<<<dim3(BATCH), 256, 0, stream>>>(logits, out);
}

// Round 23
// 368.816 us; speedup vs baseline: 1.3343x; 1.0482x over previous
//
#include <hip/hip_runtime.h>
#include <math.h>

// Problem constants
#define BATCH 32
#define BB    64     // merged batch: rows 0..31 = H, 32..63 = F
#define SEQ  512
#define DIM  512
#define MM   1000
#define NHEAD 8
#define DHEAD 64
#define DFFN 2048
#define BROWS (BB * SEQ)     // 32768 rows (both passes)

typedef __attribute__((ext_vector_type(8))) short short8;
typedef __attribute__((ext_vector_type(4))) float f32x4;

__device__ __forceinline__ ushort f2bf(float x) {
    unsigned u = __builtin_bit_cast(unsigned, x);
    unsigned r = (u + 0x7FFFu + ((u >> 16) & 1u)) >> 16;
    return (ushort)r;
}
__device__ __forceinline__ float bf2f(ushort h) {
    unsigned u = ((unsigned)h) << 16;
    return __builtin_bit_cast(float, u);
}
// packed f32x2 -> bf16x2 (RTNE), D[15:0]=bf16(lo), D[31:16]=bf16(hi)
__device__ __forceinline__ unsigned cvtpk_bf16(float lo, float hi) {
    unsigned r;
    asm volatile("v_cvt_pk_bf16_f32 %0, %1, %2" : "=v"(r) : "v"(lo), "v"(hi));
    return r;
}

// async global->LDS, 16B per lane. LDS dest must be wave-uniform base
// (HW adds lane*16); global src is per-lane. [m97/m104 semantics]
#define GL2LDS(g, s) __builtin_amdgcn_global_load_lds( \
    (const __attribute__((address_space(1))) unsigned int*)(g), \
    (__attribute__((address_space(3))) unsigned int*)(s), 16, 0, 0)

// ---------------------------------------------------------------------------
// ws layout (float32-slot offsets) — 243.8 MB used of 256 MiB d_ws.
// Single-bf16 residual stream: ehi = e -> h (in-place Wo; pristine for W1);
// h' accumulates in Qb (dead after Wo). rbuf [32768][2048] spans Kb+Vtb+R2
// (K and V^T both dead after attention) -> FFN is 2 single-shot GEMMs.
// ---------------------------------------------------------------------------
constexpr size_t OFF_WMT  = 0;         // fp32 [1000][512]
constexpr size_t OFF_MASK = 524288;    // fp32 [32768]
constexpr size_t OFF_POOL = 557056;    // fp32 [64][512]
constexpr size_t OFF_HENC = 589824;    // fp32 [64][512]
constexpr size_t OFF_LOG  = 622592;    // fp32 [32][1000]
constexpr size_t OFF_WQTH = 655360;    // bf16 [2048][512] concat Wq|Wk|Wv|Wo
constexpr size_t OFF_W1TH = 1179648;   // bf16 [2048][512]
constexpr size_t OFF_W2TH = 1703936;   // bf16 [512][2048]
constexpr size_t OFF_EHI  = 2228224;   // bf16 [32768][512]  e -> h (pristine)
constexpr size_t OFF_QB   = 19005440;  // bf16 Q -> O -> h' (single)
constexpr size_t OFF_KB   = 27394048;  // bf16 K; after attn: rbuf [32768][2048]
constexpr size_t OFF_VB   = 35782656;  // bf16 V^T [b][512][512] (in rbuf span)

// ---------------- fused setup: WmT + WqkvT + W1T + W2T ---------------------
__global__ __launch_bounds__(256)
void setup_all(const float* __restrict__ Wm,
               const float* __restrict__ Wq, const float* __restrict__ Wk,
               const float* __restrict__ Wv, const float* __restrict__ Wo,
               const float* __restrict__ W1, const float* __restrict__ W2,
               float* __restrict__ WmT, ushort* __restrict__ WqkvTh,
               ushort* __restrict__ W1Th, ushort* __restrict__ W2Th)
{
    __shared__ float tile[32][33];
    const int bid = blockIdx.x;
    const int tx = threadIdx.x & 31;
    const int ty = threadIdx.x >> 5;
    if (bid < 512) {                         // W_m [512,1000] -> [1000,512] f32
        int mx = (bid & 31) * 32, dy = (bid >> 5) * 32;
        for (int i = ty; i < 32; i += 8) {
            int d = dy + i, m = mx + tx;
            tile[i][tx] = (m < MM) ? Wm[(size_t)d * MM + m] : 0.f;
        }
        __syncthreads();
        for (int i = ty; i < 32; i += 8) {
            int m = mx + i, d = dy + tx;
            if (m < MM) WmT[(size_t)m * DIM + d] = tile[tx][i];
        }
    } else if (bid < 1536) {                 // Wq|Wk|Wv|Wo -> [2048][512] bf16
        int id = bid - 512;
        int n0 = (id & 63) * 32, k0 = (id >> 6) * 32;
        const float* W = (n0 < 512) ? Wq : (n0 < 1024) ? Wk
                       : (n0 < 1536) ? Wv : Wo;
        int nc = n0 & 511;
        for (int i = ty; i < 32; i += 8)
            tile[i][tx] = W[(size_t)(k0 + i) * 512 + nc + tx];
        __syncthreads();
        for (int i = ty; i < 32; i += 8)
            WqkvTh[(size_t)(n0 + i) * 512 + k0 + tx] = f2bf(tile[tx][i]);
    } else if (bid < 2560) {                 // W1 [512,2048] -> [2048][512]
        int id = bid - 1536;
        int n0 = (id & 63) * 32, k0 = (id >> 6) * 32;
        for (int i = ty; i < 32; i += 8)
            tile[i][tx] = W1[(size_t)(k0 + i) * DFFN + n0 + tx];
        __syncthreads();
        for (int i = ty; i < 32; i += 8)
            W1Th[(size_t)(n0 + i) * DIM + k0 + tx] = f2bf(tile[tx][i]);
    } else {                                 // W2 [2048,512] -> [512][2048]
        int id = bid - 2560;
        int n0 = (id & 15) * 32, k0 = (id >> 4) * 32;
        for (int i = ty; i < 32; i += 8)
            tile[i][tx] = W2[(size_t)(k0 + i) * DIM + n0 + tx];
        __syncthreads();
        for (int i = ty; i < 32; i += 8)
            W2Th[(size_t)(n0 + i) * DFFN + k0 + tx] = f2bf(tile[tx][i]);
    }
}

// ---------------- embedding + mask -> e bf16 (single, both passes) ---------
__global__ __launch_bounds__(256)
void embed_kernel(const float* __restrict__ xH, const float* __restrict__ xF,
                  const float* __restrict__ WmT, const float* __restrict__ Wt,
                  const float* __restrict__ bt,
                  ushort* __restrict__ ehi, float* __restrict__ maskA)
{
    int sub  = threadIdx.x >> 6;          // 0..3
    int lane = threadIdx.x & 63;          // 0..63
    int bs   = blockIdx.x * 4 + sub;      // 0..32767
    const float* xp = (bs < BATCH * SEQ) ? (xH + (size_t)bs * 2)
                                         : (xF + (size_t)(bs - BATCH * SEQ) * 2);
    float t   = xp[0];
    float mkf = xp[1];
    int   mk  = (int)fminf(fmaxf(mkf, 0.f), (float)(MM - 1));
    bool  valid = (t >= 0.f);
    if (lane == 0) maskA[bs] = valid ? 1.f : 0.f;
    const float* wrow = WmT + (size_t)mk * DIM + lane * 8;
    float4 w0 = *reinterpret_cast<const float4*>(wrow);
    float4 w1 = *reinterpret_cast<const float4*>(wrow + 4);
    float4 t0 = *reinterpret_cast<const float4*>(Wt + lane * 8);
    float4 t1 = *reinterpret_cast<const float4*>(Wt + lane * 8 + 4);
    float4 b0 = *reinterpret_cast<const float4*>(bt + lane * 8);
    float4 b1 = *reinterpret_cast<const float4*>(bt + lane * 8 + 4);
    float v[8];
    v[0] = w0.x * 0.5f + 0.5f * (t0.x * t + b0.x);
    v[1] = w0.y * 0.5f + 0.5f * (t0.y * t + b0.y);
    v[2] = w0.z * 0.5f + 0.5f * (t0.z * t + b0.z);
    v[3] = w0.w * 0.5f + 0.5f * (t0.w * t + b0.w);
    v[4] = w1.x * 0.5f + 0.5f * (t1.x * t + b1.x);
    v[5] = w1.y * 0.5f + 0.5f * (t1.y * t + b1.y);
    v[6] = w1.z * 0.5f + 0.5f * (t1.z * t + b1.z);
    v[7] = w1.w * 0.5f + 0.5f * (t1.w * t + b1.w);
    union { uint4 u; ushort s[8]; } ph;
    #pragma unroll
    for (int j = 0; j < 8; ++j)
        ph.s[j] = f2bf(valid ? v[j] : 0.f);
    *reinterpret_cast<uint4*>(ehi + (size_t)bs * DIM + lane * 8) = ph.u;
}

// ---------------- bf16 MFMA GEMM, 128x128 tile, 2-phase dbuf ---------------
// C[M,N] = A @ B^T [+bias] [+res (single bf16)] [relu], single bf16 out.
// TRIPLE: B concat [1536][512]; cols 0-511 -> Oh (Q), 512-1023 -> Ol (K),
// 1024-1535 -> Ot transposed-per-batch (V^T).
template<bool BIAS, bool RELU, bool RES, bool TRIPLE>
__global__ __launch_bounds__(256)
void gemm_bf16(const ushort* __restrict__ A0, const ushort* __restrict__ B0,
               const float* __restrict__ bias, const ushort* __restrict__ Rh,
               ushort* __restrict__ Oh, ushort* __restrict__ Ol,
               ushort* __restrict__ Ot,
               int Md, int Nd, int Kd, int lda, int ldb,
               const float* __restrict__ mrow)
{
    __shared__ __align__(16) ushort As[2][128 * 64];
    __shared__ __align__(16) ushort Bs[2][128 * 64];
    const int tid = threadIdx.x;
    const int w = tid >> 6, l = tid & 63;
    const int wr = w >> 1, wc = w & 1;
    const int l15 = l & 15, lg = l >> 4;
    const int id  = blockIdx.x + gridDim.x * blockIdx.y;
    const int nwg = gridDim.x * gridDim.y;
    const int qc  = nwg >> 3;
    const int lin = (id & 7) * qc + (id >> 3);
    const int row0 = (lin / gridDim.x) * 128;
    const int col0 = (lin % gridDim.x) * 128;
    const int lrow   = l >> 3;
    const int gchunk = (l & 7) ^ lrow;

    if (mrow) {
        float mv = (tid < 128) ? mrow[row0 + tid] : 0.f;
        if (!__syncthreads_or(mv != 0.f)) return;
    }

    f32x4 acc[4][4];
    #pragma unroll
    for (int m = 0; m < 4; m++)
        #pragma unroll
        for (int n = 0; n < 4; n++)
            acc[m][n] = (f32x4){0.f, 0.f, 0.f, 0.f};

    const int NT = Kd >> 6;
    int skt = 0;

    auto stage = [&](int bi) {
        ushort* Asb = &As[bi][0];
        ushort* Bsb = &Bs[bi][0];
        #pragma unroll
        for (int r = 0; r < 4; ++r) {
            int rowb = w * 32 + r * 8;
            int row  = rowb + lrow;
            GL2LDS(A0 + (size_t)(row0 + row) * lda + skt + gchunk * 8,
                   Asb + rowb * 64);
            GL2LDS(B0 + (size_t)(col0 + row) * ldb + skt + gchunk * 8,
                   Bsb + rowb * 64);
        }
        skt += 64;
    };

    stage(0);
    __syncthreads();

    for (int t = 0; t < NT; ++t) {
        const int cur = t & 1;
        if (t + 1 < NT) stage(cur ^ 1);
        const char* AsB = (const char*)&As[cur][0];
        const char* BsB = (const char*)&Bs[cur][0];
        #pragma unroll
        for (int ks = 0; ks < 2; ++ks) {
            const int g = ks * 4 + lg;
            short8 af[4], bfr[4];
            #pragma unroll
            for (int m = 0; m < 4; ++m) {
                int row = wr * 64 + m * 16 + l15;
                af[m] = *reinterpret_cast<const short8*>(
                    AsB + row * 128 + ((g ^ (row & 7)) << 4));
            }
            #pragma unroll
            for (int n = 0; n < 4; ++n) {
                int row = wc * 64 + n * 16 + l15;
                bfr[n] = *reinterpret_cast<const short8*>(
                    BsB + row * 128 + ((g ^ (row & 7)) << 4));
            }
            #pragma unroll
            for (int m = 0; m < 4; ++m)
                #pragma unroll
                for (int n = 0; n < 4; ++n)
                    acc[m][n] = __builtin_amdgcn_mfma_f32_16x16x32_bf16(
                        af[m], bfr[n], acc[m][n], 0, 0, 0);
        }
        __syncthreads();
    }

    #pragma unroll
    for (int m = 0; m < 4; ++m) {
        #pragma unroll
        for (int n = 0; n < 4; ++n) {
            int col = col0 + wc * 64 + n * 16 + l15;
            if (TRIPLE) {
                if (col0 < 512) {
                    #pragma unroll
                    for (int j = 0; j < 4; ++j) {
                        int row = row0 + wr * 64 + m * 16 + lg * 4 + j;
                        Oh[(size_t)row * 512 + col] = f2bf(acc[m][n][j]);
                    }
                } else if (col0 < 1024) {
                    #pragma unroll
                    for (int j = 0; j < 4; ++j) {
                        int row = row0 + wr * 64 + m * 16 + lg * 4 + j;
                        Ol[(size_t)row * 512 + (col - 512)] = f2bf(acc[m][n][j]);
                    }
                } else {
                    union { uint2 u; ushort s4[4]; } pk;
                    #pragma unroll
                    for (int j = 0; j < 4; ++j) pk.s4[j] = f2bf(acc[m][n][j]);
                    int brow = row0 + wr * 64 + m * 16 + lg * 4;
                    size_t idx = ((size_t)(brow >> 9) << 18)
                               + (size_t)(col - 1024) * SEQ + (brow & 511);
                    *reinterpret_cast<uint2*>(Ot + idx) = pk.u;
                }
            } else {
                float bia = 0.f;
                if (BIAS) bia = bias[col];
                #pragma unroll
                for (int j = 0; j < 4; ++j) {
                    int row = row0 + wr * 64 + m * 16 + lg * 4 + j;
                    size_t idx = (size_t)row * Nd + col;
                    float v = acc[m][n][j] + bia;
                    if (RES)  v += bf2f(Rh[idx]);
                    if (RELU) v = fmaxf(v, 0.f);
                    Oh[idx] = f2bf(v);
                }
            }
        }
    }
}

// ---------------- MFMA flash attention, 128 q-rows, KV dbuf, static-max ----
// (unchanged from r21/r22 — proven: ones-MFMA lrun + packed cvt_pk P writes)
__global__ __launch_bounds__(512)
void attn_mfma(ushort* __restrict__ QO, const ushort* __restrict__ K,
               const ushort* __restrict__ Vt, const float* __restrict__ maskA)
{
    __shared__ __align__(16) ushort Ks[2][64 * 64];   // [buf][kv][dh]
    __shared__ __align__(16) ushort Vs[2][64 * 64];   // [buf][dh][kv]
    __shared__ __align__(16) ushort Pl[8][16 * 64];   // [wave][q][kv] (Q alias)
    __shared__ float ms[512];
    const int h   = blockIdx.x;
    const int b   = blockIdx.y;
    const int qt  = blockIdx.z;
    const int tid = threadIdx.x;
    const int w = tid >> 6, l = tid & 63;
    const int l15 = l & 15, lg = l >> 4, l7 = l & 7;
    const int lrow   = l >> 3;
    const int gchunk = (l & 7) ^ lrow;
    const int qbase = qt * 128;

    // stage Q tile [128 q][64 dh] into Pl (dead until first P write)
    #pragma unroll
    for (int rr = 0; rr < 2; ++rr) {
        int rowb = rr * 64 + w * 8;             // 16 stripes, wave-uniform
        GL2LDS(QO + ((size_t)(b * SEQ + qbase + rowb + lrow)) * DIM
                  + h * DHEAD + gchunk * 8,
               &Pl[0][0] + rowb * 64);
    }
    // full mask row -> LDS (published by the q-skip barrier below)
    ms[tid] = maskA[b * SEQ + tid];
    // dead q-tile skip (global reads; barrier also drains Q-stage + ms)
    float qm = (tid < 128) ? maskA[b * SEQ + qbase + tid] : 0.f;
    if (!__syncthreads_or(qm != 0.f)) return;

    // per-64-kv-tile valid bits (block-uniform)
    unsigned hbits = 0;
    #pragma unroll
    for (int t = 0; t < 8; ++t) {
        int mine = (tid < 64) ? (ms[t * 64 + tid] != 0.f) : 0;
        if (__syncthreads_or(mine)) hbits |= (1u << t);
    }

    // hoist Q A-frags (reads Pl BEFORE any P write); wave w rows w*16+l15
    short8 af[2];
    #pragma unroll
    for (int s = 0; s < 2; ++s) {
        int q = w * 16 + l15;
        int c = (s * 4 + lg) ^ l7;
        af[s] = *reinterpret_cast<const short8*>(&Pl[0][0] + q * 64 + c * 8);
    }

    // all-ones bf16 B operand for row-sum MFMA
    short8 bones;
    #pragma unroll
    for (int i = 0; i < 8; ++i) bones[i] = (short)0x3F80;

    f32x4 oacc[4];
    #pragma unroll
    for (int t = 0; t < 4; ++t) oacc[t] = (f32x4){0.f, 0.f, 0.f, 0.f};
    f32x4 lacc = (f32x4){0.f, 0.f, 0.f, 0.f};   // row-sums of P

    ushort* pw = &Pl[w][0];

    auto stagekv = [&](int t, int bi) {
        int kv0 = t * 64;
        GL2LDS(K + ((size_t)(b * SEQ + kv0 + w * 8 + lrow)) * DIM
                 + h * DHEAD + gchunk * 8,
               &Ks[bi][0] + w * 8 * 64);
        GL2LDS(Vt + ((size_t)b << 18) + (size_t)(h * DHEAD + w * 8 + lrow) * SEQ
                  + kv0 + gchunk * 8,
               &Vs[bi][0] + w * 8 * 64);
    };

    int t0 = 0;
    while (t0 < 8 && !(hbits & (1u << t0))) ++t0;
    stagekv(t0, 0);
    __syncthreads();                         // tile t0 K/V ready
    int cur = 0;
    for (int t = t0; t < 8; ) {
        int tn = t + 1;
        while (tn < 8 && !(hbits & (1u << tn))) ++tn;
        if (tn < 8) stagekv(tn, cur ^ 1);    // async prefetch next valid tile

        // QK^T: 4 kv16-tiles x 2 k-steps
        f32x4 sacc[4];
        #pragma unroll
        for (int t4 = 0; t4 < 4; ++t4) sacc[t4] = (f32x4){0.f, 0.f, 0.f, 0.f};
        #pragma unroll
        for (int s = 0; s < 2; ++s) {
            int c = (s * 4 + lg) ^ l7;
            #pragma unroll
            for (int t4 = 0; t4 < 4; ++t4) {
                int kv = t4 * 16 + l15;
                short8 bf = *reinterpret_cast<const short8*>(
                    &Ks[cur][0] + kv * 64 + c * 8);
                sacc[t4] = __builtin_amdgcn_mfma_f32_16x16x32_bf16(af[s], bf, sacc[t4], 0, 0, 0);
            }
        }

        // static-max softmax: p = mask * exp(s/8)
        float mk[4];
        #pragma unroll
        for (int t4 = 0; t4 < 4; ++t4) mk[t4] = ms[t * 64 + t4 * 16 + l15];
        #pragma unroll
        for (int t4 = 0; t4 < 4; ++t4)
            #pragma unroll
            for (int j = 0; j < 4; ++j)
                sacc[t4][j] = mk[t4] * __expf(sacc[t4][j] * 0.125f);

        // P (bf16) -> per-wave LDS [16 q][64 kv], chunk-XOR swizzle;
        // pairs packed with v_cvt_pk_bf16_f32
        #pragma unroll
        for (int t4 = 0; t4 < 4; ++t4) {
            int kvh = t4 * 16 + l15;
            int base = (kvh & 7);
            int hi3  = (kvh >> 3);
            #pragma unroll
            for (int jp = 0; jp < 4; jp += 2) {
                unsigned u = cvtpk_bf16(sacc[t4][jp], sacc[t4][jp + 1]);
                int q0 = lg * 4 + jp;
                int q1 = q0 + 1;
                pw[q0 * 64 + base + ((hi3 ^ (q0 & 7)) << 3)] = (ushort)u;
                pw[q1 * 64 + base + ((hi3 ^ (q1 & 7)) << 3)] = (ushort)(u >> 16);
            }
        }

        // PV + row-sum: A = P[16 q][64 kv]; B = Vs[dh][kv] and ones
        #pragma unroll
        for (int s = 0; s < 2; ++s) {
            int c = (s * 4 + lg) ^ l7;
            short8 pa = *reinterpret_cast<const short8*>(&pw[l15 * 64 + c * 8]);
            lacc = __builtin_amdgcn_mfma_f32_16x16x32_bf16(pa, bones, lacc, 0, 0, 0);
            #pragma unroll
            for (int dt = 0; dt < 4; ++dt) {
                int dh = dt * 16 + l15;
                short8 vb = *reinterpret_cast<const short8*>(
                    &Vs[cur][0] + dh * 64 + c * 8);
                oacc[dt] = __builtin_amdgcn_mfma_f32_16x16x32_bf16(pa, vb, oacc[dt], 0, 0, 0);
            }
        }

        __syncthreads();                     // buf[cur] free for stage(t+2)
        cur ^= 1;
        t = tn;
    }

    // epilogue: O[q][h*64+dh] = oacc / lacc, in place over Q
    float inv[4];
    #pragma unroll
    for (int j = 0; j < 4; ++j) inv[j] = 1.0f / lacc[j];
    #pragma unroll
    for (int t = 0; t < 4; ++t) {
        #pragma unroll
        for (int j = 0; j < 4; ++j) {
            size_t g = ((size_t)(b * SEQ + qbase + w * 16 + lg * 4 + j)) * DIM
                     + h * DHEAD + t * 16 + l15;
            QO[g] = f2bf(oacc[t][j] * inv[j]);
        }
    }
}

// ---------------- masked mean pool (reads single bf16 h') ------------------
__global__ __launch_bounds__(512)
void pool_kernel(const ushort* __restrict__ hh,
                 const float* __restrict__ maskA, float* __restrict__ pooled)
{
    int b  = blockIdx.x;
    int dq = blockIdx.y;
    int dl = threadIdx.x & 31;       // 32 d-pairs
    int sg = threadIdx.x >> 5;       // 0..15 s-group
    int d  = dq * 64 + dl * 2;
    float a0 = 0.f, a1 = 0.f, cnt = 0.f;
    for (int s = sg; s < SEQ; s += 16) {
        float mv = maskA[b * SEQ + s];
        if (mv == 0.f) continue;
        unsigned vh = *reinterpret_cast<const unsigned*>(
            &hh[((size_t)(b * SEQ + s)) * DIM + d]);
        a0 += bf2f((ushort)(vh & 0xffff));
        a1 += bf2f((ushort)(vh >> 16));
        cnt += 1.f;
    }
    __shared__ float r0[16][32];
    __shared__ float r1[16][32];
    __shared__ float rc[16];
    r0[sg][dl] = a0;
    r1[sg][dl] = a1;
    if (dl == 0) rc[sg] = cnt;
    __syncthreads();
    if (sg == 0) {
        float t0 = 0.f, t1 = 0.f, c = 0.f;
        #pragma unroll
        for (int g = 0; g < 16; ++g) { t0 += r0[g][dl]; t1 += r1[g][dl]; c += rc[g]; }
        float invc = 1.0f / fmaxf(c, 1.f);
        pooled[b * DIM + d]     = t0 * invc;
        pooled[b * DIM + d + 1] = t1 * invc;
    }
}

// ---------------- pooled @ Wp + bp -> henc row b ---------------------------
__global__ __launch_bounds__(512)
void proj_kernel(const float* __restrict__ pooled, const float* __restrict__ Wp,
                 const float* __restrict__ bp, float* __restrict__ henc)
{
    int b = blockIdx.x;
    int j = threadIdx.x;
    __shared__ float p[DIM];
    p[j] = pooled[b * DIM + j];
    __syncthreads();
    float a0 = 0.f, a1 = 0.f, a2 = 0.f, a3 = 0.f;
    for (int d = 0; d < DIM; d += 4) {
        a0 += p[d]     * Wp[(size_t)d       * DIM + j];
        a1 += p[d + 1] * Wp[(size_t)(d + 1) * DIM + j];
        a2 += p[d + 2] * Wp[(size_t)(d + 2) * DIM + j];
        a3 += p[d + 3] * Wp[(size_t)(d + 3) * DIM + j];
    }
    henc[(size_t)b * DIM + j] = ((a0 + a1) + (a2 + a3)) + bp[j];
}

// ---------------- logits = concat(hH,hF) @ W_out + b_out -------------------
__global__ __launch_bounds__(256)
void logits_kernel(const float* __restrict__ henc, const float* __restrict__ Wout,
                   const float* __restrict__ bout, float* __restrict__ logits)
{
    int b = blockIdx.y;
    int m = blockIdx.x * 256 + threadIdx.x;
    __shared__ float hh[2 * DIM];
    for (int j = threadIdx.x; j < DIM; j += 256) {
        hh[j]       = henc[(size_t)b * DIM + j];
        hh[DIM + j] = henc[(size_t)(BATCH + b) * DIM + j];
    }
    __syncthreads();
    if (m < MM) {
        float a0 = 0.f, a1 = 0.f, a2 = 0.f, a3 = 0.f;
        for (int j = 0; j < 2 * DIM; j += 4) {
            a0 += hh[j]     * Wout[(size_t)j       * MM + m];
            a1 += hh[j + 1] * Wout[(size_t)(j + 1) * MM + m];
            a2 += hh[j + 2] * Wout[(size_t)(j + 2) * MM + m];
            a3 += hh[j + 3] * Wout[(size_t)(j + 3) * MM + m];
        }
        logits[b * MM + m] = ((a0 + a1) + (a2 + a3)) + bout[m];
    }
}

// ---------------- softmax + argmax ----------------
__global__ __launch_bounds__(256)
void smax_kernel(const float* __restrict__ logits, float* __restrict__ out)
{
    int b   = blockIdx.x;
    int tid = threadIdx.x;
    __shared__ float red[256];
    __shared__ int   redi[256];

    float v[4];
    float mx = -INFINITY;
    #pragma unroll
    for (int i = 0; i < 4; i++) {
        int m = tid + i * 256;
        if (m < MM) { v[i] = logits[b * MM + m]; mx = fmaxf(mx, v[i]); }
        else v[i] = -INFINITY;
    }
    red[tid] = mx; __syncthreads();
    for (int st = 128; st > 0; st >>= 1) {
        if (tid < st) red[tid] = fmaxf(red[tid], red[tid + st]);
        __syncthreads();
    }
    mx = red[0]; __syncthreads();

    float sum = 0.f;
    #pragma unroll
    for (int i = 0; i < 4; i++) {
        int m = tid + i * 256;
        if (m < MM) { v[i] = expf(v[i] - mx); sum += v[i]; }
    }
    red[tid] = sum; __syncthreads();
    for (int st = 128; st > 0; st >>= 1) {
        if (tid < st) red[tid] += red[tid + st];
        __syncthreads();
    }
    float inv = 1.0f / red[0]; __syncthreads();

    float bestv = -INFINITY; int besti = 0x7fffffff;
    #pragma unroll
    for (int i = 0; i < 4; i++) {
        int m = tid + i * 256;
        if (m < MM) {
            float lam = v[i] * inv;
            out[b * MM + m] = lam;
            if (lam > bestv) { bestv = lam; besti = m; }
        }
    }
    red[tid] = bestv; redi[tid] = besti; __syncthreads();
    for (int st = 128; st > 0; st >>= 1) {
        if (tid < st) {
            float ov = red[tid + st]; int oi = redi[tid + st];
            if (ov > red[tid] || (ov == red[tid] && oi < redi[tid])) {
                red[tid] = ov; redi[tid] = oi;
            }
        }
        __syncthreads();
    }
    if (tid == 0) out[BATCH * MM + b] = (float)redi[0];
}

// ---------------------------------------------------------------------------
extern "C" void kernel_launch(void* const* d_in, const int* in_sizes, int n_in,
                              void* d_out, int out_size, void* d_ws, size_t ws_size,
                              hipStream_t stream)
{
    const float* xH   = (const float*)d_in[0];
    const float* xF   = (const float*)d_in[1];
    const float* Wm   = (const float*)d_in[2];
    const float* Wt   = (const float*)d_in[3];
    const float* bt   = (const float*)d_in[4];
    const float* Wq   = (const float*)d_in[5];
    const float* Wk   = (const float*)d_in[6];
    const float* Wv   = (const float*)d_in[7];
    const float* Wo   = (const float*)d_in[8];
    const float* W1   = (const float*)d_in[9];
    const float* b1   = (const float*)d_in[10];
    const float* W2   = (const float*)d_in[11];
    const float* b2   = (const float*)d_in[12];
    const float* Wp   = (const float*)d_in[13];
    const float* bp   = (const float*)d_in[14];
    const float* Wout = (const float*)d_in[15];
    const float* bout = (const float*)d_in[16];
    float* out = (float*)d_out;

    float* ws     = (float*)d_ws;
    float*  WmT    = ws + OFF_WMT;
    float*  maskA  = ws + OFF_MASK;
    float*  pooled = ws + OFF_POOL;
    float*  henc   = ws + OFF_HENC;
    float*  logits = ws + OFF_LOG;
    ushort* WqkvTh = (ushort*)(ws + OFF_WQTH);
    ushort* WoTh   = WqkvTh + (size_t)1536 * 512;
    ushort* W1Th   = (ushort*)(ws + OFF_W1TH);
    ushort* W2Th   = (ushort*)(ws + OFF_W2TH);
    ushort* ehi    = (ushort*)(ws + OFF_EHI);   // e -> h (pristine for FFN)
    ushort* Qb     = (ushort*)(ws + OFF_QB);    // Q -> O -> h' (single)
    ushort* Kb     = (ushort*)(ws + OFF_KB);
    ushort* Vtb    = (ushort*)(ws + OFF_VB);
    ushort* rbuf   = (ushort*)(ws + OFF_KB);    // [32768][2048] over Kb+Vtb+R2
                                                // (K, V^T dead after attn)

    // ---- fused setup ----
    setup_all<<<dim3(3584), 256, 0, stream>>>(
        Wm, Wq, Wk, Wv, Wo, W1, W2, WmT, WqkvTh, W1Th, W2Th);

    // ---- merged H+F pass (single-bf16 residual stream) ----
    embed_kernel<<<dim3(BROWS / 4), 256, 0, stream>>>(
        xH, xF, WmT, Wt, bt, ehi, maskA);
    // fused QKV: Q->Qb, K->Kb, V->Vtb (transposed per batch)
    gemm_bf16<false,false,false,true><<<dim3(12, 256), 256, 0, stream>>>(
        ehi, WqkvTh, nullptr, nullptr,
        Qb, Kb, Vtb, BROWS, 512, DIM, DIM, DIM, maskA);
    // MFMA attention, O overwrites Q
    attn_mfma<<<dim3(NHEAD, BB, 4), 512, 0, stream>>>(Qb, Kb, Vtb, maskA);
    // h = e + O @ Wo  (in place over ehi; single residual)
    gemm_bf16<false,false,true,false><<<dim3(4, 256), 256, 0, stream>>>(
        Qb, WoTh, nullptr, ehi,
        ehi, nullptr, nullptr, BROWS, DIM, DIM, DIM, DIM, maskA);
    // FFN single-shot (rbuf [32768][2048] over dead K+V^T+R2):
    //   W1: r = relu(h @ W1 + b1)        [one N=2048 launch]
    gemm_bf16<true,true,false,false><<<dim3(16, 256), 256, 0, stream>>>(
        ehi, W1Th, b1, nullptr,
        rbuf, nullptr, nullptr, BROWS, DFFN, DIM, DIM, DIM, maskA);
    //   W2: h' = h + r @ W2 + b2 -> Qb   [one K=2048 launch, 32 K-steps]
    gemm_bf16<true,false,true,false><<<dim3(4, 256), 256, 0, stream>>>(
        rbuf, W2Th, b2, ehi,
        Qb, nullptr, nullptr, BROWS, DIM, DFFN, DFFN, DFFN, maskA);
    // masked mean pool over h' (single bf16 in Qb; masked rows skipped)
    pool_kernel<<<dim3(BB, 8), 512, 0, stream>>>(Qb, maskA, pooled);
    proj_kernel<<<dim3(BB), 512, 0, stream>>>(pooled, Wp, bp, henc);
    logits_kernel<<<dim3(4, BATCH), 256, 0, stream>>>(henc, Wout, bout, logits);
    smax_kernel<<<dim3(BATCH), 256, 0, stream>>>(logits, out);
}

// Round 24
// 353.322 us; speedup vs baseline: 1.3929x; 1.0439x over previous
//
#include <hip/hip_runtime.h>
#include <math.h>

// Problem constants
#define BATCH 32
#define BB    64     // merged batch: rows 0..31 = H, 32..63 = F
#define SEQ  512
#define DIM  512
#define MM   1000
#define NHEAD 8
#define DHEAD 64
#define DFFN 2048
#define BROWS (BB * SEQ)     // 32768 rows (both passes)

typedef __attribute__((ext_vector_type(8))) short short8;
typedef __attribute__((ext_vector_type(4))) float f32x4;

__device__ __forceinline__ ushort f2bf(float x) {
    unsigned u = __builtin_bit_cast(unsigned, x);
    unsigned r = (u + 0x7FFFu + ((u >> 16) & 1u)) >> 16;
    return (ushort)r;
}
__device__ __forceinline__ float bf2f(ushort h) {
    unsigned u = ((unsigned)h) << 16;
    return __builtin_bit_cast(float, u);
}
// packed f32x2 -> bf16x2 (RTNE)
__device__ __forceinline__ unsigned cvtpk_bf16(float lo, float hi) {
    unsigned r;
    asm volatile("v_cvt_pk_bf16_f32 %0, %1, %2" : "=v"(r) : "v"(lo), "v"(hi));
    return r;
}

// async global->LDS, 16B per lane. LDS dest must be wave-uniform base
// (HW adds lane*16); global src is per-lane. [m97/m104 semantics]
#define GL2LDS(g, s) __builtin_amdgcn_global_load_lds( \
    (const __attribute__((address_space(1))) unsigned int*)(g), \
    (__attribute__((address_space(3))) unsigned int*)(s), 16, 0, 0)

// ---------------------------------------------------------------------------
// ws layout (float32-slot offsets) — 243.8 MB used of 256 MiB d_ws.
// Single-bf16 residual stream: ehi = e -> h (in-place Wo; pristine for W1).
// rbuf [32768][2048] spans Kb+Vtb+R2 (K, V^T dead after attention).
// W2 is POOL-FUSED: never stores h'; emits pooledPart[rowblk][b][col]
// (each slot written by exactly one block; all-masked blocks write zeros).
// ---------------------------------------------------------------------------
constexpr size_t OFF_WMT  = 0;         // fp32 [1000][512]
constexpr size_t OFF_MASK = 524288;    // fp32 [32768]
constexpr size_t OFF_POOL = 557056;    // (unused; kept for layout stability)
constexpr size_t OFF_HENC = 589824;    // fp32 [64][512]
constexpr size_t OFF_LOG  = 622592;    // fp32 [32][1000]
constexpr size_t OFF_WQTH = 655360;    // bf16 [2048][512] concat Wq|Wk|Wv|Wo
constexpr size_t OFF_W1TH = 1179648;   // bf16 [2048][512]
constexpr size_t OFF_W2TH = 1703936;   // bf16 [512][2048]
constexpr size_t OFF_EHI  = 2228224;   // bf16 [32768][512]  e -> h (pristine)
constexpr size_t OFF_PPART= 10616832;  // fp32 [4][64][512] pool partials
constexpr size_t OFF_QB   = 19005440;  // bf16 Q -> O
constexpr size_t OFF_KB   = 27394048;  // bf16 K; after attn: rbuf [32768][2048]
constexpr size_t OFF_VB   = 35782656;  // bf16 V^T [b][512][512] (in rbuf span)

// ---------------- fused setup: WmT + WqkvT + W1T + W2T ---------------------
__global__ __launch_bounds__(256)
void setup_all(const float* __restrict__ Wm,
               const float* __restrict__ Wq, const float* __restrict__ Wk,
               const float* __restrict__ Wv, const float* __restrict__ Wo,
               const float* __restrict__ W1, const float* __restrict__ W2,
               float* __restrict__ WmT, ushort* __restrict__ WqkvTh,
               ushort* __restrict__ W1Th, ushort* __restrict__ W2Th)
{
    __shared__ float tile[32][33];
    const int bid = blockIdx.x;
    const int tx = threadIdx.x & 31;
    const int ty = threadIdx.x >> 5;
    if (bid < 512) {                         // W_m [512,1000] -> [1000,512] f32
        int mx = (bid & 31) * 32, dy = (bid >> 5) * 32;
        for (int i = ty; i < 32; i += 8) {
            int d = dy + i, m = mx + tx;
            tile[i][tx] = (m < MM) ? Wm[(size_t)d * MM + m] : 0.f;
        }
        __syncthreads();
        for (int i = ty; i < 32; i += 8) {
            int m = mx + i, d = dy + tx;
            if (m < MM) WmT[(size_t)m * DIM + d] = tile[tx][i];
        }
    } else if (bid < 1536) {                 // Wq|Wk|Wv|Wo -> [2048][512] bf16
        int id = bid - 512;
        int n0 = (id & 63) * 32, k0 = (id >> 6) * 32;
        const float* W = (n0 < 512) ? Wq : (n0 < 1024) ? Wk
                       : (n0 < 1536) ? Wv : Wo;
        int nc = n0 & 511;
        for (int i = ty; i < 32; i += 8)
            tile[i][tx] = W[(size_t)(k0 + i) * 512 + nc + tx];
        __syncthreads();
        for (int i = ty; i < 32; i += 8)
            WqkvTh[(size_t)(n0 + i) * 512 + k0 + tx] = f2bf(tile[tx][i]);
    } else if (bid < 2560) {                 // W1 [512,2048] -> [2048][512]
        int id = bid - 1536;
        int n0 = (id & 63) * 32, k0 = (id >> 6) * 32;
        for (int i = ty; i < 32; i += 8)
            tile[i][tx] = W1[(size_t)(k0 + i) * DFFN + n0 + tx];
        __syncthreads();
        for (int i = ty; i < 32; i += 8)
            W1Th[(size_t)(n0 + i) * DIM + k0 + tx] = f2bf(tile[tx][i]);
    } else {                                 // W2 [2048,512] -> [512][2048]
        int id = bid - 2560;
        int n0 = (id & 15) * 32, k0 = (id >> 4) * 32;
        for (int i = ty; i < 32; i += 8)
            tile[i][tx] = W2[(size_t)(k0 + i) * DIM + n0 + tx];
        __syncthreads();
        for (int i = ty; i < 32; i += 8)
            W2Th[(size_t)(n0 + i) * DFFN + k0 + tx] = f2bf(tile[tx][i]);
    }
}

// ---------------- embedding + mask -> e bf16 (single, both passes) ---------
__global__ __launch_bounds__(256)
void embed_kernel(const float* __restrict__ xH, const float* __restrict__ xF,
                  const float* __restrict__ WmT, const float* __restrict__ Wt,
                  const float* __restrict__ bt,
                  ushort* __restrict__ ehi, float* __restrict__ maskA)
{
    int sub  = threadIdx.x >> 6;          // 0..3
    int lane = threadIdx.x & 63;          // 0..63
    int bs   = blockIdx.x * 4 + sub;      // 0..32767
    const float* xp = (bs < BATCH * SEQ) ? (xH + (size_t)bs * 2)
                                         : (xF + (size_t)(bs - BATCH * SEQ) * 2);
    float t   = xp[0];
    float mkf = xp[1];
    int   mk  = (int)fminf(fmaxf(mkf, 0.f), (float)(MM - 1));
    bool  valid = (t >= 0.f);
    if (lane == 0) maskA[bs] = valid ? 1.f : 0.f;
    const float* wrow = WmT + (size_t)mk * DIM + lane * 8;
    float4 w0 = *reinterpret_cast<const float4*>(wrow);
    float4 w1 = *reinterpret_cast<const float4*>(wrow + 4);
    float4 t0 = *reinterpret_cast<const float4*>(Wt + lane * 8);
    float4 t1 = *reinterpret_cast<const float4*>(Wt + lane * 8 + 4);
    float4 b0 = *reinterpret_cast<const float4*>(bt + lane * 8);
    float4 b1 = *reinterpret_cast<const float4*>(bt + lane * 8 + 4);
    float v[8];
    v[0] = w0.x * 0.5f + 0.5f * (t0.x * t + b0.x);
    v[1] = w0.y * 0.5f + 0.5f * (t0.y * t + b0.y);
    v[2] = w0.z * 0.5f + 0.5f * (t0.z * t + b0.z);
    v[3] = w0.w * 0.5f + 0.5f * (t0.w * t + b0.w);
    v[4] = w1.x * 0.5f + 0.5f * (t1.x * t + b1.x);
    v[5] = w1.y * 0.5f + 0.5f * (t1.y * t + b1.y);
    v[6] = w1.z * 0.5f + 0.5f * (t1.z * t + b1.z);
    v[7] = w1.w * 0.5f + 0.5f * (t1.w * t + b1.w);
    union { uint4 u; ushort s[8]; } ph;
    #pragma unroll
    for (int j = 0; j < 8; ++j)
        ph.s[j] = f2bf(valid ? v[j] : 0.f);
    *reinterpret_cast<uint4*>(ehi + (size_t)bs * DIM + lane * 8) = ph.u;
}

// ---------------- bf16 MFMA GEMM, 128x128 tile, 2-phase dbuf ---------------
// C[M,N] = A @ B^T [+bias] [+res] [relu], single bf16 out.
// TRIPLE: B concat [1536][512]; Q/K/V^T routed outputs.
// POOLF: pool-fused epilogue — no C store; per-block masked column sums
// -> pPart[rowblk][b][col] (skipped all-masked blocks write zeros).
template<bool BIAS, bool RELU, bool RES, bool TRIPLE, bool POOLF>
__global__ __launch_bounds__(256)
void gemm_bf16(const ushort* __restrict__ A0, const ushort* __restrict__ B0,
               const float* __restrict__ bias, const ushort* __restrict__ Rh,
               ushort* __restrict__ Oh, ushort* __restrict__ Ol,
               ushort* __restrict__ Ot, float* __restrict__ pPart,
               int Md, int Nd, int Kd, int lda, int ldb,
               const float* __restrict__ mrow)
{
    __shared__ __align__(16) ushort As[2][128 * 64];
    __shared__ __align__(16) ushort Bs[2][128 * 64];
    __shared__ float msk[128];
    __shared__ float poolred[128];
    const int tid = threadIdx.x;
    const int w = tid >> 6, l = tid & 63;
    const int wr = w >> 1, wc = w & 1;
    const int l15 = l & 15, lg = l >> 4;
    const int id  = blockIdx.x + gridDim.x * blockIdx.y;
    const int nwg = gridDim.x * gridDim.y;
    const int qc  = nwg >> 3;
    const int lin = (id & 7) * qc + (id >> 3);
    const int row0 = (lin / gridDim.x) * 128;
    const int col0 = (lin % gridDim.x) * 128;
    const int lrow   = l >> 3;
    const int gchunk = (l & 7) ^ lrow;

    if (mrow) {
        float mv = (tid < 128) ? mrow[row0 + tid] : 0.f;
        if (tid < 128 && POOLF) msk[tid] = mv;
        if (!__syncthreads_or(mv != 0.f)) {
            if (POOLF && tid < 128)          // dead block: zero its partial
                pPart[(((size_t)((row0 >> 7) & 3)) * 64 + (row0 >> 9)) * 512
                      + col0 + tid] = 0.f;
            return;
        }
    }

    f32x4 acc[4][4];
    #pragma unroll
    for (int m = 0; m < 4; m++)
        #pragma unroll
        for (int n = 0; n < 4; n++)
            acc[m][n] = (f32x4){0.f, 0.f, 0.f, 0.f};

    const int NT = Kd >> 6;
    int skt = 0;

    auto stage = [&](int bi) {
        ushort* Asb = &As[bi][0];
        ushort* Bsb = &Bs[bi][0];
        #pragma unroll
        for (int r = 0; r < 4; ++r) {
            int rowb = w * 32 + r * 8;
            int row  = rowb + lrow;
            GL2LDS(A0 + (size_t)(row0 + row) * lda + skt + gchunk * 8,
                   Asb + rowb * 64);
            GL2LDS(B0 + (size_t)(col0 + row) * ldb + skt + gchunk * 8,
                   Bsb + rowb * 64);
        }
        skt += 64;
    };

    stage(0);
    __syncthreads();

    for (int t = 0; t < NT; ++t) {
        const int cur = t & 1;
        if (t + 1 < NT) stage(cur ^ 1);
        const char* AsB = (const char*)&As[cur][0];
        const char* BsB = (const char*)&Bs[cur][0];
        #pragma unroll
        for (int ks = 0; ks < 2; ++ks) {
            const int g = ks * 4 + lg;
            short8 af[4], bfr[4];
            #pragma unroll
            for (int m = 0; m < 4; ++m) {
                int row = wr * 64 + m * 16 + l15;
                af[m] = *reinterpret_cast<const short8*>(
                    AsB + row * 128 + ((g ^ (row & 7)) << 4));
            }
            #pragma unroll
            for (int n = 0; n < 4; ++n) {
                int row = wc * 64 + n * 16 + l15;
                bfr[n] = *reinterpret_cast<const short8*>(
                    BsB + row * 128 + ((g ^ (row & 7)) << 4));
            }
            #pragma unroll
            for (int m = 0; m < 4; ++m)
                #pragma unroll
                for (int n = 0; n < 4; ++n)
                    acc[m][n] = __builtin_amdgcn_mfma_f32_16x16x32_bf16(
                        af[m], bfr[n], acc[m][n], 0, 0, 0);
        }
        __syncthreads();
    }

    if (POOLF) {
        // masked per-column sums of v = acc + bias + res over this block's
        // 128 rows; one partial row per block -> pPart[rowblk][b][col0..]
        if (tid < 128) poolred[tid] = 0.f;
        __syncthreads();
        #pragma unroll
        for (int n = 0; n < 4; ++n) {
            int colloc = wc * 64 + n * 16 + l15;
            int col = col0 + colloc;
            float bia = BIAS ? bias[col] : 0.f;
            float p = 0.f;
            #pragma unroll
            for (int m = 0; m < 4; ++m) {
                #pragma unroll
                for (int j = 0; j < 4; ++j) {
                    int rowloc = wr * 64 + m * 16 + lg * 4 + j;
                    float v = acc[m][n][j] + bia;
                    if (RES) v += bf2f(Rh[(size_t)(row0 + rowloc) * Nd + col]);
                    p += v * msk[rowloc];
                }
            }
            atomicAdd(&poolred[colloc], p);
        }
        __syncthreads();
        if (tid < 128)
            pPart[(((size_t)((row0 >> 7) & 3)) * 64 + (row0 >> 9)) * 512
                  + col0 + tid] = poolred[tid];
        return;
    }

    #pragma unroll
    for (int m = 0; m < 4; ++m) {
        #pragma unroll
        for (int n = 0; n < 4; ++n) {
            int col = col0 + wc * 64 + n * 16 + l15;
            if (TRIPLE) {
                if (col0 < 512) {
                    #pragma unroll
                    for (int j = 0; j < 4; ++j) {
                        int row = row0 + wr * 64 + m * 16 + lg * 4 + j;
                        Oh[(size_t)row * 512 + col] = f2bf(acc[m][n][j]);
                    }
                } else if (col0 < 1024) {
                    #pragma unroll
                    for (int j = 0; j < 4; ++j) {
                        int row = row0 + wr * 64 + m * 16 + lg * 4 + j;
                        Ol[(size_t)row * 512 + (col - 512)] = f2bf(acc[m][n][j]);
                    }
                } else {
                    union { uint2 u; ushort s4[4]; } pk;
                    #pragma unroll
                    for (int j = 0; j < 4; ++j) pk.s4[j] = f2bf(acc[m][n][j]);
                    int brow = row0 + wr * 64 + m * 16 + lg * 4;
                    size_t idx = ((size_t)(brow >> 9) << 18)
                               + (size_t)(col - 1024) * SEQ + (brow & 511);
                    *reinterpret_cast<uint2*>(Ot + idx) = pk.u;
                }
            } else {
                float bia = 0.f;
                if (BIAS) bia = bias[col];
                #pragma unroll
                for (int j = 0; j < 4; ++j) {
                    int row = row0 + wr * 64 + m * 16 + lg * 4 + j;
                    size_t idx = (size_t)row * Nd + col;
                    float v = acc[m][n][j] + bia;
                    if (RES)  v += bf2f(Rh[idx]);
                    if (RELU) v = fmaxf(v, 0.f);
                    Oh[idx] = f2bf(v);
                }
            }
        }
    }
}

// ---------------- MFMA flash attention, 128 q-rows, KV dbuf, static-max ----
// (unchanged from r21-23 — proven)
__global__ __launch_bounds__(512)
void attn_mfma(ushort* __restrict__ QO, const ushort* __restrict__ K,
               const ushort* __restrict__ Vt, const float* __restrict__ maskA)
{
    __shared__ __align__(16) ushort Ks[2][64 * 64];   // [buf][kv][dh]
    __shared__ __align__(16) ushort Vs[2][64 * 64];   // [buf][dh][kv]
    __shared__ __align__(16) ushort Pl[8][16 * 64];   // [wave][q][kv] (Q alias)
    __shared__ float ms[512];
    const int h   = blockIdx.x;
    const int b   = blockIdx.y;
    const int qt  = blockIdx.z;
    const int tid = threadIdx.x;
    const int w = tid >> 6, l = tid & 63;
    const int l15 = l & 15, lg = l >> 4, l7 = l & 7;
    const int lrow   = l >> 3;
    const int gchunk = (l & 7) ^ lrow;
    const int qbase = qt * 128;

    // stage Q tile [128 q][64 dh] into Pl (dead until first P write)
    #pragma unroll
    for (int rr = 0; rr < 2; ++rr) {
        int rowb = rr * 64 + w * 8;             // 16 stripes, wave-uniform
        GL2LDS(QO + ((size_t)(b * SEQ + qbase + rowb + lrow)) * DIM
                  + h * DHEAD + gchunk * 8,
               &Pl[0][0] + rowb * 64);
    }
    // full mask row -> LDS (published by the q-skip barrier below)
    ms[tid] = maskA[b * SEQ + tid];
    // dead q-tile skip (global reads; barrier also drains Q-stage + ms)
    float qm = (tid < 128) ? maskA[b * SEQ + qbase + tid] : 0.f;
    if (!__syncthreads_or(qm != 0.f)) return;

    // per-64-kv-tile valid bits (block-uniform)
    unsigned hbits = 0;
    #pragma unroll
    for (int t = 0; t < 8; ++t) {
        int mine = (tid < 64) ? (ms[t * 64 + tid] != 0.f) : 0;
        if (__syncthreads_or(mine)) hbits |= (1u << t);
    }

    // hoist Q A-frags (reads Pl BEFORE any P write); wave w rows w*16+l15
    short8 af[2];
    #pragma unroll
    for (int s = 0; s < 2; ++s) {
        int q = w * 16 + l15;
        int c = (s * 4 + lg) ^ l7;
        af[s] = *reinterpret_cast<const short8*>(&Pl[0][0] + q * 64 + c * 8);
    }

    // all-ones bf16 B operand for row-sum MFMA
    short8 bones;
    #pragma unroll
    for (int i = 0; i < 8; ++i) bones[i] = (short)0x3F80;

    f32x4 oacc[4];
    #pragma unroll
    for (int t = 0; t < 4; ++t) oacc[t] = (f32x4){0.f, 0.f, 0.f, 0.f};
    f32x4 lacc = (f32x4){0.f, 0.f, 0.f, 0.f};   // row-sums of P

    ushort* pw = &Pl[w][0];

    auto stagekv = [&](int t, int bi) {
        int kv0 = t * 64;
        GL2LDS(K + ((size_t)(b * SEQ + kv0 + w * 8 + lrow)) * DIM
                 + h * DHEAD + gchunk * 8,
               &Ks[bi][0] + w * 8 * 64);
        GL2LDS(Vt + ((size_t)b << 18) + (size_t)(h * DHEAD + w * 8 + lrow) * SEQ
                  + kv0 + gchunk * 8,
               &Vs[bi][0] + w * 8 * 64);
    };

    int t0 = 0;
    while (t0 < 8 && !(hbits & (1u << t0))) ++t0;
    stagekv(t0, 0);
    __syncthreads();                         // tile t0 K/V ready
    int cur = 0;
    for (int t = t0; t < 8; ) {
        int tn = t + 1;
        while (tn < 8 && !(hbits & (1u << tn))) ++tn;
        if (tn < 8) stagekv(tn, cur ^ 1);    // async prefetch next valid tile

        // QK^T: 4 kv16-tiles x 2 k-steps
        f32x4 sacc[4];
        #pragma unroll
        for (int t4 = 0; t4 < 4; ++t4) sacc[t4] = (f32x4){0.f, 0.f, 0.f, 0.f};
        #pragma unroll
        for (int s = 0; s < 2; ++s) {
            int c = (s * 4 + lg) ^ l7;
            #pragma unroll
            for (int t4 = 0; t4 < 4; ++t4) {
                int kv = t4 * 16 + l15;
                short8 bf = *reinterpret_cast<const short8*>(
                    &Ks[cur][0] + kv * 64 + c * 8);
                sacc[t4] = __builtin_amdgcn_mfma_f32_16x16x32_bf16(af[s], bf, sacc[t4], 0, 0, 0);
            }
        }

        // static-max softmax: p = mask * exp(s/8)
        float mk[4];
        #pragma unroll
        for (int t4 = 0; t4 < 4; ++t4) mk[t4] = ms[t * 64 + t4 * 16 + l15];
        #pragma unroll
        for (int t4 = 0; t4 < 4; ++t4)
            #pragma unroll
            for (int j = 0; j < 4; ++j)
                sacc[t4][j] = mk[t4] * __expf(sacc[t4][j] * 0.125f);

        // P (bf16) -> per-wave LDS [16 q][64 kv], chunk-XOR swizzle;
        // pairs packed with v_cvt_pk_bf16_f32
        #pragma unroll
        for (int t4 = 0; t4 < 4; ++t4) {
            int kvh = t4 * 16 + l15;
            int base = (kvh & 7);
            int hi3  = (kvh >> 3);
            #pragma unroll
            for (int jp = 0; jp < 4; jp += 2) {
                unsigned u = cvtpk_bf16(sacc[t4][jp], sacc[t4][jp + 1]);
                int q0 = lg * 4 + jp;
                int q1 = q0 + 1;
                pw[q0 * 64 + base + ((hi3 ^ (q0 & 7)) << 3)] = (ushort)u;
                pw[q1 * 64 + base + ((hi3 ^ (q1 & 7)) << 3)] = (ushort)(u >> 16);
            }
        }

        // PV + row-sum: A = P[16 q][64 kv]; B = Vs[dh][kv] and ones
        #pragma unroll
        for (int s = 0; s < 2; ++s) {
            int c = (s * 4 + lg) ^ l7;
            short8 pa = *reinterpret_cast<const short8*>(&pw[l15 * 64 + c * 8]);
            lacc = __builtin_amdgcn_mfma_f32_16x16x32_bf16(pa, bones, lacc, 0, 0, 0);
            #pragma unroll
            for (int dt = 0; dt < 4; ++dt) {
                int dh = dt * 16 + l15;
                short8 vb = *reinterpret_cast<const short8*>(
                    &Vs[cur][0] + dh * 64 + c * 8);
                oacc[dt] = __builtin_amdgcn_mfma_f32_16x16x32_bf16(pa, vb, oacc[dt], 0, 0, 0);
            }
        }

        __syncthreads();                     // buf[cur] free for stage(t+2)
        cur ^= 1;
        t = tn;
    }

    // epilogue: O[q][h*64+dh] = oacc / lacc, in place over Q
    float inv[4];
    #pragma unroll
    for (int j = 0; j < 4; ++j) inv[j] = 1.0f / lacc[j];
    #pragma unroll
    for (int t = 0; t < 4; ++t) {
        #pragma unroll
        for (int j = 0; j < 4; ++j) {
            size_t g = ((size_t)(b * SEQ + qbase + w * 16 + lg * 4 + j)) * DIM
                     + h * DHEAD + t * 16 + l15;
            QO[g] = f2bf(oacc[t][j] * inv[j]);
        }
    }
}

// ---------------- proj: pooled (from partials) @ Wp + bp -> henc -----------
__global__ __launch_bounds__(512)
void proj_kernel(const float* __restrict__ pPart, const float* __restrict__ maskA,
                 const float* __restrict__ Wp, const float* __restrict__ bp,
                 float* __restrict__ henc)
{
    int b = blockIdx.x;     // 0..63
    int j = threadIdx.x;    // 0..511
    __shared__ float p[DIM];
    __shared__ float cs[512];
    // count of valid rows for this b
    cs[j] = maskA[b * SEQ + j];
    __syncthreads();
    for (int st = 256; st > 0; st >>= 1) {
        if (j < st) cs[j] += cs[j + st];
        __syncthreads();
    }
    float invc = 1.0f / fmaxf(cs[0], 1.f);
    __syncthreads();
    // sum 4 row-block partials, divide by count
    float s = pPart[((size_t)0 * 64 + b) * 512 + j]
            + pPart[((size_t)1 * 64 + b) * 512 + j]
            + pPart[((size_t)2 * 64 + b) * 512 + j]
            + pPart[((size_t)3 * 64 + b) * 512 + j];
    p[j] = s * invc;
    __syncthreads();
    float a0 = 0.f, a1 = 0.f, a2 = 0.f, a3 = 0.f;
    for (int d = 0; d < DIM; d += 4) {
        a0 += p[d]     * Wp[(size_t)d       * DIM + j];
        a1 += p[d + 1] * Wp[(size_t)(d + 1) * DIM + j];
        a2 += p[d + 2] * Wp[(size_t)(d + 2) * DIM + j];
        a3 += p[d + 3] * Wp[(size_t)(d + 3) * DIM + j];
    }
    henc[(size_t)b * DIM + j] = ((a0 + a1) + (a2 + a3)) + bp[j];
}

// ---------------- logits = concat(hH,hF) @ W_out + b_out -------------------
__global__ __launch_bounds__(256)
void logits_kernel(const float* __restrict__ henc, const float* __restrict__ Wout,
                   const float* __restrict__ bout, float* __restrict__ logits)
{
    int b = blockIdx.y;
    int m = blockIdx.x * 256 + threadIdx.x;
    __shared__ float hh[2 * DIM];
    for (int j = threadIdx.x; j < DIM; j += 256) {
        hh[j]       = henc[(size_t)b * DIM + j];
        hh[DIM + j] = henc[(size_t)(BATCH + b) * DIM + j];
    }
    __syncthreads();
    if (m < MM) {
        float a0 = 0.f, a1 = 0.f, a2 = 0.f, a3 = 0.f;
        for (int j = 0; j < 2 * DIM; j += 4) {
            a0 += hh[j]     * Wout[(size_t)j       * MM + m];
            a1 += hh[j + 1] * Wout[(size_t)(j + 1) * MM + m];
            a2 += hh[j + 2] * Wout[(size_t)(j + 2) * MM + m];
            a3 += hh[j + 3] * Wout[(size_t)(j + 3) * MM + m];
        }
        logits[b * MM + m] = ((a0 + a1) + (a2 + a3)) + bout[m];
    }
}

// ---------------- softmax + argmax ----------------
__global__ __launch_bounds__(256)
void smax_kernel(const float* __restrict__ logits, float* __restrict__ out)
{
    int b   = blockIdx.x;
    int tid = threadIdx.x;
    __shared__ float red[256];
    __shared__ int   redi[256];

    float v[4];
    float mx = -INFINITY;
    #pragma unroll
    for (int i = 0; i < 4; i++) {
        int m = tid + i * 256;
        if (m < MM) { v[i] = logits[b * MM + m]; mx = fmaxf(mx, v[i]); }
        else v[i] = -INFINITY;
    }
    red[tid] = mx; __syncthreads();
    for (int st = 128; st > 0; st >>= 1) {
        if (tid < st) red[tid] = fmaxf(red[tid], red[tid + st]);
        __syncthreads();
    }
    mx = red[0]; __syncthreads();

    float sum = 0.f;
    #pragma unroll
    for (int i = 0; i < 4; i++) {
        int m = tid + i * 256;
        if (m < MM) { v[i] = expf(v[i] - mx); sum += v[i]; }
    }
    red[tid] = sum; __syncthreads();
    for (int st = 128; st > 0; st >>= 1) {
        if (tid < st) red[tid] += red[tid + st];
        __syncthreads();
    }
    float inv = 1.0f / red[0]; __syncthreads();

    float bestv = -INFINITY; int besti = 0x7fffffff;
    #pragma unroll
    for (int i = 0; i < 4; i++) {
        int m = tid + i * 256;
        if (m < MM) {
            float lam = v[i] * inv;
            out[b * MM + m] = lam;
            if (lam > bestv) { bestv = lam; besti = m; }
        }
    }
    red[tid] = bestv; redi[tid] = besti; __syncthreads();
    for (int st = 128; st > 0; st >>= 1) {
        if (tid < st) {
            float ov = red[tid + st]; int oi = redi[tid + st];
            if (ov > red[tid] || (ov == red[tid] && oi < redi[tid])) {
                red[tid] = ov; redi[tid] = oi;
            }
        }
        __syncthreads();
    }
    if (tid == 0) out[BATCH * MM + b] = (float)redi[0];
}

// ---------------------------------------------------------------------------
extern "C" void kernel_launch(void* const* d_in, const int* in_sizes, int n_in,
                              void* d_out, int out_size, void* d_ws, size_t ws_size,
                              hipStream_t stream)
{
    const float* xH   = (const float*)d_in[0];
    const float* xF   = (const float*)d_in[1];
    const float* Wm   = (const float*)d_in[2];
    const float* Wt   = (const float*)d_in[3];
    const float* bt   = (const float*)d_in[4];
    const float* Wq   = (const float*)d_in[5];
    const float* Wk   = (const float*)d_in[6];
    const float* Wv   = (const float*)d_in[7];
    const float* Wo   = (const float*)d_in[8];
    const float* W1   = (const float*)d_in[9];
    const float* b1   = (const float*)d_in[10];
    const float* W2   = (const float*)d_in[11];
    const float* b2   = (const float*)d_in[12];
    const float* Wp   = (const float*)d_in[13];
    const float* bp   = (const float*)d_in[14];
    const float* Wout = (const float*)d_in[15];
    const float* bout = (const float*)d_in[16];
    float* out = (float*)d_out;

    float* ws     = (float*)d_ws;
    float*  WmT    = ws + OFF_WMT;
    float*  maskA  = ws + OFF_MASK;
    float*  henc   = ws + OFF_HENC;
    float*  logits = ws + OFF_LOG;
    float*  pPart  = ws + OFF_PPART;            // fp32 [4][64][512]
    ushort* WqkvTh = (ushort*)(ws + OFF_WQTH);
    ushort* WoTh   = WqkvTh + (size_t)1536 * 512;
    ushort* W1Th   = (ushort*)(ws + OFF_W1TH);
    ushort* W2Th   = (ushort*)(ws + OFF_W2TH);
    ushort* ehi    = (ushort*)(ws + OFF_EHI);   // e -> h (pristine for FFN)
    ushort* Qb     = (ushort*)(ws + OFF_QB);    // Q -> O
    ushort* Kb     = (ushort*)(ws + OFF_KB);
    ushort* Vtb    = (ushort*)(ws + OFF_VB);
    ushort* rbuf   = (ushort*)(ws + OFF_KB);    // [32768][2048] over Kb+Vtb+R2

    // ---- fused setup ----
    setup_all<<<dim3(3584), 256, 0, stream>>>(
        Wm, Wq, Wk, Wv, Wo, W1, W2, WmT, WqkvTh, W1Th, W2Th);

    // ---- merged H+F pass (single-bf16 residual stream) ----
    embed_kernel<<<dim3(BROWS / 4), 256, 0, stream>>>(
        xH, xF, WmT, Wt, bt, ehi, maskA);
    // fused QKV: Q->Qb, K->Kb, V->Vtb (transposed per batch)
    gemm_bf16<false,false,false,true,false><<<dim3(12, 256), 256, 0, stream>>>(
        ehi, WqkvTh, nullptr, nullptr,
        Qb, Kb, Vtb, nullptr, BROWS, 512, DIM, DIM, DIM, maskA);
    // MFMA attention, O overwrites Q
    attn_mfma<<<dim3(NHEAD, BB, 4), 512, 0, stream>>>(Qb, Kb, Vtb, maskA);
    // h = e + O @ Wo  (in place over ehi; single residual)
    gemm_bf16<false,false,true,false,false><<<dim3(4, 256), 256, 0, stream>>>(
        Qb, WoTh, nullptr, ehi,
        ehi, nullptr, nullptr, nullptr, BROWS, DIM, DIM, DIM, DIM, maskA);
    // FFN single-shot (rbuf [32768][2048] over dead K+V^T+R2):
    //   W1: r = relu(h @ W1 + b1)
    gemm_bf16<true,true,false,false,false><<<dim3(16, 256), 256, 0, stream>>>(
        ehi, W1Th, b1, nullptr,
        rbuf, nullptr, nullptr, nullptr, BROWS, DFFN, DIM, DIM, DIM, maskA);
    //   W2 POOL-FUSED: masked column-sums of (h + r@W2 + b2) -> pPart
    gemm_bf16<true,false,true,false,true><<<dim3(4, 256), 256, 0, stream>>>(
        rbuf, W2Th, b2, ehi,
        nullptr, nullptr, nullptr, pPart, BROWS, DIM, DFFN, DFFN, DFFN, maskA);
    // proj: pooled = sum(partials)/cnt; henc = pooled @ Wp + bp
    proj_kernel<<<dim3(BB), 512, 0, stream>>>(pPart, maskA, Wp, bp, henc);
    logits_kernel<<<dim3(4, BATCH), 256, 0, stream>>>(henc, Wout, bout, logits);
    smax_kernel<<<dim3(BATCH), 256, 0, stream>>>(logits, out);
}

// Round 25
// 352.833 us; speedup vs baseline: 1.3948x; 1.0014x over previous
//
#include <hip/hip_runtime.h>
#include <math.h>

// Problem constants
#define BATCH 32
#define BB    64     // merged batch: rows 0..31 = H, 32..63 = F
#define SEQ  512
#define DIM  512
#define MM   1000
#define NHEAD 8
#define DHEAD 64
#define DFFN 2048
#define BROWS (BB * SEQ)     // 32768 rows (both passes)

typedef __attribute__((ext_vector_type(8))) short short8;
typedef __attribute__((ext_vector_type(4))) float f32x4;

__device__ __forceinline__ ushort f2bf(float x) {
    unsigned u = __builtin_bit_cast(unsigned, x);
    unsigned r = (u + 0x7FFFu + ((u >> 16) & 1u)) >> 16;
    return (ushort)r;
}
__device__ __forceinline__ float bf2f(ushort h) {
    unsigned u = ((unsigned)h) << 16;
    return __builtin_bit_cast(float, u);
}
// packed f32x2 -> bf16x2 (RTNE)
__device__ __forceinline__ unsigned cvtpk_bf16(float lo, float hi) {
    unsigned r;
    asm volatile("v_cvt_pk_bf16_f32 %0, %1, %2" : "=v"(r) : "v"(lo), "v"(hi));
    return r;
}

// async global->LDS, 16B per lane. LDS dest must be wave-uniform base
// (HW adds lane*16); global src is per-lane. [m97/m104 semantics]
#define GL2LDS(g, s) __builtin_amdgcn_global_load_lds( \
    (const __attribute__((address_space(1))) unsigned int*)(g), \
    (__attribute__((address_space(3))) unsigned int*)(s), 16, 0, 0)

// ---------------------------------------------------------------------------
// ws layout (float32-slot offsets) — 243.8 MB used of 256 MiB d_ws.
// Single-bf16 residual stream: ehi = e -> h (in-place Wo; pristine for W1).
// rbuf [32768][2048] spans Kb+Vtb+R2. W2 POOL-FUSED (no h' store).
// ---------------------------------------------------------------------------
constexpr size_t OFF_WMT  = 0;         // fp32 [1000][512]
constexpr size_t OFF_MASK = 524288;    // fp32 [32768]
constexpr size_t OFF_HENC = 589824;    // fp32 [64][512]
constexpr size_t OFF_LOG  = 622592;    // fp32 [32][1000]
constexpr size_t OFF_WQTH = 655360;    // bf16 [2048][512] concat Wq|Wk|Wv|Wo
constexpr size_t OFF_W1TH = 1179648;   // bf16 [2048][512]
constexpr size_t OFF_W2TH = 1703936;   // bf16 [512][2048]
constexpr size_t OFF_EHI  = 2228224;   // bf16 [32768][512]  e -> h (pristine)
constexpr size_t OFF_PPART= 10616832;  // fp32 [4][64][512] pool partials
constexpr size_t OFF_QB   = 19005440;  // bf16 Q -> O
constexpr size_t OFF_KB   = 27394048;  // bf16 K; after attn: rbuf [32768][2048]
constexpr size_t OFF_VB   = 35782656;  // bf16 V^T [b][512][512] (in rbuf span)

// ---------------- fused setup: WmT + WqkvT + W1T + W2T ---------------------
__global__ __launch_bounds__(256)
void setup_all(const float* __restrict__ Wm,
               const float* __restrict__ Wq, const float* __restrict__ Wk,
               const float* __restrict__ Wv, const float* __restrict__ Wo,
               const float* __restrict__ W1, const float* __restrict__ W2,
               float* __restrict__ WmT, ushort* __restrict__ WqkvTh,
               ushort* __restrict__ W1Th, ushort* __restrict__ W2Th)
{
    __shared__ float tile[32][33];
    const int bid = blockIdx.x;
    const int tx = threadIdx.x & 31;
    const int ty = threadIdx.x >> 5;
    if (bid < 512) {                         // W_m [512,1000] -> [1000,512] f32
        int mx = (bid & 31) * 32, dy = (bid >> 5) * 32;
        for (int i = ty; i < 32; i += 8) {
            int d = dy + i, m = mx + tx;
            tile[i][tx] = (m < MM) ? Wm[(size_t)d * MM + m] : 0.f;
        }
        __syncthreads();
        for (int i = ty; i < 32; i += 8) {
            int m = mx + i, d = dy + tx;
            if (m < MM) WmT[(size_t)m * DIM + d] = tile[tx][i];
        }
    } else if (bid < 1536) {                 // Wq|Wk|Wv|Wo -> [2048][512] bf16
        int id = bid - 512;
        int n0 = (id & 63) * 32, k0 = (id >> 6) * 32;
        const float* W = (n0 < 512) ? Wq : (n0 < 1024) ? Wk
                       : (n0 < 1536) ? Wv : Wo;
        int nc = n0 & 511;
        for (int i = ty; i < 32; i += 8)
            tile[i][tx] = W[(size_t)(k0 + i) * 512 + nc + tx];
        __syncthreads();
        for (int i = ty; i < 32; i += 8)
            WqkvTh[(size_t)(n0 + i) * 512 + k0 + tx] = f2bf(tile[tx][i]);
    } else if (bid < 2560) {                 // W1 [512,2048] -> [2048][512]
        int id = bid - 1536;
        int n0 = (id & 63) * 32, k0 = (id >> 6) * 32;
        for (int i = ty; i < 32; i += 8)
            tile[i][tx] = W1[(size_t)(k0 + i) * DFFN + n0 + tx];
        __syncthreads();
        for (int i = ty; i < 32; i += 8)
            W1Th[(size_t)(n0 + i) * DIM + k0 + tx] = f2bf(tile[tx][i]);
    } else {                                 // W2 [2048,512] -> [512][2048]
        int id = bid - 2560;
        int n0 = (id & 15) * 32, k0 = (id >> 4) * 32;
        for (int i = ty; i < 32; i += 8)
            tile[i][tx] = W2[(size_t)(k0 + i) * DIM + n0 + tx];
        __syncthreads();
        for (int i = ty; i < 32; i += 8)
            W2Th[(size_t)(n0 + i) * DFFN + k0 + tx] = f2bf(tile[tx][i]);
    }
}

// ---------------- embedding + mask -> e bf16 (single, both passes) ---------
__global__ __launch_bounds__(256)
void embed_kernel(const float* __restrict__ xH, const float* __restrict__ xF,
                  const float* __restrict__ WmT, const float* __restrict__ Wt,
                  const float* __restrict__ bt,
                  ushort* __restrict__ ehi, float* __restrict__ maskA)
{
    int sub  = threadIdx.x >> 6;          // 0..3
    int lane = threadIdx.x & 63;          // 0..63
    int bs   = blockIdx.x * 4 + sub;      // 0..32767
    const float* xp = (bs < BATCH * SEQ) ? (xH + (size_t)bs * 2)
                                         : (xF + (size_t)(bs - BATCH * SEQ) * 2);
    float t   = xp[0];
    float mkf = xp[1];
    int   mk  = (int)fminf(fmaxf(mkf, 0.f), (float)(MM - 1));
    bool  valid = (t >= 0.f);
    if (lane == 0) maskA[bs] = valid ? 1.f : 0.f;
    const float* wrow = WmT + (size_t)mk * DIM + lane * 8;
    float4 w0 = *reinterpret_cast<const float4*>(wrow);
    float4 w1 = *reinterpret_cast<const float4*>(wrow + 4);
    float4 t0 = *reinterpret_cast<const float4*>(Wt + lane * 8);
    float4 t1 = *reinterpret_cast<const float4*>(Wt + lane * 8 + 4);
    float4 b0 = *reinterpret_cast<const float4*>(bt + lane * 8);
    float4 b1 = *reinterpret_cast<const float4*>(bt + lane * 8 + 4);
    float v[8];
    v[0] = w0.x * 0.5f + 0.5f * (t0.x * t + b0.x);
    v[1] = w0.y * 0.5f + 0.5f * (t0.y * t + b0.y);
    v[2] = w0.z * 0.5f + 0.5f * (t0.z * t + b0.z);
    v[3] = w0.w * 0.5f + 0.5f * (t0.w * t + b0.w);
    v[4] = w1.x * 0.5f + 0.5f * (t1.x * t + b1.x);
    v[5] = w1.y * 0.5f + 0.5f * (t1.y * t + b1.y);
    v[6] = w1.z * 0.5f + 0.5f * (t1.z * t + b1.z);
    v[7] = w1.w * 0.5f + 0.5f * (t1.w * t + b1.w);
    union { uint4 u; ushort s[8]; } ph;
    #pragma unroll
    for (int j = 0; j < 8; ++j)
        ph.s[j] = f2bf(valid ? v[j] : 0.f);
    *reinterpret_cast<uint4*>(ehi + (size_t)bs * DIM + lane * 8) = ph.u;
}

// ---------------- bf16 MFMA GEMM, 128x128 tile, 2-phase dbuf ---------------
// C[M,N] = A @ B^T [+bias] [+res] [relu], single bf16 out.
// TRIPLE: B concat [1536][512]; Q/K/V^T routed outputs.
// POOLF: pool-fused epilogue (no C store) -> pPart.
// r25: VECTORIZED STORE EPILOGUE (non-POOLF, non-V^T): acc scattered into a
// wave-private padded LDS tile (64x72, aliases dead staging LDS; same-wave
// in-order so no barrier), read back as aligned 16B row-chunks, stored as
// global_store_dwordx4 (8 per thread vs 64 scalar 2B). RES applied
// vectorized at readback (one extra bf16 rounding, <=1 ulp).
template<bool BIAS, bool RELU, bool RES, bool TRIPLE, bool POOLF>
__global__ __launch_bounds__(256)
void gemm_bf16(const ushort* __restrict__ A0, const ushort* __restrict__ B0,
               const float* __restrict__ bias, const ushort* __restrict__ Rh,
               ushort* __restrict__ Oh, ushort* __restrict__ Ol,
               ushort* __restrict__ Ot, float* __restrict__ pPart,
               int Md, int Nd, int Kd, int lda, int ldb,
               const float* __restrict__ mrow)
{
    __shared__ __align__(16) ushort SM[4 * 128 * 64];   // As[2] | Bs[2], 64 KB
    __shared__ float msk[128];
    __shared__ float poolred[128];
    const int tid = threadIdx.x;
    const int w = tid >> 6, l = tid & 63;
    const int wr = w >> 1, wc = w & 1;
    const int l15 = l & 15, lg = l >> 4;
    const int id  = blockIdx.x + gridDim.x * blockIdx.y;
    const int nwg = gridDim.x * gridDim.y;
    const int qc  = nwg >> 3;
    const int lin = (id & 7) * qc + (id >> 3);
    const int row0 = (lin / gridDim.x) * 128;
    const int col0 = (lin % gridDim.x) * 128;
    const int lrow   = l >> 3;
    const int gchunk = (l & 7) ^ lrow;

    if (mrow) {
        float mv = (tid < 128) ? mrow[row0 + tid] : 0.f;
        if (tid < 128 && POOLF) msk[tid] = mv;
        if (!__syncthreads_or(mv != 0.f)) {
            if (POOLF && tid < 128)          // dead block: zero its partial
                pPart[(((size_t)((row0 >> 7) & 3)) * 64 + (row0 >> 9)) * 512
                      + col0 + tid] = 0.f;
            return;
        }
    }

    f32x4 acc[4][4];
    #pragma unroll
    for (int m = 0; m < 4; m++)
        #pragma unroll
        for (int n = 0; n < 4; n++)
            acc[m][n] = (f32x4){0.f, 0.f, 0.f, 0.f};

    const int NT = Kd >> 6;
    int skt = 0;

    auto stage = [&](int bi) {
        ushort* Asb = SM + bi * (128 * 64);
        ushort* Bsb = SM + (2 + bi) * (128 * 64);
        #pragma unroll
        for (int r = 0; r < 4; ++r) {
            int rowb = w * 32 + r * 8;
            int row  = rowb + lrow;
            GL2LDS(A0 + (size_t)(row0 + row) * lda + skt + gchunk * 8,
                   Asb + rowb * 64);
            GL2LDS(B0 + (size_t)(col0 + row) * ldb + skt + gchunk * 8,
                   Bsb + rowb * 64);
        }
        skt += 64;
    };

    stage(0);
    __syncthreads();

    for (int t = 0; t < NT; ++t) {
        const int cur = t & 1;
        if (t + 1 < NT) stage(cur ^ 1);
        const char* AsB = (const char*)(SM + cur * (128 * 64));
        const char* BsB = (const char*)(SM + (2 + cur) * (128 * 64));
        #pragma unroll
        for (int ks = 0; ks < 2; ++ks) {
            const int g = ks * 4 + lg;
            short8 af[4], bfr[4];
            #pragma unroll
            for (int m = 0; m < 4; ++m) {
                int row = wr * 64 + m * 16 + l15;
                af[m] = *reinterpret_cast<const short8*>(
                    AsB + row * 128 + ((g ^ (row & 7)) << 4));
            }
            #pragma unroll
            for (int n = 0; n < 4; ++n) {
                int row = wc * 64 + n * 16 + l15;
                bfr[n] = *reinterpret_cast<const short8*>(
                    BsB + row * 128 + ((g ^ (row & 7)) << 4));
            }
            #pragma unroll
            for (int m = 0; m < 4; ++m)
                #pragma unroll
                for (int n = 0; n < 4; ++n)
                    acc[m][n] = __builtin_amdgcn_mfma_f32_16x16x32_bf16(
                        af[m], bfr[n], acc[m][n], 0, 0, 0);
        }
        __syncthreads();
    }

    if (POOLF) {
        // masked per-column sums of v = acc + bias + res over 128 rows
        if (tid < 128) poolred[tid] = 0.f;
        __syncthreads();
        #pragma unroll
        for (int n = 0; n < 4; ++n) {
            int colloc = wc * 64 + n * 16 + l15;
            int col = col0 + colloc;
            float bia = BIAS ? bias[col] : 0.f;
            float p = 0.f;
            #pragma unroll
            for (int m = 0; m < 4; ++m) {
                #pragma unroll
                for (int j = 0; j < 4; ++j) {
                    int rowloc = wr * 64 + m * 16 + lg * 4 + j;
                    float v = acc[m][n][j] + bia;
                    if (RES) v += bf2f(Rh[(size_t)(row0 + rowloc) * Nd + col]);
                    p += v * msk[rowloc];
                }
            }
            atomicAdd(&poolred[colloc], p);
        }
        __syncthreads();
        if (tid < 128)
            pPart[(((size_t)((row0 >> 7) & 3)) * 64 + (row0 >> 9)) * 512
                  + col0 + tid] = poolred[tid];
        return;
    }

    if (TRIPLE && col0 >= 1024) {
        // V branch: transposed-per-batch uint2 stores (unchanged)
        #pragma unroll
        for (int m = 0; m < 4; ++m) {
            #pragma unroll
            for (int n = 0; n < 4; ++n) {
                int col = col0 + wc * 64 + n * 16 + l15;
                union { uint2 u; ushort s4[4]; } pk;
                #pragma unroll
                for (int j = 0; j < 4; ++j) pk.s4[j] = f2bf(acc[m][n][j]);
                int brow = row0 + wr * 64 + m * 16 + lg * 4;
                size_t idx = ((size_t)(brow >> 9) << 18)
                           + (size_t)(col - 1024) * SEQ + (brow & 511);
                *reinterpret_cast<uint2*>(Ot + idx) = pk.u;
            }
        }
        return;
    }

    // vectorized pack epilogue: per-wave 64x72 LDS tile over dead staging SM
    ushort* pb = SM + w * (64 * 72);
    #pragma unroll
    for (int n = 0; n < 4; ++n) {
        int col = col0 + wc * 64 + n * 16 + l15;
        float bia = (!TRIPLE && BIAS) ? bias[col] : 0.f;
        #pragma unroll
        for (int m = 0; m < 4; ++m) {
            #pragma unroll
            for (int j = 0; j < 4; ++j) {
                int rloc = m * 16 + lg * 4 + j;
                float v = acc[m][n][j] + bia;
                if (!TRIPLE && RELU) v = fmaxf(v, 0.f);
                pb[rloc * 72 + n * 16 + l15] = f2bf(v);
            }
        }
    }
    // same-wave in-order LDS: writes above complete before reads below
    #pragma unroll
    for (int it = 0; it < 8; ++it) {
        int rl = it * 8 + (l >> 3);
        int ch = l & 7;
        uint4 pv = *reinterpret_cast<const uint4*>(pb + rl * 72 + ch * 8);
        int rowg = row0 + wr * 64 + rl;
        int colg = (TRIPLE ? (col0 & 511) : col0) + wc * 64 + ch * 8;
        ushort* Odst = TRIPLE ? ((col0 < 512) ? Oh : Ol) : Oh;
        size_t gidx = (size_t)rowg * (TRIPLE ? 512 : Nd) + colg;
        if (!TRIPLE && RES) {
            union { uint4 u; ushort s[8]; } rv, sv, ov;
            rv.u = *reinterpret_cast<const uint4*>(Rh + gidx);
            sv.u = pv;
            #pragma unroll
            for (int k = 0; k < 8; ++k)
                ov.s[k] = f2bf(bf2f(sv.s[k]) + bf2f(rv.s[k]));
            *reinterpret_cast<uint4*>(Odst + gidx) = ov.u;
        } else {
            *reinterpret_cast<uint4*>(Odst + gidx) = pv;
        }
    }
}

// ---------------- MFMA flash attention, 128 q-rows, KV dbuf, static-max ----
// (unchanged from r21-24 — proven)
__global__ __launch_bounds__(512)
void attn_mfma(ushort* __restrict__ QO, const ushort* __restrict__ K,
               const ushort* __restrict__ Vt, const float* __restrict__ maskA)
{
    __shared__ __align__(16) ushort Ks[2][64 * 64];   // [buf][kv][dh]
    __shared__ __align__(16) ushort Vs[2][64 * 64];   // [buf][dh][kv]
    __shared__ __align__(16) ushort Pl[8][16 * 64];   // [wave][q][kv] (Q alias)
    __shared__ float ms[512];
    const int h   = blockIdx.x;
    const int b   = blockIdx.y;
    const int qt  = blockIdx.z;
    const int tid = threadIdx.x;
    const int w = tid >> 6, l = tid & 63;
    const int l15 = l & 15, lg = l >> 4, l7 = l & 7;
    const int lrow   = l >> 3;
    const int gchunk = (l & 7) ^ lrow;
    const int qbase = qt * 128;

    // stage Q tile [128 q][64 dh] into Pl (dead until first P write)
    #pragma unroll
    for (int rr = 0; rr < 2; ++rr) {
        int rowb = rr * 64 + w * 8;             // 16 stripes, wave-uniform
        GL2LDS(QO + ((size_t)(b * SEQ + qbase + rowb + lrow)) * DIM
                  + h * DHEAD + gchunk * 8,
               &Pl[0][0] + rowb * 64);
    }
    // full mask row -> LDS (published by the q-skip barrier below)
    ms[tid] = maskA[b * SEQ + tid];
    // dead q-tile skip (global reads; barrier also drains Q-stage + ms)
    float qm = (tid < 128) ? maskA[b * SEQ + qbase + tid] : 0.f;
    if (!__syncthreads_or(qm != 0.f)) return;

    // per-64-kv-tile valid bits (block-uniform)
    unsigned hbits = 0;
    #pragma unroll
    for (int t = 0; t < 8; ++t) {
        int mine = (tid < 64) ? (ms[t * 64 + tid] != 0.f) : 0;
        if (__syncthreads_or(mine)) hbits |= (1u << t);
    }

    // hoist Q A-frags (reads Pl BEFORE any P write); wave w rows w*16+l15
    short8 af[2];
    #pragma unroll
    for (int s = 0; s < 2; ++s) {
        int q = w * 16 + l15;
        int c = (s * 4 + lg) ^ l7;
        af[s] = *reinterpret_cast<const short8*>(&Pl[0][0] + q * 64 + c * 8);
    }

    // all-ones bf16 B operand for row-sum MFMA
    short8 bones;
    #pragma unroll
    for (int i = 0; i < 8; ++i) bones[i] = (short)0x3F80;

    f32x4 oacc[4];
    #pragma unroll
    for (int t = 0; t < 4; ++t) oacc[t] = (f32x4){0.f, 0.f, 0.f, 0.f};
    f32x4 lacc = (f32x4){0.f, 0.f, 0.f, 0.f};   // row-sums of P

    ushort* pw = &Pl[w][0];

    auto stagekv = [&](int t, int bi) {
        int kv0 = t * 64;
        GL2LDS(K + ((size_t)(b * SEQ + kv0 + w * 8 + lrow)) * DIM
                 + h * DHEAD + gchunk * 8,
               &Ks[bi][0] + w * 8 * 64);
        GL2LDS(Vt + ((size_t)b << 18) + (size_t)(h * DHEAD + w * 8 + lrow) * SEQ
                  + kv0 + gchunk * 8,
               &Vs[bi][0] + w * 8 * 64);
    };

    int t0 = 0;
    while (t0 < 8 && !(hbits & (1u << t0))) ++t0;
    stagekv(t0, 0);
    __syncthreads();                         // tile t0 K/V ready
    int cur = 0;
    for (int t = t0; t < 8; ) {
        int tn = t + 1;
        while (tn < 8 && !(hbits & (1u << tn))) ++tn;
        if (tn < 8) stagekv(tn, cur ^ 1);    // async prefetch next valid tile

        // QK^T: 4 kv16-tiles x 2 k-steps
        f32x4 sacc[4];
        #pragma unroll
        for (int t4 = 0; t4 < 4; ++t4) sacc[t4] = (f32x4){0.f, 0.f, 0.f, 0.f};
        #pragma unroll
        for (int s = 0; s < 2; ++s) {
            int c = (s * 4 + lg) ^ l7;
            #pragma unroll
            for (int t4 = 0; t4 < 4; ++t4) {
                int kv = t4 * 16 + l15;
                short8 bf = *reinterpret_cast<const short8*>(
                    &Ks[cur][0] + kv * 64 + c * 8);
                sacc[t4] = __builtin_amdgcn_mfma_f32_16x16x32_bf16(af[s], bf, sacc[t4], 0, 0, 0);
            }
        }

        // static-max softmax: p = mask * exp(s/8)
        float mk[4];
        #pragma unroll
        for (int t4 = 0; t4 < 4; ++t4) mk[t4] = ms[t * 64 + t4 * 16 + l15];
        #pragma unroll
        for (int t4 = 0; t4 < 4; ++t4)
            #pragma unroll
            for (int j = 0; j < 4; ++j)
                sacc[t4][j] = mk[t4] * __expf(sacc[t4][j] * 0.125f);

        // P (bf16) -> per-wave LDS [16 q][64 kv], chunk-XOR swizzle;
        // pairs packed with v_cvt_pk_bf16_f32
        #pragma unroll
        for (int t4 = 0; t4 < 4; ++t4) {
            int kvh = t4 * 16 + l15;
            int base = (kvh & 7);
            int hi3  = (kvh >> 3);
            #pragma unroll
            for (int jp = 0; jp < 4; jp += 2) {
                unsigned u = cvtpk_bf16(sacc[t4][jp], sacc[t4][jp + 1]);
                int q0 = lg * 4 + jp;
                int q1 = q0 + 1;
                pw[q0 * 64 + base + ((hi3 ^ (q0 & 7)) << 3)] = (ushort)u;
                pw[q1 * 64 + base + ((hi3 ^ (q1 & 7)) << 3)] = (ushort)(u >> 16);
            }
        }

        // PV + row-sum: A = P[16 q][64 kv]; B = Vs[dh][kv] and ones
        #pragma unroll
        for (int s = 0; s < 2; ++s) {
            int c = (s * 4 + lg) ^ l7;
            short8 pa = *reinterpret_cast<const short8*>(&pw[l15 * 64 + c * 8]);
            lacc = __builtin_amdgcn_mfma_f32_16x16x32_bf16(pa, bones, lacc, 0, 0, 0);
            #pragma unroll
            for (int dt = 0; dt < 4; ++dt) {
                int dh = dt * 16 + l15;
                short8 vb = *reinterpret_cast<const short8*>(
                    &Vs[cur][0] + dh * 64 + c * 8);
                oacc[dt] = __builtin_amdgcn_mfma_f32_16x16x32_bf16(pa, vb, oacc[dt], 0, 0, 0);
            }
        }

        __syncthreads();                     // buf[cur] free for stage(t+2)
        cur ^= 1;
        t = tn;
    }

    // epilogue: O[q][h*64+dh] = oacc / lacc, in place over Q
    float inv[4];
    #pragma unroll
    for (int j = 0; j < 4; ++j) inv[j] = 1.0f / lacc[j];
    #pragma unroll
    for (int t = 0; t < 4; ++t) {
        #pragma unroll
        for (int j = 0; j < 4; ++j) {
            size_t g = ((size_t)(b * SEQ + qbase + w * 16 + lg * 4 + j)) * DIM
                     + h * DHEAD + t * 16 + l15;
            QO[g] = f2bf(oacc[t][j] * inv[j]);
        }
    }
}

// ---------------- proj: pooled (from partials) @ Wp + bp -> henc -----------
__global__ __launch_bounds__(512)
void proj_kernel(const float* __restrict__ pPart, const float* __restrict__ maskA,
                 const float* __restrict__ Wp, const float* __restrict__ bp,
                 float* __restrict__ henc)
{
    int b = blockIdx.x;     // 0..63
    int j = threadIdx.x;    // 0..511
    __shared__ float p[DIM];
    __shared__ float cs[512];
    cs[j] = maskA[b * SEQ + j];
    __syncthreads();
    for (int st = 256; st > 0; st >>= 1) {
        if (j < st) cs[j] += cs[j + st];
        __syncthreads();
    }
    float invc = 1.0f / fmaxf(cs[0], 1.f);
    __syncthreads();
    float s = pPart[((size_t)0 * 64 + b) * 512 + j]
            + pPart[((size_t)1 * 64 + b) * 512 + j]
            + pPart[((size_t)2 * 64 + b) * 512 + j]
            + pPart[((size_t)3 * 64 + b) * 512 + j];
    p[j] = s * invc;
    __syncthreads();
    float a0 = 0.f, a1 = 0.f, a2 = 0.f, a3 = 0.f;
    for (int d = 0; d < DIM; d += 4) {
        a0 += p[d]     * Wp[(size_t)d       * DIM + j];
        a1 += p[d + 1] * Wp[(size_t)(d + 1) * DIM + j];
        a2 += p[d + 2] * Wp[(size_t)(d + 2) * DIM + j];
        a3 += p[d + 3] * Wp[(size_t)(d + 3) * DIM + j];
    }
    henc[(size_t)b * DIM + j] = ((a0 + a1) + (a2 + a3)) + bp[j];
}

// ---------------- logits = concat(hH,hF) @ W_out + b_out -------------------
__global__ __launch_bounds__(256)
void logits_kernel(const float* __restrict__ henc, const float* __restrict__ Wout,
                   const float* __restrict__ bout, float* __restrict__ logits)
{
    int b = blockIdx.y;
    int m = blockIdx.x * 256 + threadIdx.x;
    __shared__ float hh[2 * DIM];
    for (int j = threadIdx.x; j < DIM; j += 256) {
        hh[j]       = henc[(size_t)b * DIM + j];
        hh[DIM + j] = henc[(size_t)(BATCH + b) * DIM + j];
    }
    __syncthreads();
    if (m < MM) {
        float a0 = 0.f, a1 = 0.f, a2 = 0.f, a3 = 0.f;
        for (int j = 0; j < 2 * DIM; j += 4) {
            a0 += hh[j]     * Wout[(size_t)j       * MM + m];
            a1 += hh[j + 1] * Wout[(size_t)(j + 1) * MM + m];
            a2 += hh[j + 2] * Wout[(size_t)(j + 2) * MM + m];
            a3 += hh[j + 3] * Wout[(size_t)(j + 3) * MM + m];
        }
        logits[b * MM + m] = ((a0 + a1) + (a2 + a3)) + bout[m];
    }
}

// ---------------- softmax + argmax ----------------
__global__ __launch_bounds__(256)
void smax_kernel(const float* __restrict__ logits, float* __restrict__ out)
{
    int b   = blockIdx.x;
    int tid = threadIdx.x;
    __shared__ float red[256];
    __shared__ int   redi[256];

    float v[4];
    float mx = -INFINITY;
    #pragma unroll
    for (int i = 0; i < 4; i++) {
        int m = tid + i * 256;
        if (m < MM) { v[i] = logits[b * MM + m]; mx = fmaxf(mx, v[i]); }
        else v[i] = -INFINITY;
    }
    red[tid] = mx; __syncthreads();
    for (int st = 128; st > 0; st >>= 1) {
        if (tid < st) red[tid] = fmaxf(red[tid], red[tid + st]);
        __syncthreads();
    }
    mx = red[0]; __syncthreads();

    float sum = 0.f;
    #pragma unroll
    for (int i = 0; i < 4; i++) {
        int m = tid + i * 256;
        if (m < MM) { v[i] = expf(v[i] - mx); sum += v[i]; }
    }
    red[tid] = sum; __syncthreads();
    for (int st = 128; st > 0; st >>= 1) {
        if (tid < st) red[tid] += red[tid + st];
        __syncthreads();
    }
    float inv = 1.0f / red[0]; __syncthreads();

    float bestv = -INFINITY; int besti = 0x7fffffff;
    #pragma unroll
    for (int i = 0; i < 4; i++) {
        int m = tid + i * 256;
        if (m < MM) {
            float lam = v[i] * inv;
            out[b * MM + m] = lam;
            if (lam > bestv) { bestv = lam; besti = m; }
        }
    }
    red[tid] = bestv; redi[tid] = besti; __syncthreads();
    for (int st = 128; st > 0; st >>= 1) {
        if (tid < st) {
            float ov = red[tid + st]; int oi = redi[tid + st];
            if (ov > red[tid] || (ov == red[tid] && oi < redi[tid])) {
                red[tid] = ov; redi[tid] = oi;
            }
        }
        __syncthreads();
    }
    if (tid == 0) out[BATCH * MM + b] = (float)redi[0];
}

// ---------------------------------------------------------------------------
extern "C" void kernel_launch(void* const* d_in, const int* in_sizes, int n_in,
                              void* d_out, int out_size, void* d_ws, size_t ws_size,
                              hipStream_t stream)
{
    const float* xH   = (const float*)d_in[0];
    const float* xF   = (const float*)d_in[1];
    const float* Wm   = (const float*)d_in[2];
    const float* Wt   = (const float*)d_in[3];
    const float* bt   = (const float*)d_in[4];
    const float* Wq   = (const float*)d_in[5];
    const float* Wk   = (const float*)d_in[6];
    const float* Wv   = (const float*)d_in[7];
    const float* Wo   = (const float*)d_in[8];
    const float* W1   = (const float*)d_in[9];
    const float* b1   = (const float*)d_in[10];
    const float* W2   = (const float*)d_in[11];
    const float* b2   = (const float*)d_in[12];
    const float* Wp   = (const float*)d_in[13];
    const float* bp   = (const float*)d_in[14];
    const float* Wout = (const float*)d_in[15];
    const float* bout = (const float*)d_in[16];
    float* out = (float*)d_out;

    float* ws     = (float*)d_ws;
    float*  WmT    = ws + OFF_WMT;
    float*  maskA  = ws + OFF_MASK;
    float*  henc   = ws + OFF_HENC;
    float*  logits = ws + OFF_LOG;
    float*  pPart  = ws + OFF_PPART;            // fp32 [4][64][512]
    ushort* WqkvTh = (ushort*)(ws + OFF_WQTH);
    ushort* WoTh   = WqkvTh + (size_t)1536 * 512;
    ushort* W1Th   = (ushort*)(ws + OFF_W1TH);
    ushort* W2Th   = (ushort*)(ws + OFF_W2TH);
    ushort* ehi    = (ushort*)(ws + OFF_EHI);   // e -> h (pristine for FFN)
    ushort* Qb     = (ushort*)(ws + OFF_QB);    // Q -> O
    ushort* Kb     = (ushort*)(ws + OFF_KB);
    ushort* Vtb    = (ushort*)(ws + OFF_VB);
    ushort* rbuf   = (ushort*)(ws + OFF_KB);    // [32768][2048] over Kb+Vtb+R2

    // ---- fused setup ----
    setup_all<<<dim3(3584), 256, 0, stream>>>(
        Wm, Wq, Wk, Wv, Wo, W1, W2, WmT, WqkvTh, W1Th, W2Th);

    // ---- merged H+F pass (single-bf16 residual stream) ----
    embed_kernel<<<dim3(BROWS / 4), 256, 0, stream>>>(
        xH, xF, WmT, Wt, bt, ehi, maskA);
    // fused QKV: Q->Qb, K->Kb, V->Vtb (transposed per batch)
    gemm_bf16<false,false,false,true,false><<<dim3(12, 256), 256, 0, stream>>>(
        ehi, WqkvTh, nullptr, nullptr,
        Qb, Kb, Vtb, nullptr, BROWS, 512, DIM, DIM, DIM, maskA);
    // MFMA attention, O overwrites Q
    attn_mfma<<<dim3(NHEAD, BB, 4), 512, 0, stream>>>(Qb, Kb, Vtb, maskA);
    // h = e + O @ Wo  (in place over ehi; single residual, vector epilogue)
    gemm_bf16<false,false,true,false,false><<<dim3(4, 256), 256, 0, stream>>>(
        Qb, WoTh, nullptr, ehi,
        ehi, nullptr, nullptr, nullptr, BROWS, DIM, DIM, DIM, DIM, maskA);
    // FFN single-shot (rbuf [32768][2048] over dead K+V^T+R2):
    //   W1: r = relu(h @ W1 + b1)   [vector store epilogue]
    gemm_bf16<true,true,false,false,false><<<dim3(16, 256), 256, 0, stream>>>(
        ehi, W1Th, b1, nullptr,
        rbuf, nullptr, nullptr, nullptr, BROWS, DFFN, DIM, DIM, DIM, maskA);
    //   W2 POOL-FUSED: masked column-sums of (h + r@W2 + b2) -> pPart
    gemm_bf16<true,false,true,false,true><<<dim3(4, 256), 256, 0, stream>>>(
        rbuf, W2Th, b2, ehi,
        nullptr, nullptr, nullptr, pPart, BROWS, DIM, DFFN, DFFN, DFFN, maskA);
    // proj: pooled = sum(partials)/cnt; henc = pooled @ Wp + bp
    proj_kernel<<<dim3(BB), 512, 0, stream>>>(pPart, maskA, Wp, bp, henc);
    logits_kernel<<<dim3(4, BATCH), 256, 0, stream>>>(henc, Wout, bout, logits);
    smax_kernel<<<dim3(BATCH), 256, 0, stream>>>(logits, out);
}